// Round 7
// baseline (3056.084 us; speedup 1.0000x reference)
//
#include <hip/hip_runtime.h>

#define NU 100000
#define NI 150000
#define NTOT 250000
#define DD 64
#define NNZ_A 2000000
#define NNZ_S 800000
#define SCAN_CHUNK 2048  // 256 threads x 8

typedef unsigned int uint;
typedef unsigned short ushort;

// ================= helpers =================
#define RDLANE_F(x, k) __uint_as_float(__builtin_amdgcn_readlane(__float_as_uint(x), (unsigned)(k)))
#define RDLANE_I(x, k) ((int)__builtin_amdgcn_readlane((unsigned)(x), (unsigned)(k)))

__device__ __forceinline__ uint f2bf_bits(float x) {  // RNE round to bf16 (upper 16)
  uint a = __float_as_uint(x);
  return (a + 0x7fffu + ((a >> 16) & 1u)) >> 16;
}
__device__ __forceinline__ ushort f2bf(float x) { return (ushort)f2bf_bits(x); }
__device__ __forceinline__ float bf2f(ushort h) { return __uint_as_float(((uint)h) << 16); }
__device__ __forceinline__ uint pack_bf16x2(float lo, float hi) {
  return f2bf_bits(lo) | (f2bf_bits(hi) << 16);
}
__device__ __forceinline__ float unpk_lo(uint p) { return __uint_as_float(p << 16); }
__device__ __forceinline__ float unpk_hi(uint p) { return __uint_as_float(p & 0xffff0000u); }

// load lane's row of staged W (Wl[j*65+k]) into regs and PIN to VGPRs
__device__ __forceinline__ void load_wreg(const float* __restrict__ Wl, int lane,
                                          float* __restrict__ w) {
#pragma unroll
  for (int k = 0; k < 64; ++k) w[k] = Wl[lane * 65 + k];
#pragma unroll
  for (int k = 0; k < 64; ++k) asm("" : "+v"(w[k]));
}

__device__ __forceinline__ void gemm64x2(float aA, float aB, const float* __restrict__ w,
                                         float& oA, float& oB) {
  oA = 0.f; oB = 0.f;
#pragma unroll
  for (int k = 0; k < 64; ++k) {
    float wk = w[k];
    oA = fmaf(RDLANE_F(aA, k), wk, oA);
    oB = fmaf(RDLANE_F(aB, k), wk, oB);
  }
}

__device__ __forceinline__ void gemm64x4(float a1, float a2, float a3, float a4,
                                         const float* __restrict__ w,
                                         float& o1, float& o2, float& o3, float& o4) {
  o1 = 0.f; o2 = 0.f; o3 = 0.f; o4 = 0.f;
#pragma unroll
  for (int k = 0; k < 64; ++k) {
    float wk = w[k];
    o1 = fmaf(RDLANE_F(a1, k), wk, o1);
    o2 = fmaf(RDLANE_F(a2, k), wk, o2);
    o3 = fmaf(RDLANE_F(a3, k), wk, o3);
    o4 = fmaf(RDLANE_F(a4, k), wk, o4);
  }
}

// ---------- init: all_emb_bf16 = [(u1+u2)/2 ; item]; out = same (fp32) ----------
__global__ void k_init(const float* __restrict__ u1, const float* __restrict__ u2,
                       const float* __restrict__ item, ushort* __restrict__ emb_bf,
                       float* __restrict__ out_final) {
  int idx = blockIdx.x * blockDim.x + threadIdx.x;
  const int tot = NTOT * DD;
  const int nu = NU * DD;
  for (; idx < tot; idx += gridDim.x * blockDim.x) {
    float v;
    if (idx < nu) v = 0.5f * (u1[idx] + u2[idx]);
    else          v = item[idx - nu];
    emb_bf[idx] = f2bf(v);
    out_final[idx] = v;
  }
}

// ================= CSR build (counting sort) =================
__global__ void k_hist(const int* __restrict__ rows, int* __restrict__ cnt, int nnz) {
  int idx = blockIdx.x * blockDim.x + threadIdx.x;
  for (; idx < nnz; idx += gridDim.x * blockDim.x)
    atomicAdd(&cnt[rows[idx]], 1);
}

__global__ void k_scan1(const int* __restrict__ cnt, int* __restrict__ bsum, int n) {
  __shared__ int sdata[256];
  int base = blockIdx.x * SCAN_CHUNK;
  int s = 0;
#pragma unroll
  for (int k = 0; k < 8; ++k) {
    int i = base + threadIdx.x * 8 + k;
    s += (i < n) ? cnt[i] : 0;
  }
  sdata[threadIdx.x] = s;
  __syncthreads();
  for (int off = 128; off > 0; off >>= 1) {
    if (threadIdx.x < off) sdata[threadIdx.x] += sdata[threadIdx.x + off];
    __syncthreads();
  }
  if (threadIdx.x == 0) bsum[blockIdx.x] = sdata[0];
}

__global__ void k_scan2(int* bsum, int nb) {
  __shared__ int sdata[256];
  int v = (threadIdx.x < nb) ? bsum[threadIdx.x] : 0;
  sdata[threadIdx.x] = v;
  __syncthreads();
  for (int off = 1; off < 256; off <<= 1) {
    int t = (threadIdx.x >= (unsigned)off) ? sdata[threadIdx.x - off] : 0;
    __syncthreads();
    sdata[threadIdx.x] += t;
    __syncthreads();
  }
  if (threadIdx.x < nb) bsum[threadIdx.x] = sdata[threadIdx.x] - v;
}

__global__ void k_scan3(const int* __restrict__ cnt, const int* __restrict__ bsum,
                        int* __restrict__ rowptr, int* __restrict__ cur, int n, int nnz) {
  __shared__ int sdata[256];
  int base = blockIdx.x * SCAN_CHUNK;
  int loc[8];
  int s = 0;
#pragma unroll
  for (int k = 0; k < 8; ++k) {
    int i = base + threadIdx.x * 8 + k;
    loc[k] = (i < n) ? cnt[i] : 0;
    s += loc[k];
  }
  sdata[threadIdx.x] = s;
  __syncthreads();
  for (int off = 1; off < 256; off <<= 1) {
    int t = (threadIdx.x >= (unsigned)off) ? sdata[threadIdx.x - off] : 0;
    __syncthreads();
    sdata[threadIdx.x] += t;
    __syncthreads();
  }
  int pre = bsum[blockIdx.x] + sdata[threadIdx.x] - s;
#pragma unroll
  for (int k = 0; k < 8; ++k) {
    int i = base + threadIdx.x * 8 + k;
    if (i < n) { rowptr[i] = pre; cur[i] = pre; pre += loc[k]; }
  }
  if (blockIdx.x == 0 && threadIdx.x == 0) rowptr[n] = nnz;
}

__global__ void k_scatter(const int* __restrict__ rows, const int* __restrict__ cols,
                          const float* __restrict__ vals, int* __restrict__ cur,
                          int2* __restrict__ cv, int nnz) {
  int idx = blockIdx.x * blockDim.x + threadIdx.x;
  for (; idx < nnz; idx += gridDim.x * blockDim.x) {
    int r = rows[idx];
    int p = atomicAdd(&cur[r], 1);
    cv[p] = make_int2(cols[idx], __float_as_int(vals[idx]));
  }
}

// ================= dense pre-transform =================
// SOCP[i] = pack(u1[i]@Wc.T, u2[i]@Wc.T); NEG0P[i] = pack(u1[s1[i]]@Wc.T, u2[s2[i]]@Wc.T)
__global__ void k_transform(const float* __restrict__ u1, const float* __restrict__ u2,
                            const int* __restrict__ s1, const int* __restrict__ s2,
                            const float* __restrict__ Wc, uint* __restrict__ SOCP,
                            uint* __restrict__ NEG0P) {
  __shared__ float Wl[64 * 65];
  for (int idx = threadIdx.x; idx < 64 * 64; idx += blockDim.x)
    Wl[(idx >> 6) * 65 + (idx & 63)] = Wc[idx];
  __syncthreads();
  int lane = threadIdx.x & 63;
  float w[64];
  load_wreg(Wl, lane, w);
  int wid = (blockIdx.x * blockDim.x + threadIdx.x) >> 6;
  int nw = (gridDim.x * blockDim.x) >> 6;
  for (int i = wid; i < NU; i += nw) {
    float a1 = u1[(size_t)i * DD + lane];
    float a2 = u2[(size_t)i * DD + lane];
    int g1 = s1[i], g2 = s2[i];
    float a3 = u1[(size_t)g1 * DD + lane];
    float a4 = u2[(size_t)g2 * DD + lane];
    float o1, o2, o3, o4;
    gemm64x4(a1, a2, a3, a4, w, o1, o2, o3, o4);
    SOCP[(size_t)i * DD + lane]  = pack_bf16x2(o1, o2);
    NEG0P[(size_t)i * DD + lane] = pack_bf16x2(o3, o4);
  }
}

// ================= gather kernels =================
// quad: gathers 2 packed tables (4 chains); tanh; writes 4 bf16 outputs +
// next-layer packed table (fused gemm on the neg pair).
__global__ void k_quadS(const int* __restrict__ rowptr, const int2* __restrict__ cv,
                        const uint* __restrict__ SOCP, const uint* __restrict__ NEG0P,
                        const float* __restrict__ Wc,
                        ushort* __restrict__ u1s, ushort* __restrict__ u2s,
                        ushort* __restrict__ n1o, ushort* __restrict__ n2o,
                        uint* __restrict__ NEGPa) {
  __shared__ float Wl[64 * 65];
  for (int idx = threadIdx.x; idx < 64 * 64; idx += blockDim.x)
    Wl[(idx >> 6) * 65 + (idx & 63)] = Wc[idx];
  __syncthreads();
  int lane = threadIdx.x & 63;
  float w[64];
  load_wreg(Wl, lane, w);
  int wid = (blockIdx.x * blockDim.x + threadIdx.x) >> 6;
  int nw = (gridDim.x * blockDim.x) >> 6;
  for (int r = wid; r < NU; r += nw) {
    int start = rowptr[r], end = rowptr[r + 1];
    float a1 = 0.f, a2 = 0.f, a3 = 0.f, a4 = 0.f;
    for (int p0 = start; p0 < end; p0 += 64) {
      int n = min(64, end - p0);
      int2 e = cv[p0 + (lane < n ? lane : 0)];
      for (int k = 0; k < n; k += 8) {
        uint q1[8], q2[8];
        float vv[8];
#pragma unroll
        for (int u = 0; u < 8; ++u) {
          int kk = k + u;
          int ks = min(kk, n - 1);
          int c = RDLANE_I(e.x, ks);
          vv[u] = (kk < n) ? RDLANE_F(__int_as_float(e.y), ks) : 0.f;
          q1[u] = SOCP[(size_t)c * DD + lane];
          q2[u] = NEG0P[(size_t)c * DD + lane];
        }
#pragma unroll
        for (int u = 0; u < 8; ++u) {
          a1 = fmaf(vv[u], unpk_lo(q1[u]), a1);
          a2 = fmaf(vv[u], unpk_hi(q1[u]), a2);
          a3 = fmaf(vv[u], unpk_lo(q2[u]), a3);
          a4 = fmaf(vv[u], unpk_hi(q2[u]), a4);
        }
      }
    }
    float t1 = tanhf(a1), t2 = tanhf(a2), t3 = tanhf(a3), t4 = tanhf(a4);
    u1s[(size_t)r * DD + lane] = f2bf(t1);
    u2s[(size_t)r * DD + lane] = f2bf(t2);
    n1o[(size_t)r * DD + lane] = f2bf(t3);
    n2o[(size_t)r * DD + lane] = f2bf(t4);
    float o3, o4;
    gemm64x2(t3, t4, w, o3, o4);  // pre-transform layer-0 negs for layer-1 gather
    NEGPa[(size_t)r * DD + lane] = pack_bf16x2(o3, o4);
  }
}

// dual: gathers 1 packed table; tanh; fused false-logits; optional next-table.
__global__ void k_dualS(const int* __restrict__ rowptr, const int2* __restrict__ cv,
                        const uint* __restrict__ T, const float* __restrict__ Wc,
                        const float* __restrict__ wva, const float* __restrict__ wvb,
                        const float* __restrict__ fkb, float* __restrict__ out_logits,
                        int slot, uint* __restrict__ Tnext) {
  __shared__ float Wl[64 * 65];
  for (int idx = threadIdx.x; idx < 64 * 64; idx += blockDim.x)
    Wl[(idx >> 6) * 65 + (idx & 63)] = Wc[idx];
  __syncthreads();
  int lane = threadIdx.x & 63;
  float w[64];
  load_wreg(Wl, lane, w);
  int wid = (blockIdx.x * blockDim.x + threadIdx.x) >> 6;
  int nw = (gridDim.x * blockDim.x) >> 6;
  float b = fkb[0];
  float wa = wva[lane], wb = wvb[lane];
  for (int r = wid; r < NU; r += nw) {
    int start = rowptr[r], end = rowptr[r + 1];
    float accA = 0.f, accB = 0.f;
    for (int p0 = start; p0 < end; p0 += 64) {
      int n = min(64, end - p0);
      int2 e = cv[p0 + (lane < n ? lane : 0)];
      for (int k = 0; k < n; k += 8) {
        uint q[8];
        float vv[8];
#pragma unroll
        for (int u = 0; u < 8; ++u) {
          int kk = k + u;
          int ks = min(kk, n - 1);
          int c = RDLANE_I(e.x, ks);
          vv[u] = (kk < n) ? RDLANE_F(__int_as_float(e.y), ks) : 0.f;
          q[u] = T[(size_t)c * DD + lane];
        }
#pragma unroll
        for (int u = 0; u < 8; ++u) {
          accA = fmaf(vv[u], unpk_lo(q[u]), accA);
          accB = fmaf(vv[u], unpk_hi(q[u]), accB);
        }
      }
    }
    float ta = tanhf(accA), tb = tanhf(accB);
    float pa = ta * wa, pb = tb * wb;
#pragma unroll
    for (int off = 32; off > 0; off >>= 1) {
      pa += __shfl_xor(pa, off);
      pb += __shfl_xor(pb, off);
    }
    if (lane == 0) {
      out_logits[(size_t)(NU + r) * 6 + slot] = pa + b;  // sc4: u1_neg chain
      out_logits[(size_t)r * 6 + slot] = pb + b;          // sc3: u2_neg chain
    }
    if (Tnext) {
      float oa, ob;
      gemm64x2(ta, tb, w, oa, ob);
      Tnext[(size_t)r * DD + lane] = pack_bf16x2(oa, ob);
    }
  }
}

// A-type, bf16 table, 2 rows per wave.
__global__ void k_spmm_fusedA2(const int* __restrict__ rowptr, const int2* __restrict__ cv,
                               const ushort* __restrict__ X, const float* __restrict__ W,
                               ushort* __restrict__ embNext, float* __restrict__ outF) {
  __shared__ float Wl[64 * 65];
  for (int idx = threadIdx.x; idx < 64 * 64; idx += blockDim.x)
    Wl[(idx >> 6) * 65 + (idx & 63)] = W[idx];
  __syncthreads();
  int lane = threadIdx.x & 63;
  float w[64];
  load_wreg(Wl, lane, w);
  int wid = (blockIdx.x * blockDim.x + threadIdx.x) >> 6;
  int nw = (gridDim.x * blockDim.x) >> 6;
  for (int r = wid * 2; r < NTOT; r += nw * 2) {
    int sA = rowptr[r], m = rowptr[r + 1], eB = rowptr[r + 2];
    float accA = 0.f, accB = 0.f;
    for (int pA = sA, pB = m; pA < m || pB < eB; pA += 64, pB += 64) {
      int nA = (pA < m) ? min(64, m - pA) : 0;
      int nB = (pB < eB) ? min(64, eB - pB) : 0;
      int2 eAv = cv[(nA ? pA : 0) + (lane < nA ? lane : 0)];
      int2 eBv = cv[(nB ? pB : 0) + (lane < nB ? lane : 0)];
      int kmax = max(nA, nB);
      for (int k = 0; k < kmax; k += 8) {
        uint hA[8], hB[8];
        float vA[8], vB[8];
#pragma unroll
        for (int u = 0; u < 8; ++u) {
          int kk = k + u;
          int ksA = min(kk, max(nA - 1, 0));
          int ksB = min(kk, max(nB - 1, 0));
          int cA = RDLANE_I(eAv.x, ksA);
          int cB = RDLANE_I(eBv.x, ksB);
          vA[u] = (kk < nA) ? RDLANE_F(__int_as_float(eAv.y), ksA) : 0.f;
          vB[u] = (kk < nB) ? RDLANE_F(__int_as_float(eBv.y), ksB) : 0.f;
          hA[u] = X[(size_t)cA * DD + lane];
          hB[u] = X[(size_t)cB * DD + lane];
        }
#pragma unroll
        for (int u = 0; u < 8; ++u) {
          accA = fmaf(vA[u], __uint_as_float(hA[u] << 16), accA);
          accB = fmaf(vB[u], __uint_as_float(hB[u] << 16), accB);
        }
      }
    }
    if (r < NU) {  // NU even: pair never straddles
      float oA, oB;
      gemm64x2(accA, accB, w, oA, oB);
      embNext[(size_t)r * DD + lane] = f2bf(tanhf(oA));
      embNext[(size_t)(r + 1) * DD + lane] = f2bf(tanhf(oB));
    } else {
      embNext[(size_t)r * DD + lane] = f2bf(accA);
      embNext[(size_t)(r + 1) * DD + lane] = f2bf(accB);
      outF[(size_t)r * DD + lane] += accA;
      outF[(size_t)(r + 1) * DD + lane] += accB;
    }
  }
}

// ---------- fused column sums (bf16 inputs) ----------
__global__ void k_colsum2(const ushort* __restrict__ x1, const ushort* __restrict__ x2,
                          float* __restrict__ c1, float* __restrict__ c2) {
  int lane = threadIdx.x & 63;
  int wid = (blockIdx.x * blockDim.x + threadIdx.x) >> 6;
  int nw = (gridDim.x * blockDim.x) >> 6;
  float a1 = 0.f, a2 = 0.f;
  for (int i = wid; i < NU; i += nw) {
    a1 += bf2f(x1[(size_t)i * DD + lane]);
    a2 += bf2f(x2[(size_t)i * DD + lane]);
  }
  atomicAdd(&c1[lane], a1);
  atomicAdd(&c2[lane], a2);
}

// ---------- w = fk_W @ (csum/NU) ----------
__global__ void k_wvec(const float* __restrict__ fkW, const float* __restrict__ c1r,
                       const float* __restrict__ c2r, float* __restrict__ w1,
                       float* __restrict__ w2) {
  int j = threadIdx.x;
  float a1 = 0.f, a2 = 0.f;
  for (int k = 0; k < 64; ++k) {
    float w = fkW[j * 64 + k];
    a1 += w * c1r[k];
    a2 += w * c2r[k];
  }
  w1[j] = a1 * (1.0f / NU);
  w2[j] = a2 * (1.0f / NU);
}

// ---------- logits: true slots 0-2 + false slot 3 (layer-0 negs) ----------
__global__ void k_logits4(const ushort* __restrict__ u1s, const ushort* __restrict__ u2s,
                          const ushort* __restrict__ n1o, const ushort* __restrict__ n2o,
                          const float* __restrict__ w1, const float* __restrict__ w2,
                          const float* __restrict__ fkb, float* __restrict__ out_logits) {
  int lane = threadIdx.x & 63;
  int wid = (blockIdx.x * blockDim.x + threadIdx.x) >> 6;
  int nw = (gridDim.x * blockDim.x) >> 6;
  float b = fkb[0];
  for (int i = wid; i < 2 * NU; i += nw) {
    bool lo = i < NU;
    int r = lo ? i : i - NU;
    const ushort* xs = lo ? u2s : u1s;
    const ushort* xn = lo ? n2o : n1o;
    const float* wv = lo ? w1 : w2;
    float wvl = wv[lane];
    float ps = bf2f(xs[(size_t)r * DD + lane]) * wvl;
    float pn = bf2f(xn[(size_t)r * DD + lane]) * wvl;
#pragma unroll
    for (int off = 32; off > 0; off >>= 1) {
      ps += __shfl_xor(ps, off);
      pn += __shfl_xor(pn, off);
    }
    if (lane == 0) {
      float vs = ps + b;
      out_logits[(size_t)i * 6 + 0] = vs;
      out_logits[(size_t)i * 6 + 1] = vs;
      out_logits[(size_t)i * 6 + 2] = vs;
      out_logits[(size_t)i * 6 + 3] = pn + b;
    }
  }
}

// ---------- UC[i] = (0.5*(u1s+u2s)) @ Ws[:,64:].T -> bf16 ----------
__global__ void k_comb_gemm(const ushort* __restrict__ u1s, const ushort* __restrict__ u2s,
                            const float* __restrict__ Ws, ushort* __restrict__ UC) {
  __shared__ float Wl[64 * 65];
  for (int idx = threadIdx.x; idx < 64 * 64; idx += blockDim.x) {
    int j = idx >> 6, k = idx & 63;
    Wl[j * 65 + k] = Ws[j * 128 + 64 + k];
  }
  __syncthreads();
  int lane = threadIdx.x & 63;
  float w[64];
  load_wreg(Wl, lane, w);
  int wid = (blockIdx.x * blockDim.x + threadIdx.x) >> 6;
  int nw = (gridDim.x * blockDim.x) >> 6;
  for (int i = wid; i < NU; i += nw) {
    float c = 0.5f * (bf2f(u1s[(size_t)i * DD + lane]) + bf2f(u2s[(size_t)i * DD + lane]));
    float o = 0.f;
#pragma unroll
    for (int k = 0; k < 64; ++k) o = fmaf(RDLANE_F(c, k), w[k], o);
    UC[(size_t)i * DD + lane] = f2bf(o);
  }
}

// ---------- users_raw = u_next @ Ws[:,:64].T + UC ; sum of squares ----------
__global__ void k_users(const ushort* __restrict__ u_next, const ushort* __restrict__ uc,
                        const float* __restrict__ Ws, float* __restrict__ users_raw,
                        float* __restrict__ sumsq) {
  __shared__ float Wl[64 * 65];
  for (int idx = threadIdx.x; idx < 64 * 64; idx += blockDim.x) {
    int j = idx >> 6, k = idx & 63;
    Wl[j * 65 + k] = Ws[j * 128 + k];
  }
  __syncthreads();
  int lane = threadIdx.x & 63;
  float w[64];
  load_wreg(Wl, lane, w);
  int wid = (blockIdx.x * blockDim.x + threadIdx.x) >> 6;
  int nw = (gridDim.x * blockDim.x) >> 6;
  float ss = 0.f;
  for (int i = wid; i < NU; i += nw) {
    float va = bf2f(u_next[(size_t)i * DD + lane]);
    float acc = bf2f(uc[(size_t)i * DD + lane]);
#pragma unroll
    for (int k = 0; k < 64; ++k) acc = fmaf(RDLANE_F(va, k), w[k], acc);
    users_raw[(size_t)i * DD + lane] = acc;
    ss += acc * acc;
  }
#pragma unroll
  for (int off = 32; off > 0; off >>= 1) ss += __shfl_xor(ss, off);
  if (lane == 0) atomicAdd(sumsq, ss);
}

__global__ void k_users_acc(const float* __restrict__ users_raw,
                            const float* __restrict__ sumsq, float* __restrict__ out_final) {
  float scale = 1.0f / sqrtf(*sumsq);
  int idx = blockIdx.x * blockDim.x + threadIdx.x;
  for (; idx < NU * DD; idx += gridDim.x * blockDim.x)
    out_final[idx] += users_raw[idx] * scale;
}

__global__ void k_scale(float* __restrict__ out_final) {
  int idx = blockIdx.x * blockDim.x + threadIdx.x;
  const int tot = NTOT * DD;
  for (; idx < tot; idx += gridDim.x * blockDim.x) out_final[idx] *= 0.25f;
}

extern "C" void kernel_launch(void* const* d_in, const int* in_sizes, int n_in,
                              void* d_out, int out_size, void* d_ws, size_t ws_size,
                              hipStream_t stream) {
  const float* u1      = (const float*)d_in[0];
  const float* u2      = (const float*)d_in[1];
  const float* item    = (const float*)d_in[2];
  const float* Wi      = (const float*)d_in[3];
  const float* Wc      = (const float*)d_in[4];
  const float* Ws      = (const float*)d_in[5];
  const float* fk_W    = (const float*)d_in[6];
  const float* fk_b    = (const float*)d_in[7];
  const float* A_vals  = (const float*)d_in[8];
  const float* A2_vals = (const float*)d_in[9];
  const float* S_vals  = (const float*)d_in[10];
  const int*   A_rows  = (const int*)d_in[11];
  const int*   A_cols  = (const int*)d_in[12];
  const int*   A2_rows = (const int*)d_in[13];
  const int*   A2_cols = (const int*)d_in[14];
  const int*   S_rows  = (const int*)d_in[15];
  const int*   S_cols  = (const int*)d_in[16];
  const int*   sh1     = (const int*)d_in[17];
  const int*   sh2     = (const int*)d_in[18];

  // ---- workspace layout (float offsets), total ~54.2M floats = 216.8MB ----
  float* ws = (float*)d_ws;
  ushort* embA_bf = (ushort*)ws;                   // [0, 8M)   16M ushorts
  ushort* embB_bf = (ushort*)(ws + 8000000);       // [8M, 16M)
  uint*   SOCP    = (uint*)(ws + 16000000);        // [16M, 22.4M)  dead after quad
  uint*   NEGPb   = SOCP;                          //   overlay: written at l=1 dual
  uint*   NEG0P   = (uint*)(ws + 22400000);        // [22.4M, 28.8M) dead after quad
  float*  uraw    = ws + 22400000;                 //   overlay: fp32 users scratch
  uint*   NEGPa   = (uint*)(ws + 28800000);        // [28.8M, 35.2M)
  ushort* u1s     = (ushort*)(ws + 35200000);      // [35.2M, 38.4M) dead after comb
  ushort* u2s     = (ushort*)(ws + 38400000);      // [38.4M, 41.6M) dead after comb
  int2*   cvA2    = (int2*)(ws + 35200000);        //   overlay: built after comb
  int*    ptrA2   = (int*)(ws + 39200000);         //   overlay (inside u2s region)
  ushort* n1o     = (ushort*)(ws + 41600000);      // [41.6M, 44.8M) dead after logits4
  ushort* UCb     = (ushort*)(ws + 41600000);      //   overlay: written by comb_gemm
  ushort* n2o     = (ushort*)(ws + 44800000);      // [44.8M, 48M)   dead after logits4
  int2*   cvA     = (int2*)(ws + 48000000);        // [48M, 52M)
  int2*   cvS     = (int2*)(ws + 52000000);        // [52M, 53.6M)
  int*    ptrA    = (int*)(ws + 53600000);         // 250001
  int*    ptrS    = ptrA + (NTOT + 1);             // 100001
  int*    cur     = ptrS + (NU + 1);               // 250000
  int*    bsum    = cur + NTOT;                    // 256
  float*  c1r     = (float*)(bsum + 256);          // 64
  float*  c2r     = c1r + 64;
  float*  w1      = c2r + 64;
  float*  w2      = w1 + 64;
  float*  sumsq   = w2 + 64;                       // 1

  float* out        = (float*)d_out;
  float* out_logits = out + (size_t)NTOT * DD;

  auto build = [&](const int* rows, const int* cols, const float* vals,
                   int n, int nnz, int* ptr, int2* cv) {
    int nb = (n + SCAN_CHUNK - 1) / SCAN_CHUNK;
    hipMemsetAsync(cur, 0, (size_t)n * sizeof(int), stream);
    k_hist<<<2048, 256, 0, stream>>>(rows, cur, nnz);
    k_scan1<<<nb, 256, 0, stream>>>(cur, bsum, n);
    k_scan2<<<1, 256, 0, stream>>>(bsum, nb);
    k_scan3<<<nb, 256, 0, stream>>>(cur, bsum, ptr, cur, n, nnz);
    k_scatter<<<2048, 256, 0, stream>>>(rows, cols, vals, cur, cv, nnz);
  };

  // ---------- CSR builds (S, A) ----------
  build(S_rows, S_cols, S_vals, NU, NNZ_S, ptrS, cvS);
  build(A_rows, A_cols, A_vals, NTOT, NNZ_A, ptrA, cvA);

  // ---------- init + pre-transform ----------
  hipMemsetAsync(c1r, 0, 128 * sizeof(float), stream);
  k_init<<<2048, 256, 0, stream>>>(u1, u2, item, embA_bf, out);
  k_transform<<<2048, 256, 0, stream>>>(u1, u2, sh1, sh2, Wc, SOCP, NEG0P);

  // ---------- quad gather: socials + layer-0 negs + layer-1 table ----------
  k_quadS<<<2048, 256, 0, stream>>>(ptrS, cvS, SOCP, NEG0P, Wc,
                                    u1s, u2s, n1o, n2o, NEGPa);
  k_colsum2<<<256, 256, 0, stream>>>(u1s, u2s, c1r, c2r);
  k_wvec<<<1, 64, 0, stream>>>(fk_W, c1r, c2r, w1, w2);
  k_logits4<<<1024, 256, 0, stream>>>(u1s, u2s, n1o, n2o, w1, w2, fk_b, out_logits);
  k_comb_gemm<<<1024, 256, 0, stream>>>(u1s, u2s, Ws, UCb);

  // A2 CSR into the dead u1s/u2s region (persistent for layers 1,2)
  build(A2_rows, A2_cols, A2_vals, NTOT, NNZ_A, ptrA2, cvA2);

  // ---------- layer loop ----------
  ushort* embCur = embA_bf;
  ushort* embNext = embB_bf;
  for (int l = 0; l < 3; ++l) {
    const int* pA = (l == 0) ? ptrA : ptrA2;
    const int2* cA = (l == 0) ? cvA : cvA2;

    k_spmm_fusedA2<<<4096, 256, 0, stream>>>(pA, cA, embCur, Wi, embNext, out);

    if (l == 1)  // false-logits slot 4 + table for layer 2
      k_dualS<<<2048, 256, 0, stream>>>(ptrS, cvS, NEGPa, Wc, w2, w1, fk_b,
                                        out_logits, 4, NEGPb);
    else if (l == 2)  // false-logits slot 5, no next table
      k_dualS<<<2048, 256, 0, stream>>>(ptrS, cvS, NEGPb, Wc, w2, w1, fk_b,
                                        out_logits, 5, (uint*)nullptr);

    hipMemsetAsync(sumsq, 0, sizeof(float), stream);
    k_users<<<1024, 256, 0, stream>>>(embNext, UCb, Ws, uraw, sumsq);
    k_users_acc<<<2048, 256, 0, stream>>>(uraw, sumsq, out);

    { ushort* t = embCur; embCur = embNext; embNext = t; }
  }

  k_scale<<<2048, 256, 0, stream>>>(out);
}

// Round 8
// 2559.809 us; speedup vs baseline: 1.1939x; 1.1939x over previous
//
#include <hip/hip_runtime.h>

#define NU 100000
#define NI 150000
#define NTOT 250000
#define DD 64
#define NNZ_A 2000000
#define NNZ_S 800000
#define SCAN_CHUNK 2048  // 256 threads x 8

typedef unsigned int uint;
typedef unsigned short ushort;

// ================= helpers =================
#define RDLANE_F(x, k) __uint_as_float(__builtin_amdgcn_readlane(__float_as_uint(x), (unsigned)(k)))
#define RDLANE_I(x, k) ((int)__builtin_amdgcn_readlane((unsigned)(x), (unsigned)(k)))

__device__ __forceinline__ uint f2bf_bits(float x) {  // RNE round to bf16 (upper 16)
  uint a = __float_as_uint(x);
  return (a + 0x7fffu + ((a >> 16) & 1u)) >> 16;
}
__device__ __forceinline__ ushort f2bf(float x) { return (ushort)f2bf_bits(x); }
__device__ __forceinline__ float bf2f(ushort h) { return __uint_as_float(((uint)h) << 16); }
__device__ __forceinline__ uint pack_bf16x2(float lo, float hi) {
  return f2bf_bits(lo) | (f2bf_bits(hi) << 16);
}
__device__ __forceinline__ float unpk_lo(uint p) { return __uint_as_float(p << 16); }
__device__ __forceinline__ float unpk_hi(uint p) { return __uint_as_float(p & 0xffff0000u); }

// ---- 64x64 GEMM, transposed-W LDS form. Wt[k*65 + j] = W[j][k].
// One ds_read_b32 per k SHARED by all chains; lanes stride-1 over banks
// (2 lanes/bank = free). NO per-lane w[64] array -> no scratch spill.
__device__ __forceinline__ void gemm64x2_lds(float aA, float aB,
                                             const float* __restrict__ Wt, int lane,
                                             float& oA, float& oB) {
  oA = 0.f; oB = 0.f;
#pragma unroll
  for (int k = 0; k < 64; ++k) {
    float wk = Wt[k * 65 + lane];
    oA = fmaf(RDLANE_F(aA, k), wk, oA);
    oB = fmaf(RDLANE_F(aB, k), wk, oB);
  }
}

__device__ __forceinline__ void gemm64x4_lds(float a1, float a2, float a3, float a4,
                                             const float* __restrict__ Wt, int lane,
                                             float& o1, float& o2, float& o3, float& o4) {
  o1 = 0.f; o2 = 0.f; o3 = 0.f; o4 = 0.f;
#pragma unroll
  for (int k = 0; k < 64; ++k) {
    float wk = Wt[k * 65 + lane];
    o1 = fmaf(RDLANE_F(a1, k), wk, o1);
    o2 = fmaf(RDLANE_F(a2, k), wk, o2);
    o3 = fmaf(RDLANE_F(a3, k), wk, o3);
    o4 = fmaf(RDLANE_F(a4, k), wk, o4);
  }
}

// stage Wt[k*65+j] = W[j][k] from row-major W[j*64+k]
__device__ __forceinline__ void stage_wt(const float* __restrict__ W, float* __restrict__ Wt) {
  for (int idx = threadIdx.x; idx < 64 * 64; idx += blockDim.x)
    Wt[(idx & 63) * 65 + (idx >> 6)] = W[idx];
  __syncthreads();
}

// ---------- init: all_emb_bf16 = [(u1+u2)/2 ; item]; out = same (fp32) ----------
__global__ void k_init(const float* __restrict__ u1, const float* __restrict__ u2,
                       const float* __restrict__ item, ushort* __restrict__ emb_bf,
                       float* __restrict__ out_final) {
  int idx = blockIdx.x * blockDim.x + threadIdx.x;
  const int tot = NTOT * DD;
  const int nu = NU * DD;
  for (; idx < tot; idx += gridDim.x * blockDim.x) {
    float v;
    if (idx < nu) v = 0.5f * (u1[idx] + u2[idx]);
    else          v = item[idx - nu];
    emb_bf[idx] = f2bf(v);
    out_final[idx] = v;
  }
}

// ================= CSR build (counting sort) =================
__global__ void k_hist(const int* __restrict__ rows, int* __restrict__ cnt, int nnz) {
  int idx = blockIdx.x * blockDim.x + threadIdx.x;
  for (; idx < nnz; idx += gridDim.x * blockDim.x)
    atomicAdd(&cnt[rows[idx]], 1);
}

__global__ void k_scan1(const int* __restrict__ cnt, int* __restrict__ bsum, int n) {
  __shared__ int sdata[256];
  int base = blockIdx.x * SCAN_CHUNK;
  int s = 0;
#pragma unroll
  for (int k = 0; k < 8; ++k) {
    int i = base + threadIdx.x * 8 + k;
    s += (i < n) ? cnt[i] : 0;
  }
  sdata[threadIdx.x] = s;
  __syncthreads();
  for (int off = 128; off > 0; off >>= 1) {
    if (threadIdx.x < off) sdata[threadIdx.x] += sdata[threadIdx.x + off];
    __syncthreads();
  }
  if (threadIdx.x == 0) bsum[blockIdx.x] = sdata[0];
}

__global__ void k_scan2(int* bsum, int nb) {
  __shared__ int sdata[256];
  int v = (threadIdx.x < nb) ? bsum[threadIdx.x] : 0;
  sdata[threadIdx.x] = v;
  __syncthreads();
  for (int off = 1; off < 256; off <<= 1) {
    int t = (threadIdx.x >= (unsigned)off) ? sdata[threadIdx.x - off] : 0;
    __syncthreads();
    sdata[threadIdx.x] += t;
    __syncthreads();
  }
  if (threadIdx.x < nb) bsum[threadIdx.x] = sdata[threadIdx.x] - v;
}

__global__ void k_scan3(const int* __restrict__ cnt, const int* __restrict__ bsum,
                        int* __restrict__ rowptr, int* __restrict__ cur, int n, int nnz) {
  __shared__ int sdata[256];
  int base = blockIdx.x * SCAN_CHUNK;
  int loc[8];
  int s = 0;
#pragma unroll
  for (int k = 0; k < 8; ++k) {
    int i = base + threadIdx.x * 8 + k;
    loc[k] = (i < n) ? cnt[i] : 0;
    s += loc[k];
  }
  sdata[threadIdx.x] = s;
  __syncthreads();
  for (int off = 1; off < 256; off <<= 1) {
    int t = (threadIdx.x >= (unsigned)off) ? sdata[threadIdx.x - off] : 0;
    __syncthreads();
    sdata[threadIdx.x] += t;
    __syncthreads();
  }
  int pre = bsum[blockIdx.x] + sdata[threadIdx.x] - s;
#pragma unroll
  for (int k = 0; k < 8; ++k) {
    int i = base + threadIdx.x * 8 + k;
    if (i < n) { rowptr[i] = pre; cur[i] = pre; pre += loc[k]; }
  }
  if (blockIdx.x == 0 && threadIdx.x == 0) rowptr[n] = nnz;
}

__global__ void k_scatter(const int* __restrict__ rows, const int* __restrict__ cols,
                          const float* __restrict__ vals, int* __restrict__ cur,
                          int2* __restrict__ cv, int nnz) {
  int idx = blockIdx.x * blockDim.x + threadIdx.x;
  for (; idx < nnz; idx += gridDim.x * blockDim.x) {
    int r = rows[idx];
    int p = atomicAdd(&cur[r], 1);
    cv[p] = make_int2(cols[idx], __float_as_int(vals[idx]));
  }
}

// ================= dense pre-transform =================
// SOCP[i] = pack(u1[i]@Wc.T, u2[i]@Wc.T); NEG0P[i] = pack(u1[s1[i]]@Wc.T, u2[s2[i]]@Wc.T)
__global__ void k_transform(const float* __restrict__ u1, const float* __restrict__ u2,
                            const int* __restrict__ s1, const int* __restrict__ s2,
                            const float* __restrict__ Wc, uint* __restrict__ SOCP,
                            uint* __restrict__ NEG0P) {
  __shared__ float Wt[64 * 65];
  stage_wt(Wc, Wt);
  int lane = threadIdx.x & 63;
  int wid = (blockIdx.x * blockDim.x + threadIdx.x) >> 6;
  int nw = (gridDim.x * blockDim.x) >> 6;
  for (int i = wid; i < NU; i += nw) {
    float a1 = u1[(size_t)i * DD + lane];
    float a2 = u2[(size_t)i * DD + lane];
    int g1 = s1[i], g2 = s2[i];
    float a3 = u1[(size_t)g1 * DD + lane];
    float a4 = u2[(size_t)g2 * DD + lane];
    float o1, o2, o3, o4;
    gemm64x4_lds(a1, a2, a3, a4, Wt, lane, o1, o2, o3, o4);
    SOCP[(size_t)i * DD + lane]  = pack_bf16x2(o1, o2);
    NEG0P[(size_t)i * DD + lane] = pack_bf16x2(o3, o4);
  }
}

// ================= gather kernels =================
// quad: gathers 2 packed tables (4 chains); tanh; writes 4 bf16 outputs +
// next-layer packed table (fused gemm on the neg pair).
__global__ void k_quadS(const int* __restrict__ rowptr, const int2* __restrict__ cv,
                        const uint* __restrict__ SOCP, const uint* __restrict__ NEG0P,
                        const float* __restrict__ Wc,
                        ushort* __restrict__ u1s, ushort* __restrict__ u2s,
                        ushort* __restrict__ n1o, ushort* __restrict__ n2o,
                        uint* __restrict__ NEGPa) {
  __shared__ float Wt[64 * 65];
  stage_wt(Wc, Wt);
  int lane = threadIdx.x & 63;
  int wid = (blockIdx.x * blockDim.x + threadIdx.x) >> 6;
  int nw = (gridDim.x * blockDim.x) >> 6;
  for (int r = wid; r < NU; r += nw) {
    int start = rowptr[r], end = rowptr[r + 1];
    float a1 = 0.f, a2 = 0.f, a3 = 0.f, a4 = 0.f;
    for (int p0 = start; p0 < end; p0 += 64) {
      int n = min(64, end - p0);
      int2 e = cv[p0 + (lane < n ? lane : 0)];
      for (int k = 0; k < n; k += 8) {
        uint q1[8], q2[8];
        float vv[8];
#pragma unroll
        for (int u = 0; u < 8; ++u) {
          int kk = k + u;
          int ks = min(kk, n - 1);
          int c = RDLANE_I(e.x, ks);
          vv[u] = (kk < n) ? RDLANE_F(__int_as_float(e.y), ks) : 0.f;
          q1[u] = SOCP[(size_t)c * DD + lane];
          q2[u] = NEG0P[(size_t)c * DD + lane];
        }
#pragma unroll
        for (int u = 0; u < 8; ++u) {
          a1 = fmaf(vv[u], unpk_lo(q1[u]), a1);
          a2 = fmaf(vv[u], unpk_hi(q1[u]), a2);
          a3 = fmaf(vv[u], unpk_lo(q2[u]), a3);
          a4 = fmaf(vv[u], unpk_hi(q2[u]), a4);
        }
      }
    }
    float t1 = tanhf(a1), t2 = tanhf(a2), t3 = tanhf(a3), t4 = tanhf(a4);
    u1s[(size_t)r * DD + lane] = f2bf(t1);
    u2s[(size_t)r * DD + lane] = f2bf(t2);
    n1o[(size_t)r * DD + lane] = f2bf(t3);
    n2o[(size_t)r * DD + lane] = f2bf(t4);
    float o3, o4;
    gemm64x2_lds(t3, t4, Wt, lane, o3, o4);  // pre-transform layer-0 negs for layer-1
    NEGPa[(size_t)r * DD + lane] = pack_bf16x2(o3, o4);
  }
}

// dual: gathers 1 packed table; tanh; fused false-logits; optional next-table.
__global__ void k_dualS(const int* __restrict__ rowptr, const int2* __restrict__ cv,
                        const uint* __restrict__ T, const float* __restrict__ Wc,
                        const float* __restrict__ wva, const float* __restrict__ wvb,
                        const float* __restrict__ fkb, float* __restrict__ out_logits,
                        int slot, uint* __restrict__ Tnext) {
  __shared__ float Wt[64 * 65];
  stage_wt(Wc, Wt);
  int lane = threadIdx.x & 63;
  int wid = (blockIdx.x * blockDim.x + threadIdx.x) >> 6;
  int nw = (gridDim.x * blockDim.x) >> 6;
  float b = fkb[0];
  float wa = wva[lane], wb = wvb[lane];
  for (int r = wid; r < NU; r += nw) {
    int start = rowptr[r], end = rowptr[r + 1];
    float accA = 0.f, accB = 0.f;
    for (int p0 = start; p0 < end; p0 += 64) {
      int n = min(64, end - p0);
      int2 e = cv[p0 + (lane < n ? lane : 0)];
      for (int k = 0; k < n; k += 8) {
        uint q[8];
        float vv[8];
#pragma unroll
        for (int u = 0; u < 8; ++u) {
          int kk = k + u;
          int ks = min(kk, n - 1);
          int c = RDLANE_I(e.x, ks);
          vv[u] = (kk < n) ? RDLANE_F(__int_as_float(e.y), ks) : 0.f;
          q[u] = T[(size_t)c * DD + lane];
        }
#pragma unroll
        for (int u = 0; u < 8; ++u) {
          accA = fmaf(vv[u], unpk_lo(q[u]), accA);
          accB = fmaf(vv[u], unpk_hi(q[u]), accB);
        }
      }
    }
    float ta = tanhf(accA), tb = tanhf(accB);
    float pa = ta * wa, pb = tb * wb;
#pragma unroll
    for (int off = 32; off > 0; off >>= 1) {
      pa += __shfl_xor(pa, off);
      pb += __shfl_xor(pb, off);
    }
    if (lane == 0) {
      out_logits[(size_t)(NU + r) * 6 + slot] = pa + b;  // sc4: u1_neg chain
      out_logits[(size_t)r * 6 + slot] = pb + b;          // sc3: u2_neg chain
    }
    if (Tnext) {
      float oa, ob;
      gemm64x2_lds(ta, tb, Wt, lane, oa, ob);
      Tnext[(size_t)r * DD + lane] = pack_bf16x2(oa, ob);
    }
  }
}

// A-type, bf16 table, 2 rows per wave.
__global__ void k_spmm_fusedA2(const int* __restrict__ rowptr, const int2* __restrict__ cv,
                               const ushort* __restrict__ X, const float* __restrict__ W,
                               ushort* __restrict__ embNext, float* __restrict__ outF) {
  __shared__ float Wt[64 * 65];
  stage_wt(W, Wt);
  int lane = threadIdx.x & 63;
  int wid = (blockIdx.x * blockDim.x + threadIdx.x) >> 6;
  int nw = (gridDim.x * blockDim.x) >> 6;
  for (int r = wid * 2; r < NTOT; r += nw * 2) {
    int sA = rowptr[r], m = rowptr[r + 1], eB = rowptr[r + 2];
    float accA = 0.f, accB = 0.f;
    for (int pA = sA, pB = m; pA < m || pB < eB; pA += 64, pB += 64) {
      int nA = (pA < m) ? min(64, m - pA) : 0;
      int nB = (pB < eB) ? min(64, eB - pB) : 0;
      int2 eAv = cv[(nA ? pA : 0) + (lane < nA ? lane : 0)];
      int2 eBv = cv[(nB ? pB : 0) + (lane < nB ? lane : 0)];
      int kmax = max(nA, nB);
      for (int k = 0; k < kmax; k += 8) {
        uint hA[8], hB[8];
        float vA[8], vB[8];
#pragma unroll
        for (int u = 0; u < 8; ++u) {
          int kk = k + u;
          int ksA = min(kk, max(nA - 1, 0));
          int ksB = min(kk, max(nB - 1, 0));
          int cA = RDLANE_I(eAv.x, ksA);
          int cB = RDLANE_I(eBv.x, ksB);
          vA[u] = (kk < nA) ? RDLANE_F(__int_as_float(eAv.y), ksA) : 0.f;
          vB[u] = (kk < nB) ? RDLANE_F(__int_as_float(eBv.y), ksB) : 0.f;
          hA[u] = X[(size_t)cA * DD + lane];
          hB[u] = X[(size_t)cB * DD + lane];
        }
#pragma unroll
        for (int u = 0; u < 8; ++u) {
          accA = fmaf(vA[u], __uint_as_float(hA[u] << 16), accA);
          accB = fmaf(vB[u], __uint_as_float(hB[u] << 16), accB);
        }
      }
    }
    if (r < NU) {  // NU even: pair never straddles
      float oA, oB;
      gemm64x2_lds(accA, accB, Wt, lane, oA, oB);
      embNext[(size_t)r * DD + lane] = f2bf(tanhf(oA));
      embNext[(size_t)(r + 1) * DD + lane] = f2bf(tanhf(oB));
    } else {
      embNext[(size_t)r * DD + lane] = f2bf(accA);
      embNext[(size_t)(r + 1) * DD + lane] = f2bf(accB);
      outF[(size_t)r * DD + lane] += accA;
      outF[(size_t)(r + 1) * DD + lane] += accB;
    }
  }
}

// ---------- fused column sums (bf16 inputs) ----------
__global__ void k_colsum2(const ushort* __restrict__ x1, const ushort* __restrict__ x2,
                          float* __restrict__ c1, float* __restrict__ c2) {
  int lane = threadIdx.x & 63;
  int wid = (blockIdx.x * blockDim.x + threadIdx.x) >> 6;
  int nw = (gridDim.x * blockDim.x) >> 6;
  float a1 = 0.f, a2 = 0.f;
  for (int i = wid; i < NU; i += nw) {
    a1 += bf2f(x1[(size_t)i * DD + lane]);
    a2 += bf2f(x2[(size_t)i * DD + lane]);
  }
  atomicAdd(&c1[lane], a1);
  atomicAdd(&c2[lane], a2);
}

// ---------- w = fk_W @ (csum/NU) ----------
__global__ void k_wvec(const float* __restrict__ fkW, const float* __restrict__ c1r,
                       const float* __restrict__ c2r, float* __restrict__ w1,
                       float* __restrict__ w2) {
  int j = threadIdx.x;
  float a1 = 0.f, a2 = 0.f;
  for (int k = 0; k < 64; ++k) {
    float w = fkW[j * 64 + k];
    a1 += w * c1r[k];
    a2 += w * c2r[k];
  }
  w1[j] = a1 * (1.0f / NU);
  w2[j] = a2 * (1.0f / NU);
}

// ---------- logits: true slots 0-2 + false slot 3 (layer-0 negs) ----------
__global__ void k_logits4(const ushort* __restrict__ u1s, const ushort* __restrict__ u2s,
                          const ushort* __restrict__ n1o, const ushort* __restrict__ n2o,
                          const float* __restrict__ w1, const float* __restrict__ w2,
                          const float* __restrict__ fkb, float* __restrict__ out_logits) {
  int lane = threadIdx.x & 63;
  int wid = (blockIdx.x * blockDim.x + threadIdx.x) >> 6;
  int nw = (gridDim.x * blockDim.x) >> 6;
  float b = fkb[0];
  for (int i = wid; i < 2 * NU; i += nw) {
    bool lo = i < NU;
    int r = lo ? i : i - NU;
    const ushort* xs = lo ? u2s : u1s;
    const ushort* xn = lo ? n2o : n1o;
    const float* wv = lo ? w1 : w2;
    float wvl = wv[lane];
    float ps = bf2f(xs[(size_t)r * DD + lane]) * wvl;
    float pn = bf2f(xn[(size_t)r * DD + lane]) * wvl;
#pragma unroll
    for (int off = 32; off > 0; off >>= 1) {
      ps += __shfl_xor(ps, off);
      pn += __shfl_xor(pn, off);
    }
    if (lane == 0) {
      float vs = ps + b;
      out_logits[(size_t)i * 6 + 0] = vs;
      out_logits[(size_t)i * 6 + 1] = vs;
      out_logits[(size_t)i * 6 + 2] = vs;
      out_logits[(size_t)i * 6 + 3] = pn + b;
    }
  }
}

// ---------- UC[i] = (0.5*(u1s+u2s)) @ Ws[:,64:].T -> bf16 ----------
__global__ void k_comb_gemm(const ushort* __restrict__ u1s, const ushort* __restrict__ u2s,
                            const float* __restrict__ Ws, ushort* __restrict__ UC) {
  __shared__ float Wt[64 * 65];
  for (int idx = threadIdx.x; idx < 64 * 64; idx += blockDim.x)
    Wt[(idx & 63) * 65 + (idx >> 6)] = Ws[(idx >> 6) * 128 + 64 + (idx & 63)];
  __syncthreads();
  int lane = threadIdx.x & 63;
  int wid = (blockIdx.x * blockDim.x + threadIdx.x) >> 6;
  int nw = (gridDim.x * blockDim.x) >> 6;
  for (int i = wid; i < NU; i += nw) {
    float c = 0.5f * (bf2f(u1s[(size_t)i * DD + lane]) + bf2f(u2s[(size_t)i * DD + lane]));
    float o = 0.f;
#pragma unroll
    for (int k = 0; k < 64; ++k)
      o = fmaf(RDLANE_F(c, k), Wt[k * 65 + lane], o);
    UC[(size_t)i * DD + lane] = f2bf(o);
  }
}

// ---------- users_raw = u_next @ Ws[:,:64].T + UC ; sum of squares ----------
__global__ void k_users(const ushort* __restrict__ u_next, const ushort* __restrict__ uc,
                        const float* __restrict__ Ws, float* __restrict__ users_raw,
                        float* __restrict__ sumsq) {
  __shared__ float Wt[64 * 65];
  for (int idx = threadIdx.x; idx < 64 * 64; idx += blockDim.x)
    Wt[(idx & 63) * 65 + (idx >> 6)] = Ws[(idx >> 6) * 128 + (idx & 63)];
  __syncthreads();
  int lane = threadIdx.x & 63;
  int wid = (blockIdx.x * blockDim.x + threadIdx.x) >> 6;
  int nw = (gridDim.x * blockDim.x) >> 6;
  float ss = 0.f;
  for (int i = wid; i < NU; i += nw) {
    float va = bf2f(u_next[(size_t)i * DD + lane]);
    float acc = bf2f(uc[(size_t)i * DD + lane]);
#pragma unroll
    for (int k = 0; k < 64; ++k)
      acc = fmaf(RDLANE_F(va, k), Wt[k * 65 + lane], acc);
    users_raw[(size_t)i * DD + lane] = acc;
    ss += acc * acc;
  }
#pragma unroll
  for (int off = 32; off > 0; off >>= 1) ss += __shfl_xor(ss, off);
  if (lane == 0) atomicAdd(sumsq, ss);
}

__global__ void k_users_acc(const float* __restrict__ users_raw,
                            const float* __restrict__ sumsq, float* __restrict__ out_final) {
  float scale = 1.0f / sqrtf(*sumsq);
  int idx = blockIdx.x * blockDim.x + threadIdx.x;
  for (; idx < NU * DD; idx += gridDim.x * blockDim.x)
    out_final[idx] += users_raw[idx] * scale;
}

__global__ void k_scale(float* __restrict__ out_final) {
  int idx = blockIdx.x * blockDim.x + threadIdx.x;
  const int tot = NTOT * DD;
  for (; idx < tot; idx += gridDim.x * blockDim.x) out_final[idx] *= 0.25f;
}

extern "C" void kernel_launch(void* const* d_in, const int* in_sizes, int n_in,
                              void* d_out, int out_size, void* d_ws, size_t ws_size,
                              hipStream_t stream) {
  const float* u1      = (const float*)d_in[0];
  const float* u2      = (const float*)d_in[1];
  const float* item    = (const float*)d_in[2];
  const float* Wi      = (const float*)d_in[3];
  const float* Wc      = (const float*)d_in[4];
  const float* Ws      = (const float*)d_in[5];
  const float* fk_W    = (const float*)d_in[6];
  const float* fk_b    = (const float*)d_in[7];
  const float* A_vals  = (const float*)d_in[8];
  const float* A2_vals = (const float*)d_in[9];
  const float* S_vals  = (const float*)d_in[10];
  const int*   A_rows  = (const int*)d_in[11];
  const int*   A_cols  = (const int*)d_in[12];
  const int*   A2_rows = (const int*)d_in[13];
  const int*   A2_cols = (const int*)d_in[14];
  const int*   S_rows  = (const int*)d_in[15];
  const int*   S_cols  = (const int*)d_in[16];
  const int*   sh1     = (const int*)d_in[17];
  const int*   sh2     = (const int*)d_in[18];

  // ---- workspace layout (float offsets), total ~54.2M floats = 216.8MB ----
  float* ws = (float*)d_ws;
  ushort* embA_bf = (ushort*)ws;                   // [0, 8M)   16M ushorts
  ushort* embB_bf = (ushort*)(ws + 8000000);       // [8M, 16M)
  uint*   SOCP    = (uint*)(ws + 16000000);        // [16M, 22.4M)  dead after quad
  uint*   NEGPb   = SOCP;                          //   overlay: written at l=1 dual
  uint*   NEG0P   = (uint*)(ws + 22400000);        // [22.4M, 28.8M) dead after quad
  float*  uraw    = ws + 22400000;                 //   overlay: fp32 users scratch
  uint*   NEGPa   = (uint*)(ws + 28800000);        // [28.8M, 35.2M)
  ushort* u1s     = (ushort*)(ws + 35200000);      // [35.2M, 38.4M) dead after comb
  ushort* u2s     = (ushort*)(ws + 38400000);      // [38.4M, 41.6M) dead after comb
  int2*   cvA2    = (int2*)(ws + 35200000);        //   overlay: built after comb
  int*    ptrA2   = (int*)(ws + 39200000);         //   overlay (inside u2s region)
  ushort* n1o     = (ushort*)(ws + 41600000);      // [41.6M, 44.8M) dead after logits4
  ushort* UCb     = (ushort*)(ws + 41600000);      //   overlay: written by comb_gemm
  ushort* n2o     = (ushort*)(ws + 44800000);      // [44.8M, 48M)   dead after logits4
  int2*   cvA     = (int2*)(ws + 48000000);        // [48M, 52M)
  int2*   cvS     = (int2*)(ws + 52000000);        // [52M, 53.6M)
  int*    ptrA    = (int*)(ws + 53600000);         // 250001
  int*    ptrS    = ptrA + (NTOT + 1);             // 100001
  int*    cur     = ptrS + (NU + 1);               // 250000
  int*    bsum    = cur + NTOT;                    // 256
  float*  c1r     = (float*)(bsum + 256);          // 64
  float*  c2r     = c1r + 64;
  float*  w1      = c2r + 64;
  float*  w2      = w1 + 64;
  float*  sumsq   = w2 + 64;                       // 1

  float* out        = (float*)d_out;
  float* out_logits = out + (size_t)NTOT * DD;

  auto build = [&](const int* rows, const int* cols, const float* vals,
                   int n, int nnz, int* ptr, int2* cv) {
    int nb = (n + SCAN_CHUNK - 1) / SCAN_CHUNK;
    hipMemsetAsync(cur, 0, (size_t)n * sizeof(int), stream);
    k_hist<<<2048, 256, 0, stream>>>(rows, cur, nnz);
    k_scan1<<<nb, 256, 0, stream>>>(cur, bsum, n);
    k_scan2<<<1, 256, 0, stream>>>(bsum, nb);
    k_scan3<<<nb, 256, 0, stream>>>(cur, bsum, ptr, cur, n, nnz);
    k_scatter<<<2048, 256, 0, stream>>>(rows, cols, vals, cur, cv, nnz);
  };

  // ---------- CSR builds (S, A) ----------
  build(S_rows, S_cols, S_vals, NU, NNZ_S, ptrS, cvS);
  build(A_rows, A_cols, A_vals, NTOT, NNZ_A, ptrA, cvA);

  // ---------- init + pre-transform ----------
  hipMemsetAsync(c1r, 0, 128 * sizeof(float), stream);
  k_init<<<2048, 256, 0, stream>>>(u1, u2, item, embA_bf, out);
  k_transform<<<2048, 256, 0, stream>>>(u1, u2, sh1, sh2, Wc, SOCP, NEG0P);

  // ---------- quad gather: socials + layer-0 negs + layer-1 table ----------
  k_quadS<<<2048, 256, 0, stream>>>(ptrS, cvS, SOCP, NEG0P, Wc,
                                    u1s, u2s, n1o, n2o, NEGPa);
  k_colsum2<<<256, 256, 0, stream>>>(u1s, u2s, c1r, c2r);
  k_wvec<<<1, 64, 0, stream>>>(fk_W, c1r, c2r, w1, w2);
  k_logits4<<<1024, 256, 0, stream>>>(u1s, u2s, n1o, n2o, w1, w2, fk_b, out_logits);
  k_comb_gemm<<<1024, 256, 0, stream>>>(u1s, u2s, Ws, UCb);

  // A2 CSR into the dead u1s/u2s region (persistent for layers 1,2)
  build(A2_rows, A2_cols, A2_vals, NTOT, NNZ_A, ptrA2, cvA2);

  // ---------- layer loop ----------
  ushort* embCur = embA_bf;
  ushort* embNext = embB_bf;
  for (int l = 0; l < 3; ++l) {
    const int* pA = (l == 0) ? ptrA : ptrA2;
    const int2* cA = (l == 0) ? cvA : cvA2;

    k_spmm_fusedA2<<<4096, 256, 0, stream>>>(pA, cA, embCur, Wi, embNext, out);

    if (l == 1)  // false-logits slot 4 + table for layer 2
      k_dualS<<<2048, 256, 0, stream>>>(ptrS, cvS, NEGPa, Wc, w2, w1, fk_b,
                                        out_logits, 4, NEGPb);
    else if (l == 2)  // false-logits slot 5, no next table
      k_dualS<<<2048, 256, 0, stream>>>(ptrS, cvS, NEGPb, Wc, w2, w1, fk_b,
                                        out_logits, 5, (uint*)nullptr);

    hipMemsetAsync(sumsq, 0, sizeof(float), stream);
    k_users<<<1024, 256, 0, stream>>>(embNext, UCb, Ws, uraw, sumsq);
    k_users_acc<<<2048, 256, 0, stream>>>(uraw, sumsq, out);

    { ushort* t = embCur; embCur = embNext; embNext = t; }
  }

  k_scale<<<2048, 256, 0, stream>>>(out);
}

// Round 9
// 1845.590 us; speedup vs baseline: 1.6559x; 1.3870x over previous
//
#include <hip/hip_runtime.h>

#define NU 100000
#define NI 150000
#define NTOT 250000
#define DD 64
#define NNZ_A 2000000
#define NNZ_S 800000
#define SCAN_CHUNK 2048  // 256 threads x 8

typedef unsigned int uint;
typedef unsigned short ushort;

// launch bounds for gemm-style kernels: 256 threads, >=4 waves/EU -> 128 VGPR
// budget, no compiler low-cap (the R7/R8 scratch-spill fix, part 1)
#define LB __launch_bounds__(256, 4)

// ================= helpers =================
#define RDLANE_F(x, k) __uint_as_float(__builtin_amdgcn_readlane(__float_as_uint(x), (unsigned)(k)))
#define RDLANE_I(x, k) ((int)__builtin_amdgcn_readlane((unsigned)(x), (unsigned)(k)))

__device__ __forceinline__ uint f2bf_bits(float x) {  // RNE round to bf16 (upper 16)
  uint a = __float_as_uint(x);
  return (a + 0x7fffu + ((a >> 16) & 1u)) >> 16;
}
__device__ __forceinline__ ushort f2bf(float x) { return (ushort)f2bf_bits(x); }
__device__ __forceinline__ float bf2f(ushort h) { return __uint_as_float(((uint)h) << 16); }
__device__ __forceinline__ uint pack_bf16x2(float lo, float hi) {
  return f2bf_bits(lo) | (f2bf_bits(hi) << 16);
}
__device__ __forceinline__ float unpk_lo(uint p) { return __uint_as_float(p << 16); }
__device__ __forceinline__ float unpk_hi(uint p) { return __uint_as_float(p & 0xffff0000u); }

// ---- 64x64 GEMM, transposed-W LDS form. Wt[k*65 + j] = W[j][k].
// unroll 16 (NOT 64): bounds live ds_read results to <=16 VGPRs so the
// scheduler can't hoist 64 independent LDS reads -> no spill (fix, part 2)
__device__ __forceinline__ void gemm64x2_lds(float aA, float aB,
                                             const float* __restrict__ Wt, int lane,
                                             float& oA, float& oB) {
  oA = 0.f; oB = 0.f;
#pragma unroll 16
  for (int k = 0; k < 64; ++k) {
    float wk = Wt[k * 65 + lane];
    oA = fmaf(RDLANE_F(aA, k), wk, oA);
    oB = fmaf(RDLANE_F(aB, k), wk, oB);
  }
}

__device__ __forceinline__ void gemm64x4_lds(float a1, float a2, float a3, float a4,
                                             const float* __restrict__ Wt, int lane,
                                             float& o1, float& o2, float& o3, float& o4) {
  o1 = 0.f; o2 = 0.f; o3 = 0.f; o4 = 0.f;
#pragma unroll 16
  for (int k = 0; k < 64; ++k) {
    float wk = Wt[k * 65 + lane];
    o1 = fmaf(RDLANE_F(a1, k), wk, o1);
    o2 = fmaf(RDLANE_F(a2, k), wk, o2);
    o3 = fmaf(RDLANE_F(a3, k), wk, o3);
    o4 = fmaf(RDLANE_F(a4, k), wk, o4);
  }
}

// stage Wt[k*65+j] = W[j][k] from row-major W[j*64+k]
__device__ __forceinline__ void stage_wt(const float* __restrict__ W, float* __restrict__ Wt) {
  for (int idx = threadIdx.x; idx < 64 * 64; idx += blockDim.x)
    Wt[(idx & 63) * 65 + (idx >> 6)] = W[idx];
  __syncthreads();
}

// ---------- init: all_emb_bf16 = [(u1+u2)/2 ; item]; out = same (fp32) ----------
__global__ void k_init(const float* __restrict__ u1, const float* __restrict__ u2,
                       const float* __restrict__ item, ushort* __restrict__ emb_bf,
                       float* __restrict__ out_final) {
  int idx = blockIdx.x * blockDim.x + threadIdx.x;
  const int tot = NTOT * DD;
  const int nu = NU * DD;
  for (; idx < tot; idx += gridDim.x * blockDim.x) {
    float v;
    if (idx < nu) v = 0.5f * (u1[idx] + u2[idx]);
    else          v = item[idx - nu];
    emb_bf[idx] = f2bf(v);
    out_final[idx] = v;
  }
}

// ================= CSR build (counting sort) =================
__global__ void k_hist(const int* __restrict__ rows, int* __restrict__ cnt, int nnz) {
  int idx = blockIdx.x * blockDim.x + threadIdx.x;
  for (; idx < nnz; idx += gridDim.x * blockDim.x)
    atomicAdd(&cnt[rows[idx]], 1);
}

__global__ void k_scan1(const int* __restrict__ cnt, int* __restrict__ bsum, int n) {
  __shared__ int sdata[256];
  int base = blockIdx.x * SCAN_CHUNK;
  int s = 0;
#pragma unroll
  for (int k = 0; k < 8; ++k) {
    int i = base + threadIdx.x * 8 + k;
    s += (i < n) ? cnt[i] : 0;
  }
  sdata[threadIdx.x] = s;
  __syncthreads();
  for (int off = 128; off > 0; off >>= 1) {
    if (threadIdx.x < off) sdata[threadIdx.x] += sdata[threadIdx.x + off];
    __syncthreads();
  }
  if (threadIdx.x == 0) bsum[blockIdx.x] = sdata[0];
}

__global__ void k_scan2(int* bsum, int nb) {
  __shared__ int sdata[256];
  int v = (threadIdx.x < nb) ? bsum[threadIdx.x] : 0;
  sdata[threadIdx.x] = v;
  __syncthreads();
  for (int off = 1; off < 256; off <<= 1) {
    int t = (threadIdx.x >= (unsigned)off) ? sdata[threadIdx.x - off] : 0;
    __syncthreads();
    sdata[threadIdx.x] += t;
    __syncthreads();
  }
  if (threadIdx.x < nb) bsum[threadIdx.x] = sdata[threadIdx.x] - v;
}

__global__ void k_scan3(const int* __restrict__ cnt, const int* __restrict__ bsum,
                        int* __restrict__ rowptr, int* __restrict__ cur, int n, int nnz) {
  __shared__ int sdata[256];
  int base = blockIdx.x * SCAN_CHUNK;
  int loc[8];
  int s = 0;
#pragma unroll
  for (int k = 0; k < 8; ++k) {
    int i = base + threadIdx.x * 8 + k;
    loc[k] = (i < n) ? cnt[i] : 0;
    s += loc[k];
  }
  sdata[threadIdx.x] = s;
  __syncthreads();
  for (int off = 1; off < 256; off <<= 1) {
    int t = (threadIdx.x >= (unsigned)off) ? sdata[threadIdx.x - off] : 0;
    __syncthreads();
    sdata[threadIdx.x] += t;
    __syncthreads();
  }
  int pre = bsum[blockIdx.x] + sdata[threadIdx.x] - s;
#pragma unroll
  for (int k = 0; k < 8; ++k) {
    int i = base + threadIdx.x * 8 + k;
    if (i < n) { rowptr[i] = pre; cur[i] = pre; pre += loc[k]; }
  }
  if (blockIdx.x == 0 && threadIdx.x == 0) rowptr[n] = nnz;
}

__global__ void k_scatter(const int* __restrict__ rows, const int* __restrict__ cols,
                          const float* __restrict__ vals, int* __restrict__ cur,
                          int2* __restrict__ cv, int nnz) {
  int idx = blockIdx.x * blockDim.x + threadIdx.x;
  for (; idx < nnz; idx += gridDim.x * blockDim.x) {
    int r = rows[idx];
    int p = atomicAdd(&cur[r], 1);
    cv[p] = make_int2(cols[idx], __float_as_int(vals[idx]));
  }
}

// ================= dense pre-transform (split: fix, part 3) =================
// SOCP[i] = pack(u1[i]@Wc.T, u2[i]@Wc.T) — pure coalesced dense GEMM, 2 chains.
__global__ LB void k_transform(const float* __restrict__ u1, const float* __restrict__ u2,
                               const float* __restrict__ Wc, uint* __restrict__ SOCP) {
  __shared__ float Wt[64 * 65];
  stage_wt(Wc, Wt);
  int lane = threadIdx.x & 63;
  int wid = (blockIdx.x * blockDim.x + threadIdx.x) >> 6;
  int nw = (gridDim.x * blockDim.x) >> 6;
  for (int i = wid; i < NU; i += nw) {
    float a1 = u1[(size_t)i * DD + lane];
    float a2 = u2[(size_t)i * DD + lane];
    float o1, o2;
    gemm64x2_lds(a1, a2, Wt, lane, o1, o2);
    SOCP[(size_t)i * DD + lane] = pack_bf16x2(o1, o2);
  }
}

// NEG0P[i] = lo16(SOCP[s1[i]]) | hi16(SOCP[s2[i]]) — bit-identical to computing
// the transforms at permuted rows ((u1@W)[sh] == (u1[sh])@W).
__global__ void k_negmap(const uint* __restrict__ SOCP, const int* __restrict__ s1,
                         const int* __restrict__ s2, uint* __restrict__ NEG0P) {
  int idx = blockIdx.x * blockDim.x + threadIdx.x;
  const int tot = NU * DD;
  for (; idx < tot; idx += gridDim.x * blockDim.x) {
    int i = idx >> 6, j = idx & 63;
    uint lo = SOCP[(size_t)s1[i] * DD + j];
    uint hi = SOCP[(size_t)s2[i] * DD + j];
    NEG0P[idx] = (lo & 0xffffu) | (hi & 0xffff0000u);
  }
}

// ================= gather kernels =================
// quad: gathers 2 packed tables (4 chains); tanh; writes 4 bf16 outputs +
// next-layer packed table (fused gemm on the neg pair).
__global__ LB void k_quadS(const int* __restrict__ rowptr, const int2* __restrict__ cv,
                           const uint* __restrict__ SOCP, const uint* __restrict__ NEG0P,
                           const float* __restrict__ Wc,
                           ushort* __restrict__ u1s, ushort* __restrict__ u2s,
                           ushort* __restrict__ n1o, ushort* __restrict__ n2o,
                           uint* __restrict__ NEGPa) {
  __shared__ float Wt[64 * 65];
  stage_wt(Wc, Wt);
  int lane = threadIdx.x & 63;
  int wid = (blockIdx.x * blockDim.x + threadIdx.x) >> 6;
  int nw = (gridDim.x * blockDim.x) >> 6;
  for (int r = wid; r < NU; r += nw) {
    int start = rowptr[r], end = rowptr[r + 1];
    float a1 = 0.f, a2 = 0.f, a3 = 0.f, a4 = 0.f;
    for (int p0 = start; p0 < end; p0 += 64) {
      int n = min(64, end - p0);
      int2 e = cv[p0 + (lane < n ? lane : 0)];
      for (int k = 0; k < n; k += 8) {
        uint q1[8], q2[8];
        float vv[8];
#pragma unroll
        for (int u = 0; u < 8; ++u) {
          int kk = k + u;
          int ks = min(kk, n - 1);
          int c = RDLANE_I(e.x, ks);
          vv[u] = (kk < n) ? RDLANE_F(__int_as_float(e.y), ks) : 0.f;
          q1[u] = SOCP[(size_t)c * DD + lane];
          q2[u] = NEG0P[(size_t)c * DD + lane];
        }
#pragma unroll
        for (int u = 0; u < 8; ++u) {
          a1 = fmaf(vv[u], unpk_lo(q1[u]), a1);
          a2 = fmaf(vv[u], unpk_hi(q1[u]), a2);
          a3 = fmaf(vv[u], unpk_lo(q2[u]), a3);
          a4 = fmaf(vv[u], unpk_hi(q2[u]), a4);
        }
      }
    }
    float t1 = tanhf(a1), t2 = tanhf(a2), t3 = tanhf(a3), t4 = tanhf(a4);
    u1s[(size_t)r * DD + lane] = f2bf(t1);
    u2s[(size_t)r * DD + lane] = f2bf(t2);
    n1o[(size_t)r * DD + lane] = f2bf(t3);
    n2o[(size_t)r * DD + lane] = f2bf(t4);
    float o3, o4;
    gemm64x2_lds(t3, t4, Wt, lane, o3, o4);  // pre-transform layer-0 negs for layer-1
    NEGPa[(size_t)r * DD + lane] = pack_bf16x2(o3, o4);
  }
}

// dual: gathers 1 packed table; tanh; fused false-logits; optional next-table.
__global__ LB void k_dualS(const int* __restrict__ rowptr, const int2* __restrict__ cv,
                           const uint* __restrict__ T, const float* __restrict__ Wc,
                           const float* __restrict__ wva, const float* __restrict__ wvb,
                           const float* __restrict__ fkb, float* __restrict__ out_logits,
                           int slot, uint* __restrict__ Tnext) {
  __shared__ float Wt[64 * 65];
  stage_wt(Wc, Wt);
  int lane = threadIdx.x & 63;
  int wid = (blockIdx.x * blockDim.x + threadIdx.x) >> 6;
  int nw = (gridDim.x * blockDim.x) >> 6;
  float b = fkb[0];
  float wa = wva[lane], wb = wvb[lane];
  for (int r = wid; r < NU; r += nw) {
    int start = rowptr[r], end = rowptr[r + 1];
    float accA = 0.f, accB = 0.f;
    for (int p0 = start; p0 < end; p0 += 64) {
      int n = min(64, end - p0);
      int2 e = cv[p0 + (lane < n ? lane : 0)];
      for (int k = 0; k < n; k += 8) {
        uint q[8];
        float vv[8];
#pragma unroll
        for (int u = 0; u < 8; ++u) {
          int kk = k + u;
          int ks = min(kk, n - 1);
          int c = RDLANE_I(e.x, ks);
          vv[u] = (kk < n) ? RDLANE_F(__int_as_float(e.y), ks) : 0.f;
          q[u] = T[(size_t)c * DD + lane];
        }
#pragma unroll
        for (int u = 0; u < 8; ++u) {
          accA = fmaf(vv[u], unpk_lo(q[u]), accA);
          accB = fmaf(vv[u], unpk_hi(q[u]), accB);
        }
      }
    }
    float ta = tanhf(accA), tb = tanhf(accB);
    float pa = ta * wa, pb = tb * wb;
#pragma unroll
    for (int off = 32; off > 0; off >>= 1) {
      pa += __shfl_xor(pa, off);
      pb += __shfl_xor(pb, off);
    }
    if (lane == 0) {
      out_logits[(size_t)(NU + r) * 6 + slot] = pa + b;  // sc4: u1_neg chain
      out_logits[(size_t)r * 6 + slot] = pb + b;          // sc3: u2_neg chain
    }
    if (Tnext) {
      float oa, ob;
      gemm64x2_lds(ta, tb, Wt, lane, oa, ob);
      Tnext[(size_t)r * DD + lane] = pack_bf16x2(oa, ob);
    }
  }
}

// A-type, bf16 table, 2 rows per wave.
__global__ LB void k_spmm_fusedA2(const int* __restrict__ rowptr, const int2* __restrict__ cv,
                                  const ushort* __restrict__ X, const float* __restrict__ W,
                                  ushort* __restrict__ embNext, float* __restrict__ outF) {
  __shared__ float Wt[64 * 65];
  stage_wt(W, Wt);
  int lane = threadIdx.x & 63;
  int wid = (blockIdx.x * blockDim.x + threadIdx.x) >> 6;
  int nw = (gridDim.x * blockDim.x) >> 6;
  for (int r = wid * 2; r < NTOT; r += nw * 2) {
    int sA = rowptr[r], m = rowptr[r + 1], eB = rowptr[r + 2];
    float accA = 0.f, accB = 0.f;
    for (int pA = sA, pB = m; pA < m || pB < eB; pA += 64, pB += 64) {
      int nA = (pA < m) ? min(64, m - pA) : 0;
      int nB = (pB < eB) ? min(64, eB - pB) : 0;
      int2 eAv = cv[(nA ? pA : 0) + (lane < nA ? lane : 0)];
      int2 eBv = cv[(nB ? pB : 0) + (lane < nB ? lane : 0)];
      int kmax = max(nA, nB);
      for (int k = 0; k < kmax; k += 8) {
        uint hA[8], hB[8];
        float vA[8], vB[8];
#pragma unroll
        for (int u = 0; u < 8; ++u) {
          int kk = k + u;
          int ksA = min(kk, max(nA - 1, 0));
          int ksB = min(kk, max(nB - 1, 0));
          int cA = RDLANE_I(eAv.x, ksA);
          int cB = RDLANE_I(eBv.x, ksB);
          vA[u] = (kk < nA) ? RDLANE_F(__int_as_float(eAv.y), ksA) : 0.f;
          vB[u] = (kk < nB) ? RDLANE_F(__int_as_float(eBv.y), ksB) : 0.f;
          hA[u] = X[(size_t)cA * DD + lane];
          hB[u] = X[(size_t)cB * DD + lane];
        }
#pragma unroll
        for (int u = 0; u < 8; ++u) {
          accA = fmaf(vA[u], __uint_as_float(hA[u] << 16), accA);
          accB = fmaf(vB[u], __uint_as_float(hB[u] << 16), accB);
        }
      }
    }
    if (r < NU) {  // NU even: pair never straddles
      float oA, oB;
      gemm64x2_lds(accA, accB, Wt, lane, oA, oB);
      embNext[(size_t)r * DD + lane] = f2bf(tanhf(oA));
      embNext[(size_t)(r + 1) * DD + lane] = f2bf(tanhf(oB));
    } else {
      embNext[(size_t)r * DD + lane] = f2bf(accA);
      embNext[(size_t)(r + 1) * DD + lane] = f2bf(accB);
      outF[(size_t)r * DD + lane] += accA;
      outF[(size_t)(r + 1) * DD + lane] += accB;
    }
  }
}

// ---------- fused column sums (bf16 inputs) ----------
__global__ void k_colsum2(const ushort* __restrict__ x1, const ushort* __restrict__ x2,
                          float* __restrict__ c1, float* __restrict__ c2) {
  int lane = threadIdx.x & 63;
  int wid = (blockIdx.x * blockDim.x + threadIdx.x) >> 6;
  int nw = (gridDim.x * blockDim.x) >> 6;
  float a1 = 0.f, a2 = 0.f;
  for (int i = wid; i < NU; i += nw) {
    a1 += bf2f(x1[(size_t)i * DD + lane]);
    a2 += bf2f(x2[(size_t)i * DD + lane]);
  }
  atomicAdd(&c1[lane], a1);
  atomicAdd(&c2[lane], a2);
}

// ---------- w = fk_W @ (csum/NU) ----------
__global__ void k_wvec(const float* __restrict__ fkW, const float* __restrict__ c1r,
                       const float* __restrict__ c2r, float* __restrict__ w1,
                       float* __restrict__ w2) {
  int j = threadIdx.x;
  float a1 = 0.f, a2 = 0.f;
  for (int k = 0; k < 64; ++k) {
    float w = fkW[j * 64 + k];
    a1 += w * c1r[k];
    a2 += w * c2r[k];
  }
  w1[j] = a1 * (1.0f / NU);
  w2[j] = a2 * (1.0f / NU);
}

// ---------- logits: true slots 0-2 + false slot 3 (layer-0 negs) ----------
__global__ void k_logits4(const ushort* __restrict__ u1s, const ushort* __restrict__ u2s,
                          const ushort* __restrict__ n1o, const ushort* __restrict__ n2o,
                          const float* __restrict__ w1, const float* __restrict__ w2,
                          const float* __restrict__ fkb, float* __restrict__ out_logits) {
  int lane = threadIdx.x & 63;
  int wid = (blockIdx.x * blockDim.x + threadIdx.x) >> 6;
  int nw = (gridDim.x * blockDim.x) >> 6;
  float b = fkb[0];
  for (int i = wid; i < 2 * NU; i += nw) {
    bool lo = i < NU;
    int r = lo ? i : i - NU;
    const ushort* xs = lo ? u2s : u1s;
    const ushort* xn = lo ? n2o : n1o;
    const float* wv = lo ? w1 : w2;
    float wvl = wv[lane];
    float ps = bf2f(xs[(size_t)r * DD + lane]) * wvl;
    float pn = bf2f(xn[(size_t)r * DD + lane]) * wvl;
#pragma unroll
    for (int off = 32; off > 0; off >>= 1) {
      ps += __shfl_xor(ps, off);
      pn += __shfl_xor(pn, off);
    }
    if (lane == 0) {
      float vs = ps + b;
      out_logits[(size_t)i * 6 + 0] = vs;
      out_logits[(size_t)i * 6 + 1] = vs;
      out_logits[(size_t)i * 6 + 2] = vs;
      out_logits[(size_t)i * 6 + 3] = pn + b;
    }
  }
}

// ---------- UC[i] = (0.5*(u1s+u2s)) @ Ws[:,64:].T -> bf16 ----------
__global__ LB void k_comb_gemm(const ushort* __restrict__ u1s, const ushort* __restrict__ u2s,
                               const float* __restrict__ Ws, ushort* __restrict__ UC) {
  __shared__ float Wt[64 * 65];
  for (int idx = threadIdx.x; idx < 64 * 64; idx += blockDim.x)
    Wt[(idx & 63) * 65 + (idx >> 6)] = Ws[(idx >> 6) * 128 + 64 + (idx & 63)];
  __syncthreads();
  int lane = threadIdx.x & 63;
  int wid = (blockIdx.x * blockDim.x + threadIdx.x) >> 6;
  int nw = (gridDim.x * blockDim.x) >> 6;
  for (int i = wid; i < NU; i += nw) {
    float c = 0.5f * (bf2f(u1s[(size_t)i * DD + lane]) + bf2f(u2s[(size_t)i * DD + lane]));
    float o = 0.f;
#pragma unroll 16
    for (int k = 0; k < 64; ++k)
      o = fmaf(RDLANE_F(c, k), Wt[k * 65 + lane], o);
    UC[(size_t)i * DD + lane] = f2bf(o);
  }
}

// ---------- users_raw = u_next @ Ws[:,:64].T + UC ; sum of squares ----------
__global__ LB void k_users(const ushort* __restrict__ u_next, const ushort* __restrict__ uc,
                           const float* __restrict__ Ws, float* __restrict__ users_raw,
                           float* __restrict__ sumsq) {
  __shared__ float Wt[64 * 65];
  for (int idx = threadIdx.x; idx < 64 * 64; idx += blockDim.x)
    Wt[(idx & 63) * 65 + (idx >> 6)] = Ws[(idx >> 6) * 128 + (idx & 63)];
  __syncthreads();
  int lane = threadIdx.x & 63;
  int wid = (blockIdx.x * blockDim.x + threadIdx.x) >> 6;
  int nw = (gridDim.x * blockDim.x) >> 6;
  float ss = 0.f;
  for (int i = wid; i < NU; i += nw) {
    float va = bf2f(u_next[(size_t)i * DD + lane]);
    float acc = bf2f(uc[(size_t)i * DD + lane]);
#pragma unroll 16
    for (int k = 0; k < 64; ++k)
      acc = fmaf(RDLANE_F(va, k), Wt[k * 65 + lane], acc);
    users_raw[(size_t)i * DD + lane] = acc;
    ss += acc * acc;
  }
#pragma unroll
  for (int off = 32; off > 0; off >>= 1) ss += __shfl_xor(ss, off);
  if (lane == 0) atomicAdd(sumsq, ss);
}

__global__ void k_users_acc(const float* __restrict__ users_raw,
                            const float* __restrict__ sumsq, float* __restrict__ out_final) {
  float scale = 1.0f / sqrtf(*sumsq);
  int idx = blockIdx.x * blockDim.x + threadIdx.x;
  for (; idx < NU * DD; idx += gridDim.x * blockDim.x)
    out_final[idx] += users_raw[idx] * scale;
}

__global__ void k_scale(float* __restrict__ out_final) {
  int idx = blockIdx.x * blockDim.x + threadIdx.x;
  const int tot = NTOT * DD;
  for (; idx < tot; idx += gridDim.x * blockDim.x) out_final[idx] *= 0.25f;
}

extern "C" void kernel_launch(void* const* d_in, const int* in_sizes, int n_in,
                              void* d_out, int out_size, void* d_ws, size_t ws_size,
                              hipStream_t stream) {
  const float* u1      = (const float*)d_in[0];
  const float* u2      = (const float*)d_in[1];
  const float* item    = (const float*)d_in[2];
  const float* Wi      = (const float*)d_in[3];
  const float* Wc      = (const float*)d_in[4];
  const float* Ws      = (const float*)d_in[5];
  const float* fk_W    = (const float*)d_in[6];
  const float* fk_b    = (const float*)d_in[7];
  const float* A_vals  = (const float*)d_in[8];
  const float* A2_vals = (const float*)d_in[9];
  const float* S_vals  = (const float*)d_in[10];
  const int*   A_rows  = (const int*)d_in[11];
  const int*   A_cols  = (const int*)d_in[12];
  const int*   A2_rows = (const int*)d_in[13];
  const int*   A2_cols = (const int*)d_in[14];
  const int*   S_rows  = (const int*)d_in[15];
  const int*   S_cols  = (const int*)d_in[16];
  const int*   sh1     = (const int*)d_in[17];
  const int*   sh2     = (const int*)d_in[18];

  // ---- workspace layout (float offsets), total ~54.2M floats = 216.8MB ----
  float* ws = (float*)d_ws;
  ushort* embA_bf = (ushort*)ws;                   // [0, 8M)   16M ushorts
  ushort* embB_bf = (ushort*)(ws + 8000000);       // [8M, 16M)
  uint*   SOCP    = (uint*)(ws + 16000000);        // [16M, 22.4M)  dead after quad
  uint*   NEGPb   = SOCP;                          //   overlay: written at l=1 dual
  uint*   NEG0P   = (uint*)(ws + 22400000);        // [22.4M, 28.8M) dead after quad
  float*  uraw    = ws + 22400000;                 //   overlay: fp32 users scratch
  uint*   NEGPa   = (uint*)(ws + 28800000);        // [28.8M, 35.2M)
  ushort* u1s     = (ushort*)(ws + 35200000);      // [35.2M, 38.4M) dead after comb
  ushort* u2s     = (ushort*)(ws + 38400000);      // [38.4M, 41.6M) dead after comb
  int2*   cvA2    = (int2*)(ws + 35200000);        //   overlay: built after comb
  int*    ptrA2   = (int*)(ws + 39200000);         //   overlay (inside u2s region)
  ushort* n1o     = (ushort*)(ws + 41600000);      // [41.6M, 44.8M) dead after logits4
  ushort* UCb     = (ushort*)(ws + 41600000);      //   overlay: written by comb_gemm
  ushort* n2o     = (ushort*)(ws + 44800000);      // [44.8M, 48M)   dead after logits4
  int2*   cvA     = (int2*)(ws + 48000000);        // [48M, 52M)
  int2*   cvS     = (int2*)(ws + 52000000);        // [52M, 53.6M)
  int*    ptrA    = (int*)(ws + 53600000);         // 250001
  int*    ptrS    = ptrA + (NTOT + 1);             // 100001
  int*    cur     = ptrS + (NU + 1);               // 250000
  int*    bsum    = cur + NTOT;                    // 256
  float*  c1r     = (float*)(bsum + 256);          // 64
  float*  c2r     = c1r + 64;
  float*  w1      = c2r + 64;
  float*  w2      = w1 + 64;
  float*  sumsq   = w2 + 64;                       // 1

  float* out        = (float*)d_out;
  float* out_logits = out + (size_t)NTOT * DD;

  auto build = [&](const int* rows, const int* cols, const float* vals,
                   int n, int nnz, int* ptr, int2* cv) {
    int nb = (n + SCAN_CHUNK - 1) / SCAN_CHUNK;
    hipMemsetAsync(cur, 0, (size_t)n * sizeof(int), stream);
    k_hist<<<2048, 256, 0, stream>>>(rows, cur, nnz);
    k_scan1<<<nb, 256, 0, stream>>>(cur, bsum, n);
    k_scan2<<<1, 256, 0, stream>>>(bsum, nb);
    k_scan3<<<nb, 256, 0, stream>>>(cur, bsum, ptr, cur, n, nnz);
    k_scatter<<<2048, 256, 0, stream>>>(rows, cols, vals, cur, cv, nnz);
  };

  // ---------- CSR builds (S, A) ----------
  build(S_rows, S_cols, S_vals, NU, NNZ_S, ptrS, cvS);
  build(A_rows, A_cols, A_vals, NTOT, NNZ_A, ptrA, cvA);

  // ---------- init + pre-transform (dense) + neg remap ----------
  hipMemsetAsync(c1r, 0, 128 * sizeof(float), stream);
  k_init<<<2048, 256, 0, stream>>>(u1, u2, item, embA_bf, out);
  k_transform<<<1024, 256, 0, stream>>>(u1, u2, Wc, SOCP);
  k_negmap<<<1024, 256, 0, stream>>>(SOCP, sh1, sh2, NEG0P);

  // ---------- quad gather: socials + layer-0 negs + layer-1 table ----------
  k_quadS<<<2048, 256, 0, stream>>>(ptrS, cvS, SOCP, NEG0P, Wc,
                                    u1s, u2s, n1o, n2o, NEGPa);
  k_colsum2<<<256, 256, 0, stream>>>(u1s, u2s, c1r, c2r);
  k_wvec<<<1, 64, 0, stream>>>(fk_W, c1r, c2r, w1, w2);
  k_logits4<<<1024, 256, 0, stream>>>(u1s, u2s, n1o, n2o, w1, w2, fk_b, out_logits);
  k_comb_gemm<<<1024, 256, 0, stream>>>(u1s, u2s, Ws, UCb);

  // A2 CSR into the dead u1s/u2s region (persistent for layers 1,2)
  build(A2_rows, A2_cols, A2_vals, NTOT, NNZ_A, ptrA2, cvA2);

  // ---------- layer loop ----------
  ushort* embCur = embA_bf;
  ushort* embNext = embB_bf;
  for (int l = 0; l < 3; ++l) {
    const int* pA = (l == 0) ? ptrA : ptrA2;
    const int2* cA = (l == 0) ? cvA : cvA2;

    k_spmm_fusedA2<<<4096, 256, 0, stream>>>(pA, cA, embCur, Wi, embNext, out);

    if (l == 1)  // false-logits slot 4 + table for layer 2
      k_dualS<<<2048, 256, 0, stream>>>(ptrS, cvS, NEGPa, Wc, w2, w1, fk_b,
                                        out_logits, 4, NEGPb);
    else if (l == 2)  // false-logits slot 5, no next table
      k_dualS<<<2048, 256, 0, stream>>>(ptrS, cvS, NEGPb, Wc, w2, w1, fk_b,
                                        out_logits, 5, (uint*)nullptr);

    hipMemsetAsync(sumsq, 0, sizeof(float), stream);
    k_users<<<1024, 256, 0, stream>>>(embNext, UCb, Ws, uraw, sumsq);
    k_users_acc<<<2048, 256, 0, stream>>>(uraw, sumsq, out);

    { ushort* t = embCur; embCur = embNext; embNext = t; }
  }

  k_scale<<<2048, 256, 0, stream>>>(out);
}

// Round 10
// 1688.169 us; speedup vs baseline: 1.8103x; 1.0932x over previous
//
#include <hip/hip_runtime.h>

#define NU 100000
#define NI 150000
#define NTOT 250000
#define DD 64
#define NNZ_A 2000000
#define NNZ_S 800000
#define SCAN_CHUNK 2048  // 256 threads x 8

typedef unsigned int uint;
typedef unsigned short ushort;

// launch bounds for gemm-style kernels: 256 threads, >=4 waves/EU -> 128 VGPR
#define LB __launch_bounds__(256, 4)

// ================= helpers =================
#define RDLANE_F(x, k) __uint_as_float(__builtin_amdgcn_readlane(__float_as_uint(x), (unsigned)(k)))
#define RDLANE_I(x, k) ((int)__builtin_amdgcn_readlane((unsigned)(x), (unsigned)(k)))

__device__ __forceinline__ uint f2bf_bits(float x) {  // RNE round to bf16 (upper 16)
  uint a = __float_as_uint(x);
  return (a + 0x7fffu + ((a >> 16) & 1u)) >> 16;
}
__device__ __forceinline__ ushort f2bf(float x) { return (ushort)f2bf_bits(x); }
__device__ __forceinline__ float bf2f(ushort h) { return __uint_as_float(((uint)h) << 16); }
__device__ __forceinline__ uint pack_bf16x2(float lo, float hi) {
  return f2bf_bits(lo) | (f2bf_bits(hi) << 16);
}
__device__ __forceinline__ float unpk_lo(uint p) { return __uint_as_float(p << 16); }
__device__ __forceinline__ float unpk_hi(uint p) { return __uint_as_float(p & 0xffff0000u); }

// ---- 64x64 GEMM, transposed-W LDS form. Wt[k*65 + j] = W[j][k].
// unroll 16: bounds live ds_read results -> no spill (R9 fix, kept)
__device__ __forceinline__ void gemm64x2_lds(float aA, float aB,
                                             const float* __restrict__ Wt, int lane,
                                             float& oA, float& oB) {
  oA = 0.f; oB = 0.f;
#pragma unroll 16
  for (int k = 0; k < 64; ++k) {
    float wk = Wt[k * 65 + lane];
    oA = fmaf(RDLANE_F(aA, k), wk, oA);
    oB = fmaf(RDLANE_F(aB, k), wk, oB);
  }
}

// stage Wt[k*65+j] = W[j][k] from row-major W[j*64+k]
__device__ __forceinline__ void stage_wt(const float* __restrict__ W, float* __restrict__ Wt) {
  for (int idx = threadIdx.x; idx < 64 * 64; idx += blockDim.x)
    Wt[(idx & 63) * 65 + (idx >> 6)] = W[idx];
  __syncthreads();
}

// ---------- init: all_emb_bf16 = [(u1+u2)/2 ; item]; out = same (fp32) ----------
__global__ void k_init(const float* __restrict__ u1, const float* __restrict__ u2,
                       const float* __restrict__ item, ushort* __restrict__ emb_bf,
                       float* __restrict__ out_final) {
  int idx = blockIdx.x * blockDim.x + threadIdx.x;
  const int tot = NTOT * DD;
  const int nu = NU * DD;
  for (; idx < tot; idx += gridDim.x * blockDim.x) {
    float v;
    if (idx < nu) v = 0.5f * (u1[idx] + u2[idx]);
    else          v = item[idx - nu];
    emb_bf[idx] = f2bf(v);
    out_final[idx] = v;
  }
}

// ================= CSR build (counting sort, rank-in-hist) =================
// hist + per-edge rank capture: the ONLY atomic pass. 8-deep MLP batching,
// stride-spaced so each u-step stays lane-coalesced.
__global__ void k_hist_rank(const int* __restrict__ rows, int* __restrict__ cnt,
                            int* __restrict__ rank, int nnz) {
  int tid = blockIdx.x * blockDim.x + threadIdx.x;
  int gsz = gridDim.x * blockDim.x;
  for (int b = tid; b < nnz; b += gsz * 8) {
#pragma unroll
    for (int u = 0; u < 8; ++u) {
      int i = b + u * gsz;
      if (i < nnz) rank[i] = atomicAdd(&cnt[rows[i]], 1);
    }
  }
}

__global__ void k_scan1(const int* __restrict__ cnt, int* __restrict__ bsum, int n) {
  __shared__ int sdata[256];
  int base = blockIdx.x * SCAN_CHUNK;
  int s = 0;
#pragma unroll
  for (int k = 0; k < 8; ++k) {
    int i = base + threadIdx.x * 8 + k;
    s += (i < n) ? cnt[i] : 0;
  }
  sdata[threadIdx.x] = s;
  __syncthreads();
  for (int off = 128; off > 0; off >>= 1) {
    if (threadIdx.x < off) sdata[threadIdx.x] += sdata[threadIdx.x + off];
    __syncthreads();
  }
  if (threadIdx.x == 0) bsum[blockIdx.x] = sdata[0];
}

__global__ void k_scan2(int* bsum, int nb) {
  __shared__ int sdata[256];
  int v = (threadIdx.x < nb) ? bsum[threadIdx.x] : 0;
  sdata[threadIdx.x] = v;
  __syncthreads();
  for (int off = 1; off < 256; off <<= 1) {
    int t = (threadIdx.x >= (unsigned)off) ? sdata[threadIdx.x - off] : 0;
    __syncthreads();
    sdata[threadIdx.x] += t;
    __syncthreads();
  }
  if (threadIdx.x < nb) bsum[threadIdx.x] = sdata[threadIdx.x] - v;
}

__global__ void k_scan3(const int* __restrict__ cnt, const int* __restrict__ bsum,
                        int* __restrict__ rowptr, int n, int nnz) {
  __shared__ int sdata[256];
  int base = blockIdx.x * SCAN_CHUNK;
  int loc[8];
  int s = 0;
#pragma unroll
  for (int k = 0; k < 8; ++k) {
    int i = base + threadIdx.x * 8 + k;
    loc[k] = (i < n) ? cnt[i] : 0;
    s += loc[k];
  }
  sdata[threadIdx.x] = s;
  __syncthreads();
  for (int off = 1; off < 256; off <<= 1) {
    int t = (threadIdx.x >= (unsigned)off) ? sdata[threadIdx.x - off] : 0;
    __syncthreads();
    sdata[threadIdx.x] += t;
    __syncthreads();
  }
  int pre = bsum[blockIdx.x] + sdata[threadIdx.x] - s;
#pragma unroll
  for (int k = 0; k < 8; ++k) {
    int i = base + threadIdx.x * 8 + k;
    if (i < n) { rowptr[i] = pre; pre += loc[k]; }
  }
  if (blockIdx.x == 0 && threadIdx.x == 0) rowptr[n] = nnz;
}

// atomic-FREE scatter: position = ptr[row] + precomputed rank. 8-deep MLP.
__global__ void k_scatter2(const int* __restrict__ rows, const int* __restrict__ cols,
                           const float* __restrict__ vals, const int* __restrict__ ptr,
                           const int* __restrict__ rank, int2* __restrict__ cv, int nnz) {
  int tid = blockIdx.x * blockDim.x + threadIdx.x;
  int gsz = gridDim.x * blockDim.x;
  for (int b = tid; b < nnz; b += gsz * 8) {
#pragma unroll
    for (int u = 0; u < 8; ++u) {
      int i = b + u * gsz;
      if (i < nnz) {
        int r = rows[i];
        cv[ptr[r] + rank[i]] = make_int2(cols[i], __float_as_int(vals[i]));
      }
    }
  }
}

// ================= dense pre-transform =================
// SOCPt[i] = pack(u1[i]@Wc.T, u2[i]@Wc.T) — coalesced dense GEMM, 2 chains.
__global__ LB void k_transform(const float* __restrict__ u1, const float* __restrict__ u2,
                               const float* __restrict__ Wc, uint* __restrict__ SOCPt) {
  __shared__ float Wt[64 * 65];
  stage_wt(Wc, Wt);
  int lane = threadIdx.x & 63;
  int wid = (blockIdx.x * blockDim.x + threadIdx.x) >> 6;
  int nw = (gridDim.x * blockDim.x) >> 6;
  for (int i = wid; i < NU; i += nw) {
    float a1 = u1[(size_t)i * DD + lane];
    float a2 = u2[(size_t)i * DD + lane];
    float o1, o2;
    gemm64x2_lds(a1, a2, Wt, lane, o1, o2);
    SOCPt[(size_t)i * DD + lane] = pack_bf16x2(o1, o2);
  }
}

// QUADP[i] = { SOCPt[i], lo16(SOCPt[s1[i]]) | hi16(SOCPt[s2[i]]) } — single
// interleaved table so quadS does ONE dwordx2 gather per edge per lane.
__global__ void k_negmap(const uint* __restrict__ SOCPt, const int* __restrict__ s1,
                         const int* __restrict__ s2, uint2* __restrict__ QUADP) {
  int idx = blockIdx.x * blockDim.x + threadIdx.x;
  const int tot = NU * DD;
  for (; idx < tot; idx += gridDim.x * blockDim.x) {
    int i = idx >> 6, j = idx & 63;
    uint soc = SOCPt[idx];
    uint lo = SOCPt[(size_t)s1[i] * DD + j];
    uint hi = SOCPt[(size_t)s2[i] * DD + j];
    QUADP[idx] = make_uint2(soc, (lo & 0xffffu) | (hi & 0xffff0000u));
  }
}

// ================= gather kernels =================
// quad: ONE uint2 gather per edge (4 chains); tanh; 4 bf16 outputs +
// next-layer packed table (fused gemm on the neg pair).
__global__ LB void k_quadS(const int* __restrict__ rowptr, const int2* __restrict__ cv,
                           const uint2* __restrict__ QUADP, const float* __restrict__ Wc,
                           ushort* __restrict__ u1s, ushort* __restrict__ u2s,
                           ushort* __restrict__ n1o, ushort* __restrict__ n2o,
                           uint* __restrict__ NEGPa) {
  __shared__ float Wt[64 * 65];
  stage_wt(Wc, Wt);
  int lane = threadIdx.x & 63;
  int wid = (blockIdx.x * blockDim.x + threadIdx.x) >> 6;
  int nw = (gridDim.x * blockDim.x) >> 6;
  for (int r = wid; r < NU; r += nw) {
    int start = rowptr[r], end = rowptr[r + 1];
    float a1 = 0.f, a2 = 0.f, a3 = 0.f, a4 = 0.f;
    for (int p0 = start; p0 < end; p0 += 64) {
      int n = min(64, end - p0);
      int2 e = cv[p0 + (lane < n ? lane : 0)];
      for (int k = 0; k < n; k += 8) {
        uint2 q[8];
        float vv[8];
#pragma unroll
        for (int u = 0; u < 8; ++u) {
          int kk = k + u;
          int ks = min(kk, n - 1);
          int c = RDLANE_I(e.x, ks);
          vv[u] = (kk < n) ? RDLANE_F(__int_as_float(e.y), ks) : 0.f;
          q[u] = QUADP[(size_t)c * DD + lane];
        }
#pragma unroll
        for (int u = 0; u < 8; ++u) {
          a1 = fmaf(vv[u], unpk_lo(q[u].x), a1);
          a2 = fmaf(vv[u], unpk_hi(q[u].x), a2);
          a3 = fmaf(vv[u], unpk_lo(q[u].y), a3);
          a4 = fmaf(vv[u], unpk_hi(q[u].y), a4);
        }
      }
    }
    float t1 = tanhf(a1), t2 = tanhf(a2), t3 = tanhf(a3), t4 = tanhf(a4);
    u1s[(size_t)r * DD + lane] = f2bf(t1);
    u2s[(size_t)r * DD + lane] = f2bf(t2);
    n1o[(size_t)r * DD + lane] = f2bf(t3);
    n2o[(size_t)r * DD + lane] = f2bf(t4);
    float o3, o4;
    gemm64x2_lds(t3, t4, Wt, lane, o3, o4);  // pre-transform layer-0 negs for layer-1
    NEGPa[(size_t)r * DD + lane] = pack_bf16x2(o3, o4);
  }
}

// dual: gathers 1 packed table; tanh; fused false-logits; optional next-table.
__global__ LB void k_dualS(const int* __restrict__ rowptr, const int2* __restrict__ cv,
                           const uint* __restrict__ T, const float* __restrict__ Wc,
                           const float* __restrict__ wva, const float* __restrict__ wvb,
                           const float* __restrict__ fkb, float* __restrict__ out_logits,
                           int slot, uint* __restrict__ Tnext) {
  __shared__ float Wt[64 * 65];
  stage_wt(Wc, Wt);
  int lane = threadIdx.x & 63;
  int wid = (blockIdx.x * blockDim.x + threadIdx.x) >> 6;
  int nw = (gridDim.x * blockDim.x) >> 6;
  float b = fkb[0];
  float wa = wva[lane], wb = wvb[lane];
  for (int r = wid; r < NU; r += nw) {
    int start = rowptr[r], end = rowptr[r + 1];
    float accA = 0.f, accB = 0.f;
    for (int p0 = start; p0 < end; p0 += 64) {
      int n = min(64, end - p0);
      int2 e = cv[p0 + (lane < n ? lane : 0)];
      for (int k = 0; k < n; k += 8) {
        uint q[8];
        float vv[8];
#pragma unroll
        for (int u = 0; u < 8; ++u) {
          int kk = k + u;
          int ks = min(kk, n - 1);
          int c = RDLANE_I(e.x, ks);
          vv[u] = (kk < n) ? RDLANE_F(__int_as_float(e.y), ks) : 0.f;
          q[u] = T[(size_t)c * DD + lane];
        }
#pragma unroll
        for (int u = 0; u < 8; ++u) {
          accA = fmaf(vv[u], unpk_lo(q[u]), accA);
          accB = fmaf(vv[u], unpk_hi(q[u]), accB);
        }
      }
    }
    float ta = tanhf(accA), tb = tanhf(accB);
    float pa = ta * wa, pb = tb * wb;
#pragma unroll
    for (int off = 32; off > 0; off >>= 1) {
      pa += __shfl_xor(pa, off);
      pb += __shfl_xor(pb, off);
    }
    if (lane == 0) {
      out_logits[(size_t)(NU + r) * 6 + slot] = pa + b;  // sc4: u1_neg chain
      out_logits[(size_t)r * 6 + slot] = pb + b;          // sc3: u2_neg chain
    }
    if (Tnext) {
      float oa, ob;
      gemm64x2_lds(ta, tb, Wt, lane, oa, ob);
      Tnext[(size_t)r * DD + lane] = pack_bf16x2(oa, ob);
    }
  }
}

// A-type, bf16 table, 2 rows per wave.
__global__ LB void k_spmm_fusedA2(const int* __restrict__ rowptr, const int2* __restrict__ cv,
                                  const ushort* __restrict__ X, const float* __restrict__ W,
                                  ushort* __restrict__ embNext, float* __restrict__ outF) {
  __shared__ float Wt[64 * 65];
  stage_wt(W, Wt);
  int lane = threadIdx.x & 63;
  int wid = (blockIdx.x * blockDim.x + threadIdx.x) >> 6;
  int nw = (gridDim.x * blockDim.x) >> 6;
  for (int r = wid * 2; r < NTOT; r += nw * 2) {
    int sA = rowptr[r], m = rowptr[r + 1], eB = rowptr[r + 2];
    float accA = 0.f, accB = 0.f;
    for (int pA = sA, pB = m; pA < m || pB < eB; pA += 64, pB += 64) {
      int nA = (pA < m) ? min(64, m - pA) : 0;
      int nB = (pB < eB) ? min(64, eB - pB) : 0;
      int2 eAv = cv[(nA ? pA : 0) + (lane < nA ? lane : 0)];
      int2 eBv = cv[(nB ? pB : 0) + (lane < nB ? lane : 0)];
      int kmax = max(nA, nB);
      for (int k = 0; k < kmax; k += 8) {
        uint hA[8], hB[8];
        float vA[8], vB[8];
#pragma unroll
        for (int u = 0; u < 8; ++u) {
          int kk = k + u;
          int ksA = min(kk, max(nA - 1, 0));
          int ksB = min(kk, max(nB - 1, 0));
          int cA = RDLANE_I(eAv.x, ksA);
          int cB = RDLANE_I(eBv.x, ksB);
          vA[u] = (kk < nA) ? RDLANE_F(__int_as_float(eAv.y), ksA) : 0.f;
          vB[u] = (kk < nB) ? RDLANE_F(__int_as_float(eBv.y), ksB) : 0.f;
          hA[u] = X[(size_t)cA * DD + lane];
          hB[u] = X[(size_t)cB * DD + lane];
        }
#pragma unroll
        for (int u = 0; u < 8; ++u) {
          accA = fmaf(vA[u], __uint_as_float(hA[u] << 16), accA);
          accB = fmaf(vB[u], __uint_as_float(hB[u] << 16), accB);
        }
      }
    }
    if (r < NU) {  // NU even: pair never straddles
      float oA, oB;
      gemm64x2_lds(accA, accB, Wt, lane, oA, oB);
      embNext[(size_t)r * DD + lane] = f2bf(tanhf(oA));
      embNext[(size_t)(r + 1) * DD + lane] = f2bf(tanhf(oB));
    } else {
      embNext[(size_t)r * DD + lane] = f2bf(accA);
      embNext[(size_t)(r + 1) * DD + lane] = f2bf(accB);
      outF[(size_t)r * DD + lane] += accA;
      outF[(size_t)(r + 1) * DD + lane] += accB;
    }
  }
}

// ---------- fused column sums (bf16 inputs) ----------
__global__ void k_colsum2(const ushort* __restrict__ x1, const ushort* __restrict__ x2,
                          float* __restrict__ c1, float* __restrict__ c2) {
  int lane = threadIdx.x & 63;
  int wid = (blockIdx.x * blockDim.x + threadIdx.x) >> 6;
  int nw = (gridDim.x * blockDim.x) >> 6;
  float a1 = 0.f, a2 = 0.f;
  for (int i = wid; i < NU; i += nw) {
    a1 += bf2f(x1[(size_t)i * DD + lane]);
    a2 += bf2f(x2[(size_t)i * DD + lane]);
  }
  atomicAdd(&c1[lane], a1);
  atomicAdd(&c2[lane], a2);
}

// ---------- w = fk_W @ (csum/NU) ----------
__global__ void k_wvec(const float* __restrict__ fkW, const float* __restrict__ c1r,
                       const float* __restrict__ c2r, float* __restrict__ w1,
                       float* __restrict__ w2) {
  int j = threadIdx.x;
  float a1 = 0.f, a2 = 0.f;
  for (int k = 0; k < 64; ++k) {
    float w = fkW[j * 64 + k];
    a1 += w * c1r[k];
    a2 += w * c2r[k];
  }
  w1[j] = a1 * (1.0f / NU);
  w2[j] = a2 * (1.0f / NU);
}

// ---------- logits: true slots 0-2 + false slot 3 (layer-0 negs) ----------
__global__ void k_logits4(const ushort* __restrict__ u1s, const ushort* __restrict__ u2s,
                          const ushort* __restrict__ n1o, const ushort* __restrict__ n2o,
                          const float* __restrict__ w1, const float* __restrict__ w2,
                          const float* __restrict__ fkb, float* __restrict__ out_logits) {
  int lane = threadIdx.x & 63;
  int wid = (blockIdx.x * blockDim.x + threadIdx.x) >> 6;
  int nw = (gridDim.x * blockDim.x) >> 6;
  float b = fkb[0];
  for (int i = wid; i < 2 * NU; i += nw) {
    bool lo = i < NU;
    int r = lo ? i : i - NU;
    const ushort* xs = lo ? u2s : u1s;
    const ushort* xn = lo ? n2o : n1o;
    const float* wv = lo ? w1 : w2;
    float wvl = wv[lane];
    float ps = bf2f(xs[(size_t)r * DD + lane]) * wvl;
    float pn = bf2f(xn[(size_t)r * DD + lane]) * wvl;
#pragma unroll
    for (int off = 32; off > 0; off >>= 1) {
      ps += __shfl_xor(ps, off);
      pn += __shfl_xor(pn, off);
    }
    if (lane == 0) {
      float vs = ps + b;
      out_logits[(size_t)i * 6 + 0] = vs;
      out_logits[(size_t)i * 6 + 1] = vs;
      out_logits[(size_t)i * 6 + 2] = vs;
      out_logits[(size_t)i * 6 + 3] = pn + b;
    }
  }
}

// ---------- UC[i] = (0.5*(u1s+u2s)) @ Ws[:,64:].T -> bf16 ----------
__global__ LB void k_comb_gemm(const ushort* __restrict__ u1s, const ushort* __restrict__ u2s,
                               const float* __restrict__ Ws, ushort* __restrict__ UC) {
  __shared__ float Wt[64 * 65];
  for (int idx = threadIdx.x; idx < 64 * 64; idx += blockDim.x)
    Wt[(idx & 63) * 65 + (idx >> 6)] = Ws[(idx >> 6) * 128 + 64 + (idx & 63)];
  __syncthreads();
  int lane = threadIdx.x & 63;
  int wid = (blockIdx.x * blockDim.x + threadIdx.x) >> 6;
  int nw = (gridDim.x * blockDim.x) >> 6;
  for (int i = wid; i < NU; i += nw) {
    float c = 0.5f * (bf2f(u1s[(size_t)i * DD + lane]) + bf2f(u2s[(size_t)i * DD + lane]));
    float o = 0.f;
#pragma unroll 16
    for (int k = 0; k < 64; ++k)
      o = fmaf(RDLANE_F(c, k), Wt[k * 65 + lane], o);
    UC[(size_t)i * DD + lane] = f2bf(o);
  }
}

// ---------- users_raw = u_next @ Ws[:,:64].T + UC ; sum of squares ----------
__global__ LB void k_users(const ushort* __restrict__ u_next, const ushort* __restrict__ uc,
                           const float* __restrict__ Ws, float* __restrict__ users_raw,
                           float* __restrict__ sumsq) {
  __shared__ float Wt[64 * 65];
  for (int idx = threadIdx.x; idx < 64 * 64; idx += blockDim.x)
    Wt[(idx & 63) * 65 + (idx >> 6)] = Ws[(idx >> 6) * 128 + (idx & 63)];
  __syncthreads();
  int lane = threadIdx.x & 63;
  int wid = (blockIdx.x * blockDim.x + threadIdx.x) >> 6;
  int nw = (gridDim.x * blockDim.x) >> 6;
  float ss = 0.f;
  for (int i = wid; i < NU; i += nw) {
    float va = bf2f(u_next[(size_t)i * DD + lane]);
    float acc = bf2f(uc[(size_t)i * DD + lane]);
#pragma unroll 16
    for (int k = 0; k < 64; ++k)
      acc = fmaf(RDLANE_F(va, k), Wt[k * 65 + lane], acc);
    users_raw[(size_t)i * DD + lane] = acc;
    ss += acc * acc;
  }
#pragma unroll
  for (int off = 32; off > 0; off >>= 1) ss += __shfl_xor(ss, off);
  if (lane == 0) atomicAdd(sumsq, ss);
}

__global__ void k_users_acc(const float* __restrict__ users_raw,
                            const float* __restrict__ sumsq, float* __restrict__ out_final) {
  float scale = 1.0f / sqrtf(*sumsq);
  int idx = blockIdx.x * blockDim.x + threadIdx.x;
  for (; idx < NU * DD; idx += gridDim.x * blockDim.x)
    out_final[idx] += users_raw[idx] * scale;
}

__global__ void k_scale(float* __restrict__ out_final) {
  int idx = blockIdx.x * blockDim.x + threadIdx.x;
  const int tot = NTOT * DD;
  for (; idx < tot; idx += gridDim.x * blockDim.x) out_final[idx] *= 0.25f;
}

extern "C" void kernel_launch(void* const* d_in, const int* in_sizes, int n_in,
                              void* d_out, int out_size, void* d_ws, size_t ws_size,
                              hipStream_t stream) {
  const float* u1      = (const float*)d_in[0];
  const float* u2      = (const float*)d_in[1];
  const float* item    = (const float*)d_in[2];
  const float* Wi      = (const float*)d_in[3];
  const float* Wc      = (const float*)d_in[4];
  const float* Ws      = (const float*)d_in[5];
  const float* fk_W    = (const float*)d_in[6];
  const float* fk_b    = (const float*)d_in[7];
  const float* A_vals  = (const float*)d_in[8];
  const float* A2_vals = (const float*)d_in[9];
  const float* S_vals  = (const float*)d_in[10];
  const int*   A_rows  = (const int*)d_in[11];
  const int*   A_cols  = (const int*)d_in[12];
  const int*   A2_rows = (const int*)d_in[13];
  const int*   A2_cols = (const int*)d_in[14];
  const int*   S_rows  = (const int*)d_in[15];
  const int*   S_cols  = (const int*)d_in[16];
  const int*   sh1     = (const int*)d_in[17];
  const int*   sh2     = (const int*)d_in[18];

  // ---- workspace layout (float offsets), total ~56.2M floats = 224.8MB ----
  float* ws = (float*)d_ws;
  ushort* embA_bf = (ushort*)ws;                   // [0, 8M)   16M ushorts
  ushort* embB_bf = (ushort*)(ws + 8000000);       // [8M, 16M)
  uint2*  QUADP   = (uint2*)(ws + 16000000);       // [16M, 28.8M) dead after quad
  uint*   NEGPb   = (uint*)(ws + 16000000);        //   overlay: written at l=1 dual
  float*  uraw    = ws + 22400000;                 //   overlay: fp32 users scratch
  uint*   NEGPa   = (uint*)(ws + 28800000);        // [28.8M, 35.2M)
  ushort* u1s     = (ushort*)(ws + 35200000);      // [35.2M, 38.4M) dead after comb
  ushort* u2s     = (ushort*)(ws + 38400000);      // [38.4M, 41.6M) dead after comb
  int2*   cvA2    = (int2*)(ws + 35200000);        //   overlay: built after comb
  int*    ptrA2   = (int*)(ws + 39200000);         //   overlay (inside u2s region)
  uint*   SOCPt   = (uint*)(ws + 41600000);        // [41.6M, 48M) dead after negmap
  ushort* n1o     = (ushort*)(ws + 41600000);      //   overlay: written by quadS
  ushort* UCb     = (ushort*)(ws + 41600000);      //   overlay: written by comb_gemm
  ushort* n2o     = (ushort*)(ws + 44800000);      //   overlay: written by quadS
  int2*   cvA     = (int2*)(ws + 48000000);        // [48M, 52M)
  int2*   cvS     = (int2*)(ws + 52000000);        // [52M, 53.6M)
  int*    ptrA    = (int*)(ws + 53600000);         // 250001
  int*    ptrS    = ptrA + (NTOT + 1);             // 100001
  int*    cnt     = ptrS + (NU + 1);               // 250000
  int*    bsum    = cnt + NTOT;                    // 256
  float*  c1r     = (float*)(bsum + 256);          // 64
  float*  c2r     = c1r + 64;
  float*  w1      = c2r + 64;
  float*  w2      = w1 + 64;
  float*  sumsq   = w2 + 64;                       // 1 -> ~54,200,516
  int*    rank    = (int*)(ws + 54200520);         // 2,000,000 ints -> 56,200,520

  float* out        = (float*)d_out;
  float* out_logits = out + (size_t)NTOT * DD;

  auto build = [&](const int* rows, const int* cols, const float* vals,
                   int n, int nnz, int* ptr, int2* cv) {
    int nb = (n + SCAN_CHUNK - 1) / SCAN_CHUNK;
    int gb = (nnz + 2047) / 2048;  // 256 thr x 8 edges
    hipMemsetAsync(cnt, 0, (size_t)n * sizeof(int), stream);
    k_hist_rank<<<gb, 256, 0, stream>>>(rows, cnt, rank, nnz);
    k_scan1<<<nb, 256, 0, stream>>>(cnt, bsum, n);
    k_scan2<<<1, 256, 0, stream>>>(bsum, nb);
    k_scan3<<<nb, 256, 0, stream>>>(cnt, bsum, ptr, n, nnz);
    k_scatter2<<<gb, 256, 0, stream>>>(rows, cols, vals, ptr, rank, cv, nnz);
  };

  // ---------- CSR builds (S, A) ----------
  build(S_rows, S_cols, S_vals, NU, NNZ_S, ptrS, cvS);
  build(A_rows, A_cols, A_vals, NTOT, NNZ_A, ptrA, cvA);

  // ---------- init + pre-transform (dense) + neg remap into QUADP ----------
  hipMemsetAsync(c1r, 0, 128 * sizeof(float), stream);
  k_init<<<2048, 256, 0, stream>>>(u1, u2, item, embA_bf, out);
  k_transform<<<1024, 256, 0, stream>>>(u1, u2, Wc, SOCPt);
  k_negmap<<<1024, 256, 0, stream>>>(SOCPt, sh1, sh2, QUADP);

  // ---------- quad gather: socials + layer-0 negs + layer-1 table ----------
  k_quadS<<<2048, 256, 0, stream>>>(ptrS, cvS, QUADP, Wc,
                                    u1s, u2s, n1o, n2o, NEGPa);
  k_colsum2<<<256, 256, 0, stream>>>(u1s, u2s, c1r, c2r);
  k_wvec<<<1, 64, 0, stream>>>(fk_W, c1r, c2r, w1, w2);
  k_logits4<<<1024, 256, 0, stream>>>(u1s, u2s, n1o, n2o, w1, w2, fk_b, out_logits);
  k_comb_gemm<<<1024, 256, 0, stream>>>(u1s, u2s, Ws, UCb);

  // A2 CSR into the dead u1s/u2s region (persistent for layers 1,2)
  build(A2_rows, A2_cols, A2_vals, NTOT, NNZ_A, ptrA2, cvA2);

  // ---------- layer loop ----------
  ushort* embCur = embA_bf;
  ushort* embNext = embB_bf;
  for (int l = 0; l < 3; ++l) {
    const int* pA = (l == 0) ? ptrA : ptrA2;
    const int2* cA = (l == 0) ? cvA : cvA2;

    k_spmm_fusedA2<<<4096, 256, 0, stream>>>(pA, cA, embCur, Wi, embNext, out);

    if (l == 1)  // false-logits slot 4 + table for layer 2
      k_dualS<<<2048, 256, 0, stream>>>(ptrS, cvS, NEGPa, Wc, w2, w1, fk_b,
                                        out_logits, 4, NEGPb);
    else if (l == 2)  // false-logits slot 5, no next table
      k_dualS<<<2048, 256, 0, stream>>>(ptrS, cvS, NEGPb, Wc, w2, w1, fk_b,
                                        out_logits, 5, (uint*)nullptr);

    hipMemsetAsync(sumsq, 0, sizeof(float), stream);
    k_users<<<1024, 256, 0, stream>>>(embNext, UCb, Ws, uraw, sumsq);
    k_users_acc<<<2048, 256, 0, stream>>>(uraw, sumsq, out);

    { ushort* t = embCur; embCur = embNext; embNext = t; }
  }

  k_scale<<<2048, 256, 0, stream>>>(out);
}

// Round 12
// 1652.392 us; speedup vs baseline: 1.8495x; 1.0217x over previous
//
#include <hip/hip_runtime.h>

#define NU 100000
#define NI 150000
#define NTOT 250000
#define DD 64
#define NNZ_A 2000000
#define NNZ_S 800000
#define SCAN_CHUNK 2048  // 256 threads x 8

typedef unsigned int uint;
typedef unsigned short ushort;

// launch bounds for gemm-style kernels: 256 threads, >=4 waves/EU -> 128 VGPR
#define LB __launch_bounds__(256, 4)

// ================= helpers =================
#define RDLANE_F(x, k) __uint_as_float(__builtin_amdgcn_readlane(__float_as_uint(x), (unsigned)(k)))
#define RDLANE_I(x, k) ((int)__builtin_amdgcn_readlane((unsigned)(x), (unsigned)(k)))

__device__ __forceinline__ uint f2bf_bits(float x) {  // RNE round to bf16 (upper 16)
  uint a = __float_as_uint(x);
  return (a + 0x7fffu + ((a >> 16) & 1u)) >> 16;
}
__device__ __forceinline__ ushort f2bf(float x) { return (ushort)f2bf_bits(x); }
__device__ __forceinline__ float bf2f(ushort h) { return __uint_as_float(((uint)h) << 16); }
__device__ __forceinline__ uint pack_bf16x2(float lo, float hi) {
  return f2bf_bits(lo) | (f2bf_bits(hi) << 16);
}
__device__ __forceinline__ float unpk_lo(uint p) { return __uint_as_float(p << 16); }
__device__ __forceinline__ float unpk_hi(uint p) { return __uint_as_float(p & 0xffff0000u); }

// fast tanh: 1 - 2/(e^{2x}+1). Exact at +-inf; abs err ~1e-7 (<< bf16 rounding).
__device__ __forceinline__ float tanh_fast(float x) {
  float e = __expf(2.0f * x);
  return 1.0f - __fdividef(2.0f, e + 1.0f);
}

// ---- 64x64 GEMM, transposed-W LDS form (R10-proven readlane broadcast).
// Wt[k*65+j] = W[j][k]; unroll 16 bounds live ds_read results -> no spill.
// NOTE: R11's LDS-broadcast variant (ds_write + asm lgkmcnt + ds_read) raced
// under the compiler scheduler (guide rule #18) -> replay divergence. Reverted.
__device__ __forceinline__ void gemm64x2_lds(float aA, float aB,
                                             const float* __restrict__ Wt, int lane,
                                             float& oA, float& oB) {
  oA = 0.f; oB = 0.f;
#pragma unroll 16
  for (int k = 0; k < 64; ++k) {
    float wk = Wt[k * 65 + lane];
    oA = fmaf(RDLANE_F(aA, k), wk, oA);
    oB = fmaf(RDLANE_F(aB, k), wk, oB);
  }
}

__device__ __forceinline__ float gemm64x1_lds(float a, const float* __restrict__ Wt,
                                              int lane) {
  float s = 0.f;
#pragma unroll 16
  for (int k = 0; k < 64; ++k)
    s = fmaf(RDLANE_F(a, k), Wt[k * 65 + lane], s);
  return s;
}

// stage Wt[k*65+j] = W[j][k] from row-major W[j*64+k]
__device__ __forceinline__ void stage_wt(const float* __restrict__ W, float* __restrict__ Wt) {
  for (int idx = threadIdx.x; idx < 64 * 64; idx += blockDim.x)
    Wt[(idx & 63) * 65 + (idx >> 6)] = W[idx];
  __syncthreads();
}

// ---------- init: emb_bf = [(u1+u2)/2 ; item]; out = 0.25 * same ----------
__global__ void k_init(const float* __restrict__ u1, const float* __restrict__ u2,
                       const float* __restrict__ item, ushort* __restrict__ emb_bf,
                       float* __restrict__ out_final) {
  int idx = blockIdx.x * blockDim.x + threadIdx.x;
  const int tot = NTOT * DD;
  const int nu = NU * DD;
  for (; idx < tot; idx += gridDim.x * blockDim.x) {
    float v;
    if (idx < nu) v = 0.5f * (u1[idx] + u2[idx]);
    else          v = item[idx - nu];
    emb_bf[idx] = f2bf(v);
    out_final[idx] = 0.25f * v;
  }
}

// ================= CSR build (counting sort, rank-in-hist) =================
__global__ void k_hist_rank(const int* __restrict__ rows, int* __restrict__ cnt,
                            int* __restrict__ rank, int nnz) {
  int tid = blockIdx.x * blockDim.x + threadIdx.x;
  int gsz = gridDim.x * blockDim.x;
  for (int b = tid; b < nnz; b += gsz * 8) {
#pragma unroll
    for (int u = 0; u < 8; ++u) {
      int i = b + u * gsz;
      if (i < nnz) rank[i] = atomicAdd(&cnt[rows[i]], 1);
    }
  }
}

__global__ void k_scan1(const int* __restrict__ cnt, int* __restrict__ bsum, int n) {
  __shared__ int sdata[256];
  int base = blockIdx.x * SCAN_CHUNK;
  int s = 0;
#pragma unroll
  for (int k = 0; k < 8; ++k) {
    int i = base + threadIdx.x * 8 + k;
    s += (i < n) ? cnt[i] : 0;
  }
  sdata[threadIdx.x] = s;
  __syncthreads();
  for (int off = 128; off > 0; off >>= 1) {
    if (threadIdx.x < off) sdata[threadIdx.x] += sdata[threadIdx.x + off];
    __syncthreads();
  }
  if (threadIdx.x == 0) bsum[blockIdx.x] = sdata[0];
}

__global__ void k_scan2(int* bsum, int nb) {
  __shared__ int sdata[256];
  int v = (threadIdx.x < nb) ? bsum[threadIdx.x] : 0;
  sdata[threadIdx.x] = v;
  __syncthreads();
  for (int off = 1; off < 256; off <<= 1) {
    int t = (threadIdx.x >= (unsigned)off) ? sdata[threadIdx.x - off] : 0;
    __syncthreads();
    sdata[threadIdx.x] += t;
    __syncthreads();
  }
  if (threadIdx.x < nb) bsum[threadIdx.x] = sdata[threadIdx.x] - v;
}

__global__ void k_scan3(const int* __restrict__ cnt, const int* __restrict__ bsum,
                        int* __restrict__ rowptr, int n, int nnz) {
  __shared__ int sdata[256];
  int base = blockIdx.x * SCAN_CHUNK;
  int loc[8];
  int s = 0;
#pragma unroll
  for (int k = 0; k < 8; ++k) {
    int i = base + threadIdx.x * 8 + k;
    loc[k] = (i < n) ? cnt[i] : 0;
    s += loc[k];
  }
  sdata[threadIdx.x] = s;
  __syncthreads();
  for (int off = 1; off < 256; off <<= 1) {
    int t = (threadIdx.x >= (unsigned)off) ? sdata[threadIdx.x - off] : 0;
    __syncthreads();
    sdata[threadIdx.x] += t;
    __syncthreads();
  }
  int pre = bsum[blockIdx.x] + sdata[threadIdx.x] - s;
#pragma unroll
  for (int k = 0; k < 8; ++k) {
    int i = base + threadIdx.x * 8 + k;
    if (i < n) { rowptr[i] = pre; pre += loc[k]; }
  }
  if (blockIdx.x == 0 && threadIdx.x == 0) rowptr[n] = nnz;
}

__global__ void k_scatter2(const int* __restrict__ rows, const int* __restrict__ cols,
                           const float* __restrict__ vals, const int* __restrict__ ptr,
                           const int* __restrict__ rank, int2* __restrict__ cv, int nnz) {
  int tid = blockIdx.x * blockDim.x + threadIdx.x;
  int gsz = gridDim.x * blockDim.x;
  for (int b = tid; b < nnz; b += gsz * 8) {
#pragma unroll
    for (int u = 0; u < 8; ++u) {
      int i = b + u * gsz;
      if (i < nnz) {
        int r = rows[i];
        cv[ptr[r] + rank[i]] = make_int2(cols[i], __float_as_int(vals[i]));
      }
    }
  }
}

// ================= dense pre-transform =================
__global__ LB void k_transform(const float* __restrict__ u1, const float* __restrict__ u2,
                               const float* __restrict__ Wc, uint* __restrict__ SOCPt) {
  __shared__ float Wt[64 * 65];
  stage_wt(Wc, Wt);
  int lane = threadIdx.x & 63;
  int wid = (blockIdx.x * blockDim.x + threadIdx.x) >> 6;
  int nw = (gridDim.x * blockDim.x) >> 6;
  for (int i = wid; i < NU; i += nw) {
    float a1 = u1[(size_t)i * DD + lane];
    float a2 = u2[(size_t)i * DD + lane];
    float o1, o2;
    gemm64x2_lds(a1, a2, Wt, lane, o1, o2);
    SOCPt[(size_t)i * DD + lane] = pack_bf16x2(o1, o2);
  }
}

// QUADP[i] = { SOCPt[i], lo16(SOCPt[s1[i]]) | hi16(SOCPt[s2[i]]) }
__global__ void k_negmap(const uint* __restrict__ SOCPt, const int* __restrict__ s1,
                         const int* __restrict__ s2, uint2* __restrict__ QUADP) {
  int idx = blockIdx.x * blockDim.x + threadIdx.x;
  const int tot = NU * DD;
  for (; idx < tot; idx += gridDim.x * blockDim.x) {
    int i = idx >> 6, j = idx & 63;
    uint soc = SOCPt[idx];
    uint lo = SOCPt[(size_t)s1[i] * DD + j];
    uint hi = SOCPt[(size_t)s2[i] * DD + j];
    QUADP[idx] = make_uint2(soc, (lo & 0xffffu) | (hi & 0xffff0000u));
  }
}

// ================= gather kernels =================
// quad: ONE uint2 gather per edge (4 chains). Clean batches + clamped tail.
__global__ LB void k_quadS(const int* __restrict__ rowptr, const int2* __restrict__ cv,
                           const uint2* __restrict__ QUADP, const float* __restrict__ Wc,
                           ushort* __restrict__ u1s, ushort* __restrict__ u2s,
                           ushort* __restrict__ n1o, ushort* __restrict__ n2o,
                           uint* __restrict__ NEGPa) {
  __shared__ float Wt[64 * 65];
  stage_wt(Wc, Wt);
  int lane = threadIdx.x & 63;
  int wid = (blockIdx.x * blockDim.x + threadIdx.x) >> 6;
  int nw = (gridDim.x * blockDim.x) >> 6;
  for (int r = wid; r < NU; r += nw) {
    int start = rowptr[r], end = rowptr[r + 1];
    float a1 = 0.f, a2 = 0.f, a3 = 0.f, a4 = 0.f;
    for (int p0 = start; p0 < end; p0 += 64) {
      int n = min(64, end - p0);
      int2 e = cv[p0 + (lane < n ? lane : 0)];
      int nfull = n & ~7;
      int k = 0;
      for (; k < nfull; k += 8) {  // clean: no clamps
        uint2 q[8];
        float vv[8];
#pragma unroll
        for (int u = 0; u < 8; ++u) {
          int c = RDLANE_I(e.x, k + u);
          vv[u] = RDLANE_F(__int_as_float(e.y), k + u);
          q[u] = QUADP[(uint)c * 64u + (uint)lane];
        }
#pragma unroll
        for (int u = 0; u < 8; ++u) {
          a1 = fmaf(vv[u], unpk_lo(q[u].x), a1);
          a2 = fmaf(vv[u], unpk_hi(q[u].x), a2);
          a3 = fmaf(vv[u], unpk_lo(q[u].y), a3);
          a4 = fmaf(vv[u], unpk_hi(q[u].y), a4);
        }
      }
      if (k < n) {  // single clamped tail batch
        uint2 q[8];
        float vv[8];
#pragma unroll
        for (int u = 0; u < 8; ++u) {
          int kk = k + u;
          int ks = min(kk, n - 1);
          int c = RDLANE_I(e.x, ks);
          vv[u] = (kk < n) ? RDLANE_F(__int_as_float(e.y), ks) : 0.f;
          q[u] = QUADP[(uint)c * 64u + (uint)lane];
        }
#pragma unroll
        for (int u = 0; u < 8; ++u) {
          a1 = fmaf(vv[u], unpk_lo(q[u].x), a1);
          a2 = fmaf(vv[u], unpk_hi(q[u].x), a2);
          a3 = fmaf(vv[u], unpk_lo(q[u].y), a3);
          a4 = fmaf(vv[u], unpk_hi(q[u].y), a4);
        }
      }
    }
    float t1 = tanh_fast(a1), t2 = tanh_fast(a2), t3 = tanh_fast(a3), t4 = tanh_fast(a4);
    u1s[(size_t)r * DD + lane] = f2bf(t1);
    u2s[(size_t)r * DD + lane] = f2bf(t2);
    n1o[(size_t)r * DD + lane] = f2bf(t3);
    n2o[(size_t)r * DD + lane] = f2bf(t4);
    float o3, o4;
    gemm64x2_lds(t3, t4, Wt, lane, o3, o4);
    NEGPa[(size_t)r * DD + lane] = pack_bf16x2(o3, o4);
  }
}

// dual: 1 packed-table gather (2 chains); fast-tanh; fused false-logits; optional next table.
__global__ LB void k_dualS(const int* __restrict__ rowptr, const int2* __restrict__ cv,
                           const uint* __restrict__ T, const float* __restrict__ Wc,
                           const float* __restrict__ wva, const float* __restrict__ wvb,
                           const float* __restrict__ fkb, float* __restrict__ out_logits,
                           int slot, uint* __restrict__ Tnext) {
  __shared__ float Wt[64 * 65];
  stage_wt(Wc, Wt);
  int lane = threadIdx.x & 63;
  int wid = (blockIdx.x * blockDim.x + threadIdx.x) >> 6;
  int nw = (gridDim.x * blockDim.x) >> 6;
  float b = fkb[0];
  float wa = wva[lane], wb = wvb[lane];
  for (int r = wid; r < NU; r += nw) {
    int start = rowptr[r], end = rowptr[r + 1];
    float accA = 0.f, accB = 0.f;
    for (int p0 = start; p0 < end; p0 += 64) {
      int n = min(64, end - p0);
      int2 e = cv[p0 + (lane < n ? lane : 0)];
      int nfull = n & ~7;
      int k = 0;
      for (; k < nfull; k += 8) {
        uint q[8];
        float vv[8];
#pragma unroll
        for (int u = 0; u < 8; ++u) {
          int c = RDLANE_I(e.x, k + u);
          vv[u] = RDLANE_F(__int_as_float(e.y), k + u);
          q[u] = T[(uint)c * 64u + (uint)lane];
        }
#pragma unroll
        for (int u = 0; u < 8; ++u) {
          accA = fmaf(vv[u], unpk_lo(q[u]), accA);
          accB = fmaf(vv[u], unpk_hi(q[u]), accB);
        }
      }
      if (k < n) {
        uint q[8];
        float vv[8];
#pragma unroll
        for (int u = 0; u < 8; ++u) {
          int kk = k + u;
          int ks = min(kk, n - 1);
          int c = RDLANE_I(e.x, ks);
          vv[u] = (kk < n) ? RDLANE_F(__int_as_float(e.y), ks) : 0.f;
          q[u] = T[(uint)c * 64u + (uint)lane];
        }
#pragma unroll
        for (int u = 0; u < 8; ++u) {
          accA = fmaf(vv[u], unpk_lo(q[u]), accA);
          accB = fmaf(vv[u], unpk_hi(q[u]), accB);
        }
      }
    }
    float ta = tanh_fast(accA), tb = tanh_fast(accB);
    float pa = ta * wa, pb = tb * wb;
#pragma unroll
    for (int off = 32; off > 0; off >>= 1) {
      pa += __shfl_xor(pa, off);
      pb += __shfl_xor(pb, off);
    }
    if (lane == 0) {
      out_logits[(size_t)(NU + r) * 6 + slot] = pa + b;  // sc4: u1_neg chain
      out_logits[(size_t)r * 6 + slot] = pb + b;          // sc3: u2_neg chain
    }
    if (Tnext) {
      float oa, ob;
      gemm64x2_lds(ta, tb, Wt, lane, oa, ob);
      Tnext[(size_t)r * DD + lane] = pack_bf16x2(oa, ob);
    }
  }
}

// A-type, bf16 table, 2 rows per wave (sequential per-row 8-batched gathers).
__global__ LB void k_spmm_fusedA2(const int* __restrict__ rowptr, const int2* __restrict__ cv,
                                  const ushort* __restrict__ X, const float* __restrict__ W,
                                  ushort* __restrict__ embNext, float* __restrict__ outF) {
  __shared__ float Wt[64 * 65];
  stage_wt(W, Wt);
  int lane = threadIdx.x & 63;
  int wid = (blockIdx.x * blockDim.x + threadIdx.x) >> 6;
  int nw = (gridDim.x * blockDim.x) >> 6;
  for (int r = wid * 2; r < NTOT; r += nw * 2) {
    float acc0 = 0.f, acc1 = 0.f;
#pragma unroll
    for (int rr = 0; rr < 2; ++rr) {
      int rs = rowptr[r + rr], re = rowptr[r + rr + 1];
      float a = 0.f;
      for (int p0 = rs; p0 < re; p0 += 64) {
        int n = min(64, re - p0);
        int2 e = cv[p0 + (lane < n ? lane : 0)];
        int nfull = n & ~7;
        int k = 0;
        for (; k < nfull; k += 8) {
          uint h[8];
          float vv[8];
#pragma unroll
          for (int u = 0; u < 8; ++u) {
            int c = RDLANE_I(e.x, k + u);
            vv[u] = RDLANE_F(__int_as_float(e.y), k + u);
            h[u] = X[(uint)c * 64u + (uint)lane];
          }
#pragma unroll
          for (int u = 0; u < 8; ++u)
            a = fmaf(vv[u], __uint_as_float(h[u] << 16), a);
        }
        if (k < n) {
          uint h[8];
          float vv[8];
#pragma unroll
          for (int u = 0; u < 8; ++u) {
            int kk = k + u;
            int ks = min(kk, n - 1);
            int c = RDLANE_I(e.x, ks);
            vv[u] = (kk < n) ? RDLANE_F(__int_as_float(e.y), ks) : 0.f;
            h[u] = X[(uint)c * 64u + (uint)lane];
          }
#pragma unroll
          for (int u = 0; u < 8; ++u)
            a = fmaf(vv[u], __uint_as_float(h[u] << 16), a);
        }
      }
      if (rr == 0) acc0 = a; else acc1 = a;
    }
    if (r < NU) {  // NU even: pair never straddles
      float oA, oB;
      gemm64x2_lds(acc0, acc1, Wt, lane, oA, oB);
      embNext[(size_t)r * DD + lane] = f2bf(tanh_fast(oA));
      embNext[(size_t)(r + 1) * DD + lane] = f2bf(tanh_fast(oB));
    } else {
      embNext[(size_t)r * DD + lane] = f2bf(acc0);
      embNext[(size_t)(r + 1) * DD + lane] = f2bf(acc1);
      outF[(size_t)r * DD + lane] += 0.25f * acc0;        // fold final /4
      outF[(size_t)(r + 1) * DD + lane] += 0.25f * acc1;
    }
  }
}

// ---------- fused column sums (bf16 inputs) ----------
__global__ void k_colsum2(const ushort* __restrict__ x1, const ushort* __restrict__ x2,
                          float* __restrict__ c1, float* __restrict__ c2) {
  int lane = threadIdx.x & 63;
  int wid = (blockIdx.x * blockDim.x + threadIdx.x) >> 6;
  int nw = (gridDim.x * blockDim.x) >> 6;
  float a1 = 0.f, a2 = 0.f;
  for (int i = wid; i < NU; i += nw) {
    a1 += bf2f(x1[(size_t)i * DD + lane]);
    a2 += bf2f(x2[(size_t)i * DD + lane]);
  }
  atomicAdd(&c1[lane], a1);
  atomicAdd(&c2[lane], a2);
}

// ---------- w = fk_W @ (csum/NU) ----------
__global__ void k_wvec(const float* __restrict__ fkW, const float* __restrict__ c1r,
                       const float* __restrict__ c2r, float* __restrict__ w1,
                       float* __restrict__ w2) {
  int j = threadIdx.x;
  float a1 = 0.f, a2 = 0.f;
  for (int k = 0; k < 64; ++k) {
    float w = fkW[j * 64 + k];
    a1 += w * c1r[k];
    a2 += w * c2r[k];
  }
  w1[j] = a1 * (1.0f / NU);
  w2[j] = a2 * (1.0f / NU);
}

// ---------- logits: true slots 0-2 + false slot 3 (layer-0 negs) ----------
__global__ void k_logits4(const ushort* __restrict__ u1s, const ushort* __restrict__ u2s,
                          const ushort* __restrict__ n1o, const ushort* __restrict__ n2o,
                          const float* __restrict__ w1, const float* __restrict__ w2,
                          const float* __restrict__ fkb, float* __restrict__ out_logits) {
  int lane = threadIdx.x & 63;
  int wid = (blockIdx.x * blockDim.x + threadIdx.x) >> 6;
  int nw = (gridDim.x * blockDim.x) >> 6;
  float b = fkb[0];
  for (int i = wid; i < 2 * NU; i += nw) {
    bool lo = i < NU;
    int r = lo ? i : i - NU;
    const ushort* xs = lo ? u2s : u1s;
    const ushort* xn = lo ? n2o : n1o;
    const float* wv = lo ? w1 : w2;
    float wvl = wv[lane];
    float ps = bf2f(xs[(size_t)r * DD + lane]) * wvl;
    float pn = bf2f(xn[(size_t)r * DD + lane]) * wvl;
#pragma unroll
    for (int off = 32; off > 0; off >>= 1) {
      ps += __shfl_xor(ps, off);
      pn += __shfl_xor(pn, off);
    }
    if (lane == 0) {
      float vs = ps + b;
      out_logits[(size_t)i * 6 + 0] = vs;
      out_logits[(size_t)i * 6 + 1] = vs;
      out_logits[(size_t)i * 6 + 2] = vs;
      out_logits[(size_t)i * 6 + 3] = pn + b;
    }
  }
}

// ---------- UC[i] = (0.5*(u1s+u2s)) @ Ws[:,64:].T -> bf16 ----------
__global__ LB void k_comb_gemm(const ushort* __restrict__ u1s, const ushort* __restrict__ u2s,
                               const float* __restrict__ Ws, ushort* __restrict__ UC) {
  __shared__ float Wt[64 * 65];
  for (int idx = threadIdx.x; idx < 64 * 64; idx += blockDim.x)
    Wt[(idx & 63) * 65 + (idx >> 6)] = Ws[(idx >> 6) * 128 + 64 + (idx & 63)];
  __syncthreads();
  int lane = threadIdx.x & 63;
  int wid = (blockIdx.x * blockDim.x + threadIdx.x) >> 6;
  int nw = (gridDim.x * blockDim.x) >> 6;
  for (int i = wid; i < NU; i += nw) {
    float c = 0.5f * (bf2f(u1s[(size_t)i * DD + lane]) + bf2f(u2s[(size_t)i * DD + lane]));
    UC[(size_t)i * DD + lane] = f2bf(gemm64x1_lds(c, Wt, lane));
  }
}

// ---------- users_raw = u_next @ Ws[:,:64].T + UC ; sum of squares ----------
__global__ LB void k_users(const ushort* __restrict__ u_next, const ushort* __restrict__ uc,
                           const float* __restrict__ Ws, float* __restrict__ users_raw,
                           float* __restrict__ sumsq) {
  __shared__ float Wt[64 * 65];
  for (int idx = threadIdx.x; idx < 64 * 64; idx += blockDim.x)
    Wt[(idx & 63) * 65 + (idx >> 6)] = Ws[(idx >> 6) * 128 + (idx & 63)];
  __syncthreads();
  int lane = threadIdx.x & 63;
  int wid = (blockIdx.x * blockDim.x + threadIdx.x) >> 6;
  int nw = (gridDim.x * blockDim.x) >> 6;
  float ss = 0.f;
  for (int i = wid; i < NU; i += nw) {
    float va = bf2f(u_next[(size_t)i * DD + lane]);
    float acc = bf2f(uc[(size_t)i * DD + lane]) + gemm64x1_lds(va, Wt, lane);
    users_raw[(size_t)i * DD + lane] = acc;
    ss += acc * acc;
  }
#pragma unroll
  for (int off = 32; off > 0; off >>= 1) ss += __shfl_xor(ss, off);
  if (lane == 0) atomicAdd(sumsq, ss);
}

__global__ void k_users_acc(const float* __restrict__ users_raw,
                            const float* __restrict__ sumsq, float* __restrict__ out_final) {
  float scale = 0.25f / sqrtf(*sumsq);  // fold final /4
  int idx = blockIdx.x * blockDim.x + threadIdx.x;
  for (; idx < NU * DD; idx += gridDim.x * blockDim.x)
    out_final[idx] += users_raw[idx] * scale;
}

extern "C" void kernel_launch(void* const* d_in, const int* in_sizes, int n_in,
                              void* d_out, int out_size, void* d_ws, size_t ws_size,
                              hipStream_t stream) {
  const float* u1      = (const float*)d_in[0];
  const float* u2      = (const float*)d_in[1];
  const float* item    = (const float*)d_in[2];
  const float* Wi      = (const float*)d_in[3];
  const float* Wc      = (const float*)d_in[4];
  const float* Ws      = (const float*)d_in[5];
  const float* fk_W    = (const float*)d_in[6];
  const float* fk_b    = (const float*)d_in[7];
  const float* A_vals  = (const float*)d_in[8];
  const float* A2_vals = (const float*)d_in[9];
  const float* S_vals  = (const float*)d_in[10];
  const int*   A_rows  = (const int*)d_in[11];
  const int*   A_cols  = (const int*)d_in[12];
  const int*   A2_rows = (const int*)d_in[13];
  const int*   A2_cols = (const int*)d_in[14];
  const int*   S_rows  = (const int*)d_in[15];
  const int*   S_cols  = (const int*)d_in[16];
  const int*   sh1     = (const int*)d_in[17];
  const int*   sh2     = (const int*)d_in[18];

  // ---- workspace layout (float offsets), total ~56.2M floats = 224.8MB ----
  float* ws = (float*)d_ws;
  ushort* embA_bf = (ushort*)ws;                   // [0, 8M)   16M ushorts
  ushort* embB_bf = (ushort*)(ws + 8000000);       // [8M, 16M)
  uint2*  QUADP   = (uint2*)(ws + 16000000);       // [16M, 28.8M) dead after quad
  uint*   NEGPb   = (uint*)(ws + 16000000);        //   overlay: written at l=1 dual
  float*  uraw    = ws + 22400000;                 //   overlay: fp32 users scratch
  uint*   NEGPa   = (uint*)(ws + 28800000);        // [28.8M, 35.2M)
  ushort* u1s     = (ushort*)(ws + 35200000);      // [35.2M, 38.4M) dead after comb
  ushort* u2s     = (ushort*)(ws + 38400000);      // [38.4M, 41.6M) dead after comb
  int2*   cvA2    = (int2*)(ws + 35200000);        //   overlay: built after comb
  int*    ptrA2   = (int*)(ws + 39200000);         //   overlay (inside u2s region)
  uint*   SOCPt   = (uint*)(ws + 41600000);        // [41.6M, 48M) dead after negmap
  ushort* n1o     = (ushort*)(ws + 41600000);      //   overlay: written by quadS
  ushort* UCb     = (ushort*)(ws + 41600000);      //   overlay: written by comb_gemm
  ushort* n2o     = (ushort*)(ws + 44800000);      //   overlay: written by quadS
  int2*   cvA     = (int2*)(ws + 48000000);        // [48M, 52M)
  int2*   cvS     = (int2*)(ws + 52000000);        // [52M, 53.6M)
  int*    ptrA    = (int*)(ws + 53600000);         // 250001
  int*    ptrS    = ptrA + (NTOT + 1);             // 100001
  int*    cnt     = ptrS + (NU + 1);               // 250000
  int*    bsum    = cnt + NTOT;                    // 256
  float*  c1r     = (float*)(bsum + 256);          // 64
  float*  c2r     = c1r + 64;
  float*  w1      = c2r + 64;
  float*  w2      = w1 + 64;
  float*  sumsq   = w2 + 64;                       // 1 -> ~54,200,516
  int*    rank    = (int*)(ws + 54200520);         // 2,000,000 ints -> 56,200,520

  float* out        = (float*)d_out;
  float* out_logits = out + (size_t)NTOT * DD;

  auto build = [&](const int* rows, const int* cols, const float* vals,
                   int n, int nnz, int* ptr, int2* cv) {
    int nb = (n + SCAN_CHUNK - 1) / SCAN_CHUNK;
    int gb = (nnz + 2047) / 2048;  // 256 thr x 8 edges
    hipMemsetAsync(cnt, 0, (size_t)n * sizeof(int), stream);
    k_hist_rank<<<gb, 256, 0, stream>>>(rows, cnt, rank, nnz);
    k_scan1<<<nb, 256, 0, stream>>>(cnt, bsum, n);
    k_scan2<<<1, 256, 0, stream>>>(bsum, nb);
    k_scan3<<<nb, 256, 0, stream>>>(cnt, bsum, ptr, n, nnz);
    k_scatter2<<<gb, 256, 0, stream>>>(rows, cols, vals, ptr, rank, cv, nnz);
  };

  // ---------- CSR builds (S, A) ----------
  build(S_rows, S_cols, S_vals, NU, NNZ_S, ptrS, cvS);
  build(A_rows, A_cols, A_vals, NTOT, NNZ_A, ptrA, cvA);

  // ---------- init + pre-transform (dense) + neg remap into QUADP ----------
  hipMemsetAsync(c1r, 0, 128 * sizeof(float), stream);
  k_init<<<2048, 256, 0, stream>>>(u1, u2, item, embA_bf, out);
  k_transform<<<1024, 256, 0, stream>>>(u1, u2, Wc, SOCPt);
  k_negmap<<<1024, 256, 0, stream>>>(SOCPt, sh1, sh2, QUADP);

  // ---------- quad gather: socials + layer-0 negs + layer-1 table ----------
  k_quadS<<<2048, 256, 0, stream>>>(ptrS, cvS, QUADP, Wc,
                                    u1s, u2s, n1o, n2o, NEGPa);
  k_colsum2<<<256, 256, 0, stream>>>(u1s, u2s, c1r, c2r);
  k_wvec<<<1, 64, 0, stream>>>(fk_W, c1r, c2r, w1, w2);
  k_logits4<<<1024, 256, 0, stream>>>(u1s, u2s, n1o, n2o, w1, w2, fk_b, out_logits);
  k_comb_gemm<<<1024, 256, 0, stream>>>(u1s, u2s, Ws, UCb);

  // A2 CSR into the dead u1s/u2s region (persistent for layers 1,2)
  build(A2_rows, A2_cols, A2_vals, NTOT, NNZ_A, ptrA2, cvA2);

  // ---------- layer loop ----------
  ushort* embCur = embA_bf;
  ushort* embNext = embB_bf;
  for (int l = 0; l < 3; ++l) {
    const int* pA = (l == 0) ? ptrA : ptrA2;
    const int2* cA = (l == 0) ? cvA : cvA2;

    k_spmm_fusedA2<<<4096, 256, 0, stream>>>(pA, cA, embCur, Wi, embNext, out);

    if (l == 1)  // false-logits slot 4 + table for layer 2
      k_dualS<<<2048, 256, 0, stream>>>(ptrS, cvS, NEGPa, Wc, w2, w1, fk_b,
                                        out_logits, 4, NEGPb);
    else if (l == 2)  // false-logits slot 5, no next table
      k_dualS<<<2048, 256, 0, stream>>>(ptrS, cvS, NEGPb, Wc, w2, w1, fk_b,
                                        out_logits, 5, (uint*)nullptr);

    hipMemsetAsync(sumsq, 0, sizeof(float), stream);
    k_users<<<1024, 256, 0, stream>>>(embNext, UCb, Ws, uraw, sumsq);
    k_users_acc<<<2048, 256, 0, stream>>>(uraw, sumsq, out);

    { ushort* t = embCur; embCur = embNext; embNext = t; }
  }
}

// Round 13
// 1550.891 us; speedup vs baseline: 1.9705x; 1.0654x over previous
//
#include <hip/hip_runtime.h>

#define NU 100000
#define NI 150000
#define NTOT 250000
#define DD 64
#define NNZ_A 2000000
#define NNZ_S 800000
#define SCAN_CHUNK 2048  // 256 threads x 8

typedef unsigned int uint;
typedef unsigned short ushort;

// launch bounds for gemm-style kernels: 256 threads, >=4 waves/EU -> 128 VGPR
#define LB __launch_bounds__(256, 4)

// ================= helpers =================
#define RDLANE_F(x, k) __uint_as_float(__builtin_amdgcn_readlane(__float_as_uint(x), (unsigned)(k)))
#define RFL(x) __builtin_amdgcn_readfirstlane(x)

__device__ __forceinline__ uint f2bf_bits(float x) {  // RNE round to bf16 (upper 16)
  uint a = __float_as_uint(x);
  return (a + 0x7fffu + ((a >> 16) & 1u)) >> 16;
}
__device__ __forceinline__ ushort f2bf(float x) { return (ushort)f2bf_bits(x); }
__device__ __forceinline__ float bf2f(ushort h) { return __uint_as_float(((uint)h) << 16); }
__device__ __forceinline__ uint pack_bf16x2(float lo, float hi) {
  return f2bf_bits(lo) | (f2bf_bits(hi) << 16);
}
__device__ __forceinline__ float unpk_lo(uint p) { return __uint_as_float(p << 16); }
__device__ __forceinline__ float unpk_hi(uint p) { return __uint_as_float(p & 0xffff0000u); }

// fast tanh: 1 - 2/(e^{2x}+1). Exact at +-inf; abs err ~1e-7 (<< bf16 rounding).
__device__ __forceinline__ float tanh_fast(float x) {
  float e = __expf(2.0f * x);
  return 1.0f - __fdividef(2.0f, e + 1.0f);
}

// ---- 64x64 GEMM, transposed-W LDS form (R10-proven readlane broadcast).
__device__ __forceinline__ void gemm64x2_lds(float aA, float aB,
                                             const float* __restrict__ Wt, int lane,
                                             float& oA, float& oB) {
  oA = 0.f; oB = 0.f;
#pragma unroll 16
  for (int k = 0; k < 64; ++k) {
    float wk = Wt[k * 65 + lane];
    oA = fmaf(RDLANE_F(aA, k), wk, oA);
    oB = fmaf(RDLANE_F(aB, k), wk, oB);
  }
}

__device__ __forceinline__ float gemm64x1_lds(float a, const float* __restrict__ Wt,
                                              int lane) {
  float s = 0.f;
#pragma unroll 16
  for (int k = 0; k < 64; ++k)
    s = fmaf(RDLANE_F(a, k), Wt[k * 65 + lane], s);
  return s;
}

// stage Wt[k*65+j] = W[j][k] from row-major W[j*64+k]
__device__ __forceinline__ void stage_wt(const float* __restrict__ W, float* __restrict__ Wt) {
  for (int idx = threadIdx.x; idx < 64 * 64; idx += blockDim.x)
    Wt[(idx & 63) * 65 + (idx >> 6)] = W[idx];
  __syncthreads();
}

// ---------- init: emb_bf = [(u1+u2)/2 ; item]; out = 0.25 * same ----------
__global__ void k_init(const float* __restrict__ u1, const float* __restrict__ u2,
                       const float* __restrict__ item, ushort* __restrict__ emb_bf,
                       float* __restrict__ out_final) {
  int idx = blockIdx.x * blockDim.x + threadIdx.x;
  const int tot = NTOT * DD;
  const int nu = NU * DD;
  for (; idx < tot; idx += gridDim.x * blockDim.x) {
    float v;
    if (idx < nu) v = 0.5f * (u1[idx] + u2[idx]);
    else          v = item[idx - nu];
    emb_bf[idx] = f2bf(v);
    out_final[idx] = 0.25f * v;
  }
}

// ================= CSR build (counting sort, rank-in-hist) =================
__global__ void k_hist_rank(const int* __restrict__ rows, int* __restrict__ cnt,
                            int* __restrict__ rank, int nnz) {
  int tid = blockIdx.x * blockDim.x + threadIdx.x;
  int gsz = gridDim.x * blockDim.x;
  for (int b = tid; b < nnz; b += gsz * 8) {
#pragma unroll
    for (int u = 0; u < 8; ++u) {
      int i = b + u * gsz;
      if (i < nnz) rank[i] = atomicAdd(&cnt[rows[i]], 1);
    }
  }
}

__global__ void k_scan1(const int* __restrict__ cnt, int* __restrict__ bsum, int n) {
  __shared__ int sdata[256];
  int base = blockIdx.x * SCAN_CHUNK;
  int s = 0;
#pragma unroll
  for (int k = 0; k < 8; ++k) {
    int i = base + threadIdx.x * 8 + k;
    s += (i < n) ? cnt[i] : 0;
  }
  sdata[threadIdx.x] = s;
  __syncthreads();
  for (int off = 128; off > 0; off >>= 1) {
    if (threadIdx.x < off) sdata[threadIdx.x] += sdata[threadIdx.x + off];
    __syncthreads();
  }
  if (threadIdx.x == 0) bsum[blockIdx.x] = sdata[0];
}

__global__ void k_scan2(int* bsum, int nb) {
  __shared__ int sdata[256];
  int v = (threadIdx.x < nb) ? bsum[threadIdx.x] : 0;
  sdata[threadIdx.x] = v;
  __syncthreads();
  for (int off = 1; off < 256; off <<= 1) {
    int t = (threadIdx.x >= (unsigned)off) ? sdata[threadIdx.x - off] : 0;
    __syncthreads();
    sdata[threadIdx.x] += t;
    __syncthreads();
  }
  if (threadIdx.x < nb) bsum[threadIdx.x] = sdata[threadIdx.x] - v;
}

__global__ void k_scan3(const int* __restrict__ cnt, const int* __restrict__ bsum,
                        int* __restrict__ rowptr, int n, int nnz) {
  __shared__ int sdata[256];
  int base = blockIdx.x * SCAN_CHUNK;
  int loc[8];
  int s = 0;
#pragma unroll
  for (int k = 0; k < 8; ++k) {
    int i = base + threadIdx.x * 8 + k;
    loc[k] = (i < n) ? cnt[i] : 0;
    s += loc[k];
  }
  sdata[threadIdx.x] = s;
  __syncthreads();
  for (int off = 1; off < 256; off <<= 1) {
    int t = (threadIdx.x >= (unsigned)off) ? sdata[threadIdx.x - off] : 0;
    __syncthreads();
    sdata[threadIdx.x] += t;
    __syncthreads();
  }
  int pre = bsum[blockIdx.x] + sdata[threadIdx.x] - s;
#pragma unroll
  for (int k = 0; k < 8; ++k) {
    int i = base + threadIdx.x * 8 + k;
    if (i < n) { rowptr[i] = pre; pre += loc[k]; }
  }
  if (blockIdx.x == 0 && threadIdx.x == 0) rowptr[n] = nnz;
}

__global__ void k_scatter2(const int* __restrict__ rows, const int* __restrict__ cols,
                           const float* __restrict__ vals, const int* __restrict__ ptr,
                           const int* __restrict__ rank, int2* __restrict__ cv, int nnz) {
  int tid = blockIdx.x * blockDim.x + threadIdx.x;
  int gsz = gridDim.x * blockDim.x;
  for (int b = tid; b < nnz; b += gsz * 8) {
#pragma unroll
    for (int u = 0; u < 8; ++u) {
      int i = b + u * gsz;
      if (i < nnz) {
        int r = rows[i];
        cv[ptr[r] + rank[i]] = make_int2(cols[i], __float_as_int(vals[i]));
      }
    }
  }
}

// ================= dense pre-transform =================
__global__ LB void k_transform(const float* __restrict__ u1, const float* __restrict__ u2,
                               const float* __restrict__ Wc, uint* __restrict__ SOCPt) {
  __shared__ float Wt[64 * 65];
  stage_wt(Wc, Wt);
  int lane = threadIdx.x & 63;
  int wid = (blockIdx.x * blockDim.x + threadIdx.x) >> 6;
  int nw = (gridDim.x * blockDim.x) >> 6;
  for (int i = wid; i < NU; i += nw) {
    float a1 = u1[(size_t)i * DD + lane];
    float a2 = u2[(size_t)i * DD + lane];
    float o1, o2;
    gemm64x2_lds(a1, a2, Wt, lane, o1, o2);
    SOCPt[(size_t)i * DD + lane] = pack_bf16x2(o1, o2);
  }
}

// QUADP[i] = { SOCPt[i], lo16(SOCPt[s1[i]]) | hi16(SOCPt[s2[i]]) }
__global__ void k_negmap(const uint* __restrict__ SOCPt, const int* __restrict__ s1,
                         const int* __restrict__ s2, uint2* __restrict__ QUADP) {
  int idx = blockIdx.x * blockDim.x + threadIdx.x;
  const int tot = NU * DD;
  for (; idx < tot; idx += gridDim.x * blockDim.x) {
    int i = idx >> 6, j = idx & 63;
    uint soc = SOCPt[idx];
    uint lo = SOCPt[(size_t)s1[i] * DD + j];
    uint hi = SOCPt[(size_t)s2[i] * DD + j];
    QUADP[idx] = make_uint2(soc, (lo & 0xffffu) | (hi & 0xffff0000u));
  }
}

// ================= gather kernels =================
// Edge lists are wave-uniform: readfirstlane(start/end) forces SGPR chains ->
// compiler emits s_load_dwordx* for cv edges (8/batch), SALU table-base math,
// saddr-form gathers with loop-invariant lane voffset. Zero per-edge VALU
// broadcast work. cv arrays are padded with 8 zero entries (overshoot-safe).
__global__ LB void k_quadS(const int* __restrict__ rowptr, const int2* __restrict__ cv,
                           const uint2* __restrict__ QUADP, const float* __restrict__ Wc,
                           ushort* __restrict__ u1s, ushort* __restrict__ u2s,
                           ushort* __restrict__ n1o, ushort* __restrict__ n2o,
                           uint* __restrict__ NEGPa) {
  __shared__ float Wt[64 * 65];
  stage_wt(Wc, Wt);
  int lane = threadIdx.x & 63;
  int wid = (blockIdx.x * blockDim.x + threadIdx.x) >> 6;
  int nw = (gridDim.x * blockDim.x) >> 6;
  for (int r = wid; r < NU; r += nw) {
    int start = RFL(rowptr[r]);
    int n = RFL(rowptr[r + 1]) - start;
    float a1 = 0.f, a2 = 0.f, a3 = 0.f, a4 = 0.f;
    for (int k = 0; k < n; k += 8) {
      int2 e[8];
#pragma unroll
      for (int u = 0; u < 8; ++u) e[u] = cv[start + k + u];  // s_load (uniform)
      uint2 q[8];
#pragma unroll
      for (int u = 0; u < 8; ++u)
        q[u] = QUADP[(size_t)(uint)e[u].x * 64u + (uint)lane];  // saddr gather
#pragma unroll
      for (int u = 0; u < 8; ++u) {
        float sv = (k + u < n) ? __int_as_float(e[u].y) : 0.f;  // s_cselect
        a1 = fmaf(sv, unpk_lo(q[u].x), a1);
        a2 = fmaf(sv, unpk_hi(q[u].x), a2);
        a3 = fmaf(sv, unpk_lo(q[u].y), a3);
        a4 = fmaf(sv, unpk_hi(q[u].y), a4);
      }
    }
    float t1 = tanh_fast(a1), t2 = tanh_fast(a2), t3 = tanh_fast(a3), t4 = tanh_fast(a4);
    u1s[(size_t)r * DD + lane] = f2bf(t1);
    u2s[(size_t)r * DD + lane] = f2bf(t2);
    n1o[(size_t)r * DD + lane] = f2bf(t3);
    n2o[(size_t)r * DD + lane] = f2bf(t4);
    float o3, o4;
    gemm64x2_lds(t3, t4, Wt, lane, o3, o4);
    NEGPa[(size_t)r * DD + lane] = pack_bf16x2(o3, o4);
  }
}

// dual: 1 packed-table gather (2 chains); fast-tanh; fused false-logits; optional next table.
__global__ LB void k_dualS(const int* __restrict__ rowptr, const int2* __restrict__ cv,
                           const uint* __restrict__ T, const float* __restrict__ Wc,
                           const float* __restrict__ wva, const float* __restrict__ wvb,
                           const float* __restrict__ fkb, float* __restrict__ out_logits,
                           int slot, uint* __restrict__ Tnext) {
  __shared__ float Wt[64 * 65];
  stage_wt(Wc, Wt);
  int lane = threadIdx.x & 63;
  int wid = (blockIdx.x * blockDim.x + threadIdx.x) >> 6;
  int nw = (gridDim.x * blockDim.x) >> 6;
  float b = fkb[0];
  float wa = wva[lane], wb = wvb[lane];
  for (int r = wid; r < NU; r += nw) {
    int start = RFL(rowptr[r]);
    int n = RFL(rowptr[r + 1]) - start;
    float accA = 0.f, accB = 0.f;
    for (int k = 0; k < n; k += 8) {
      int2 e[8];
#pragma unroll
      for (int u = 0; u < 8; ++u) e[u] = cv[start + k + u];
      uint q[8];
#pragma unroll
      for (int u = 0; u < 8; ++u)
        q[u] = T[(size_t)(uint)e[u].x * 64u + (uint)lane];
#pragma unroll
      for (int u = 0; u < 8; ++u) {
        float sv = (k + u < n) ? __int_as_float(e[u].y) : 0.f;
        accA = fmaf(sv, unpk_lo(q[u]), accA);
        accB = fmaf(sv, unpk_hi(q[u]), accB);
      }
    }
    float ta = tanh_fast(accA), tb = tanh_fast(accB);
    float pa = ta * wa, pb = tb * wb;
#pragma unroll
    for (int off = 32; off > 0; off >>= 1) {
      pa += __shfl_xor(pa, off);
      pb += __shfl_xor(pb, off);
    }
    if (lane == 0) {
      out_logits[(size_t)(NU + r) * 6 + slot] = pa + b;  // sc4: u1_neg chain
      out_logits[(size_t)r * 6 + slot] = pb + b;          // sc3: u2_neg chain
    }
    if (Tnext) {
      float oa, ob;
      gemm64x2_lds(ta, tb, Wt, lane, oa, ob);
      Tnext[(size_t)r * DD + lane] = pack_bf16x2(oa, ob);
    }
  }
}

// A-type, bf16 table, 2 rows per wave (scalar edge fetch per row).
__global__ LB void k_spmm_fusedA2(const int* __restrict__ rowptr, const int2* __restrict__ cv,
                                  const ushort* __restrict__ X, const float* __restrict__ W,
                                  ushort* __restrict__ embNext, float* __restrict__ outF) {
  __shared__ float Wt[64 * 65];
  stage_wt(W, Wt);
  int lane = threadIdx.x & 63;
  int wid = (blockIdx.x * blockDim.x + threadIdx.x) >> 6;
  int nw = (gridDim.x * blockDim.x) >> 6;
  for (int r = wid * 2; r < NTOT; r += nw * 2) {
    float acc0 = 0.f, acc1 = 0.f;
#pragma unroll
    for (int rr = 0; rr < 2; ++rr) {
      int start = RFL(rowptr[r + rr]);
      int n = RFL(rowptr[r + rr + 1]) - start;
      float a = 0.f;
      for (int k = 0; k < n; k += 8) {
        int2 e[8];
#pragma unroll
        for (int u = 0; u < 8; ++u) e[u] = cv[start + k + u];
        uint h[8];
#pragma unroll
        for (int u = 0; u < 8; ++u)
          h[u] = X[(size_t)(uint)e[u].x * 64u + (uint)lane];
#pragma unroll
        for (int u = 0; u < 8; ++u) {
          float sv = (k + u < n) ? __int_as_float(e[u].y) : 0.f;
          a = fmaf(sv, __uint_as_float(h[u] << 16), a);
        }
      }
      if (rr == 0) acc0 = a; else acc1 = a;
    }
    if (r < NU) {  // NU even: pair never straddles
      float oA, oB;
      gemm64x2_lds(acc0, acc1, Wt, lane, oA, oB);
      embNext[(size_t)r * DD + lane] = f2bf(tanh_fast(oA));
      embNext[(size_t)(r + 1) * DD + lane] = f2bf(tanh_fast(oB));
    } else {
      embNext[(size_t)r * DD + lane] = f2bf(acc0);
      embNext[(size_t)(r + 1) * DD + lane] = f2bf(acc1);
      outF[(size_t)r * DD + lane] += 0.25f * acc0;        // fold final /4
      outF[(size_t)(r + 1) * DD + lane] += 0.25f * acc1;
    }
  }
}

// ---------- fused column sums (bf16 inputs) ----------
__global__ void k_colsum2(const ushort* __restrict__ x1, const ushort* __restrict__ x2,
                          float* __restrict__ c1, float* __restrict__ c2) {
  int lane = threadIdx.x & 63;
  int wid = (blockIdx.x * blockDim.x + threadIdx.x) >> 6;
  int nw = (gridDim.x * blockDim.x) >> 6;
  float a1 = 0.f, a2 = 0.f;
  for (int i = wid; i < NU; i += nw) {
    a1 += bf2f(x1[(size_t)i * DD + lane]);
    a2 += bf2f(x2[(size_t)i * DD + lane]);
  }
  atomicAdd(&c1[lane], a1);
  atomicAdd(&c2[lane], a2);
}

// ---------- w = fk_W @ (csum/NU) ----------
__global__ void k_wvec(const float* __restrict__ fkW, const float* __restrict__ c1r,
                       const float* __restrict__ c2r, float* __restrict__ w1,
                       float* __restrict__ w2) {
  int j = threadIdx.x;
  float a1 = 0.f, a2 = 0.f;
  for (int k = 0; k < 64; ++k) {
    float w = fkW[j * 64 + k];
    a1 += w * c1r[k];
    a2 += w * c2r[k];
  }
  w1[j] = a1 * (1.0f / NU);
  w2[j] = a2 * (1.0f / NU);
}

// ---------- logits: true slots 0-2 + false slot 3 (layer-0 negs) ----------
__global__ void k_logits4(const ushort* __restrict__ u1s, const ushort* __restrict__ u2s,
                          const ushort* __restrict__ n1o, const ushort* __restrict__ n2o,
                          const float* __restrict__ w1, const float* __restrict__ w2,
                          const float* __restrict__ fkb, float* __restrict__ out_logits) {
  int lane = threadIdx.x & 63;
  int wid = (blockIdx.x * blockDim.x + threadIdx.x) >> 6;
  int nw = (gridDim.x * blockDim.x) >> 6;
  float b = fkb[0];
  for (int i = wid; i < 2 * NU; i += nw) {
    bool lo = i < NU;
    int r = lo ? i : i - NU;
    const ushort* xs = lo ? u2s : u1s;
    const ushort* xn = lo ? n2o : n1o;
    const float* wv = lo ? w1 : w2;
    float wvl = wv[lane];
    float ps = bf2f(xs[(size_t)r * DD + lane]) * wvl;
    float pn = bf2f(xn[(size_t)r * DD + lane]) * wvl;
#pragma unroll
    for (int off = 32; off > 0; off >>= 1) {
      ps += __shfl_xor(ps, off);
      pn += __shfl_xor(pn, off);
    }
    if (lane == 0) {
      float vs = ps + b;
      out_logits[(size_t)i * 6 + 0] = vs;
      out_logits[(size_t)i * 6 + 1] = vs;
      out_logits[(size_t)i * 6 + 2] = vs;
      out_logits[(size_t)i * 6 + 3] = pn + b;
    }
  }
}

// ---------- UC[i] = (0.5*(u1s+u2s)) @ Ws[:,64:].T -> bf16 ----------
__global__ LB void k_comb_gemm(const ushort* __restrict__ u1s, const ushort* __restrict__ u2s,
                               const float* __restrict__ Ws, ushort* __restrict__ UC) {
  __shared__ float Wt[64 * 65];
  for (int idx = threadIdx.x; idx < 64 * 64; idx += blockDim.x)
    Wt[(idx & 63) * 65 + (idx >> 6)] = Ws[(idx >> 6) * 128 + 64 + (idx & 63)];
  __syncthreads();
  int lane = threadIdx.x & 63;
  int wid = (blockIdx.x * blockDim.x + threadIdx.x) >> 6;
  int nw = (gridDim.x * blockDim.x) >> 6;
  for (int i = wid; i < NU; i += nw) {
    float c = 0.5f * (bf2f(u1s[(size_t)i * DD + lane]) + bf2f(u2s[(size_t)i * DD + lane]));
    UC[(size_t)i * DD + lane] = f2bf(gemm64x1_lds(c, Wt, lane));
  }
}

// ---------- users_raw = u_next @ Ws[:,:64].T + UC ; sum of squares ----------
__global__ LB void k_users(const ushort* __restrict__ u_next, const ushort* __restrict__ uc,
                           const float* __restrict__ Ws, float* __restrict__ users_raw,
                           float* __restrict__ sumsq) {
  __shared__ float Wt[64 * 65];
  for (int idx = threadIdx.x; idx < 64 * 64; idx += blockDim.x)
    Wt[(idx & 63) * 65 + (idx >> 6)] = Ws[(idx >> 6) * 128 + (idx & 63)];
  __syncthreads();
  int lane = threadIdx.x & 63;
  int wid = (blockIdx.x * blockDim.x + threadIdx.x) >> 6;
  int nw = (gridDim.x * blockDim.x) >> 6;
  float ss = 0.f;
  for (int i = wid; i < NU; i += nw) {
    float va = bf2f(u_next[(size_t)i * DD + lane]);
    float acc = bf2f(uc[(size_t)i * DD + lane]) + gemm64x1_lds(va, Wt, lane);
    users_raw[(size_t)i * DD + lane] = acc;
    ss += acc * acc;
  }
#pragma unroll
  for (int off = 32; off > 0; off >>= 1) ss += __shfl_xor(ss, off);
  if (lane == 0) atomicAdd(sumsq, ss);
}

__global__ void k_users_acc(const float* __restrict__ users_raw,
                            const float* __restrict__ sumsq, float* __restrict__ out_final) {
  float scale = 0.25f / sqrtf(*sumsq);  // fold final /4
  int idx = blockIdx.x * blockDim.x + threadIdx.x;
  for (; idx < NU * DD; idx += gridDim.x * blockDim.x)
    out_final[idx] += users_raw[idx] * scale;
}

extern "C" void kernel_launch(void* const* d_in, const int* in_sizes, int n_in,
                              void* d_out, int out_size, void* d_ws, size_t ws_size,
                              hipStream_t stream) {
  const float* u1      = (const float*)d_in[0];
  const float* u2      = (const float*)d_in[1];
  const float* item    = (const float*)d_in[2];
  const float* Wi      = (const float*)d_in[3];
  const float* Wc      = (const float*)d_in[4];
  const float* Ws      = (const float*)d_in[5];
  const float* fk_W    = (const float*)d_in[6];
  const float* fk_b    = (const float*)d_in[7];
  const float* A_vals  = (const float*)d_in[8];
  const float* A2_vals = (const float*)d_in[9];
  const float* S_vals  = (const float*)d_in[10];
  const int*   A_rows  = (const int*)d_in[11];
  const int*   A_cols  = (const int*)d_in[12];
  const int*   A2_rows = (const int*)d_in[13];
  const int*   A2_cols = (const int*)d_in[14];
  const int*   S_rows  = (const int*)d_in[15];
  const int*   S_cols  = (const int*)d_in[16];
  const int*   sh1     = (const int*)d_in[17];
  const int*   sh2     = (const int*)d_in[18];

  // ---- workspace layout (float offsets); cv arrays padded +8 int2 ----
  float* ws = (float*)d_ws;
  ushort* embA_bf = (ushort*)ws;                   // [0, 8M)   16M ushorts
  ushort* embB_bf = (ushort*)(ws + 8000000);       // [8M, 16M)
  uint2*  QUADP   = (uint2*)(ws + 16000000);       // [16M, 28.8M) dead after quad
  uint*   NEGPb   = (uint*)(ws + 16000000);        //   overlay: written at l=1 dual
  float*  uraw    = ws + 22400000;                 //   overlay: fp32 users scratch
  uint*   NEGPa   = (uint*)(ws + 28800000);        // [28.8M, 35.2M)
  ushort* u1s     = (ushort*)(ws + 35200000);      // [35.2M, 38.4M) dead after comb
  ushort* u2s     = (ushort*)(ws + 38400000);      // [38.4M, 41.6M) dead after comb
  int2*   cvA2    = (int2*)(ws + 35200000);        //   overlay: 2,000,008 int2 -> 39,200,016
  int*    ptrA2   = (int*)(ws + 39200016);         //   overlay (250,001 -> 39,262,517)
  uint*   SOCPt   = (uint*)(ws + 41600000);        // [41.6M, 48M) dead after negmap
  ushort* n1o     = (ushort*)(ws + 41600000);      //   overlay: written by quadS
  ushort* UCb     = (ushort*)(ws + 41600000);      //   overlay: written by comb_gemm
  ushort* n2o     = (ushort*)(ws + 44800000);      //   overlay: written by quadS
  int2*   cvA     = (int2*)(ws + 48000000);        // 2,000,008 int2 -> 52,000,016
  int2*   cvS     = (int2*)(ws + 52000016);        // 800,008 int2 -> 53,600,032
  int*    ptrA    = (int*)(ws + 53600032);         // 250,001
  int*    ptrS    = ptrA + (NTOT + 1);             // 100,001
  int*    cnt     = ptrS + (NU + 1);               // 250,000
  int*    bsum    = cnt + NTOT;                    // 256
  float*  c1r     = (float*)(bsum + 256);          // 64
  float*  c2r     = c1r + 64;
  float*  w1      = c2r + 64;
  float*  w2      = w1 + 64;
  float*  sumsq   = w2 + 64;                       // 1
  int*    rank    = (int*)(ws + 54200580);         // 2,000,000 -> 56,200,580 (224.8MB)

  float* out        = (float*)d_out;
  float* out_logits = out + (size_t)NTOT * DD;

  auto build = [&](const int* rows, const int* cols, const float* vals,
                   int n, int nnz, int* ptr, int2* cv) {
    int nb = (n + SCAN_CHUNK - 1) / SCAN_CHUNK;
    int gb = (nnz + 2047) / 2048;  // 256 thr x 8 edges
    hipMemsetAsync(cnt, 0, (size_t)n * sizeof(int), stream);
    k_hist_rank<<<gb, 256, 0, stream>>>(rows, cnt, rank, nnz);
    k_scan1<<<nb, 256, 0, stream>>>(cnt, bsum, n);
    k_scan2<<<1, 256, 0, stream>>>(bsum, nb);
    k_scan3<<<nb, 256, 0, stream>>>(cnt, bsum, ptr, n, nnz);
    k_scatter2<<<gb, 256, 0, stream>>>(rows, cols, vals, ptr, rank, cv, nnz);
    hipMemsetAsync(cv + nnz, 0, 8 * sizeof(int2), stream);  // overshoot pad
  };

  // ---------- CSR builds (S, A) ----------
  build(S_rows, S_cols, S_vals, NU, NNZ_S, ptrS, cvS);
  build(A_rows, A_cols, A_vals, NTOT, NNZ_A, ptrA, cvA);

  // ---------- init + pre-transform (dense) + neg remap into QUADP ----------
  hipMemsetAsync(c1r, 0, 128 * sizeof(float), stream);
  k_init<<<2048, 256, 0, stream>>>(u1, u2, item, embA_bf, out);
  k_transform<<<1024, 256, 0, stream>>>(u1, u2, Wc, SOCPt);
  k_negmap<<<1024, 256, 0, stream>>>(SOCPt, sh1, sh2, QUADP);

  // ---------- quad gather: socials + layer-0 negs + layer-1 table ----------
  k_quadS<<<2048, 256, 0, stream>>>(ptrS, cvS, QUADP, Wc,
                                    u1s, u2s, n1o, n2o, NEGPa);
  k_colsum2<<<256, 256, 0, stream>>>(u1s, u2s, c1r, c2r);
  k_wvec<<<1, 64, 0, stream>>>(fk_W, c1r, c2r, w1, w2);
  k_logits4<<<1024, 256, 0, stream>>>(u1s, u2s, n1o, n2o, w1, w2, fk_b, out_logits);
  k_comb_gemm<<<1024, 256, 0, stream>>>(u1s, u2s, Ws, UCb);

  // A2 CSR into the dead u1s/u2s region (persistent for layers 1,2)
  build(A2_rows, A2_cols, A2_vals, NTOT, NNZ_A, ptrA2, cvA2);

  // ---------- layer loop ----------
  ushort* embCur = embA_bf;
  ushort* embNext = embB_bf;
  for (int l = 0; l < 3; ++l) {
    const int* pA = (l == 0) ? ptrA : ptrA2;
    const int2* cA = (l == 0) ? cvA : cvA2;

    k_spmm_fusedA2<<<4096, 256, 0, stream>>>(pA, cA, embCur, Wi, embNext, out);

    if (l == 1)  // false-logits slot 4 + table for layer 2
      k_dualS<<<2048, 256, 0, stream>>>(ptrS, cvS, NEGPa, Wc, w2, w1, fk_b,
                                        out_logits, 4, NEGPb);
    else if (l == 2)  // false-logits slot 5, no next table
      k_dualS<<<2048, 256, 0, stream>>>(ptrS, cvS, NEGPb, Wc, w2, w1, fk_b,
                                        out_logits, 5, (uint*)nullptr);

    hipMemsetAsync(sumsq, 0, sizeof(float), stream);
    k_users<<<1024, 256, 0, stream>>>(embNext, UCb, Ws, uraw, sumsq);
    k_users_acc<<<2048, 256, 0, stream>>>(uraw, sumsq, out);

    { ushort* t = embCur; embCur = embNext; embNext = t; }
  }
}

// Round 14
// 1515.208 us; speedup vs baseline: 2.0169x; 1.0235x over previous
//
#include <hip/hip_runtime.h>

#define NU 100000
#define NI 150000
#define NTOT 250000
#define DD 64
#define NNZ_A 2000000
#define NNZ_S 800000
#define SCAN_CHUNK 2048  // 256 threads x 8

typedef unsigned int uint;
typedef unsigned short ushort;

// launch bounds for gemm-style kernels: 256 threads, >=4 waves/EU -> 128 VGPR
#define LB __launch_bounds__(256, 4)

// ================= helpers =================
#define RFL(x) __builtin_amdgcn_readfirstlane(x)

__device__ __forceinline__ uint f2bf_bits(float x) {  // RNE round to bf16 (upper 16)
  uint a = __float_as_uint(x);
  return (a + 0x7fffu + ((a >> 16) & 1u)) >> 16;
}
__device__ __forceinline__ ushort f2bf(float x) { return (ushort)f2bf_bits(x); }
__device__ __forceinline__ float bf2f(ushort h) { return __uint_as_float(((uint)h) << 16); }
__device__ __forceinline__ uint pack_bf16x2(float lo, float hi) {
  return f2bf_bits(lo) | (f2bf_bits(hi) << 16);
}
__device__ __forceinline__ float unpk_lo(uint p) { return __uint_as_float(p << 16); }
__device__ __forceinline__ float unpk_hi(uint p) { return __uint_as_float(p & 0xffff0000u); }

// fast tanh: 1 - 2/(e^{2x}+1). Exact at +-inf; abs err ~1e-7 (<< bf16 rounding).
__device__ __forceinline__ float tanh_fast(float x) {
  float e = __expf(2.0f * x);
  return 1.0f - __fdividef(2.0f, e + 1.0f);
}

// ---- 64x64 GEMM with LDS-broadcast of the accumulator (per-wave buffer ab).
// Broadcast via uniform ds_read (DS pipe) instead of v_readlane (VALU):
// VALU per k drops 4 -> 2. FENCING (R11 post-mortem, guide rule #18):
//   1) lgkmcnt(0) BEFORE the write  -- WAR: prior row's broadcast reads must
//      complete before overwrite (lgkm completes out of order; compiler only
//      tracks register deps).
//   2) lgkmcnt(0) AFTER the write   -- RAW: writes visible before reads.
//   3) sched_barrier(0)             -- stop hipcc hoisting consumers past asm.
__device__ __forceinline__ void gemm64x2_b(float aA, float aB,
                                           const float* __restrict__ Wt,
                                           volatile float* __restrict__ ab, int lane,
                                           float& oA, float& oB) {
  asm volatile("s_waitcnt lgkmcnt(0)" ::: "memory");
  __builtin_amdgcn_sched_barrier(0);
  ab[lane] = aA;
  ab[64 + lane] = aB;
  asm volatile("s_waitcnt lgkmcnt(0)" ::: "memory");
  __builtin_amdgcn_sched_barrier(0);
  float sA = 0.f, sB = 0.f;
#pragma unroll 4
  for (int k0 = 0; k0 < 64; k0 += 4) {
    float4 a4 = *(const float4*)(const float*)(ab + k0);
    float4 b4 = *(const float4*)(const float*)(ab + 64 + k0);
#pragma unroll
    for (int u = 0; u < 4; ++u) {
      float wk = Wt[(k0 + u) * 65 + lane];
      sA = fmaf(((const float*)&a4)[u], wk, sA);
      sB = fmaf(((const float*)&b4)[u], wk, sB);
    }
  }
  oA = sA; oB = sB;
}

__device__ __forceinline__ float gemm64x1_b(float a, const float* __restrict__ Wt,
                                            volatile float* __restrict__ ab, int lane) {
  asm volatile("s_waitcnt lgkmcnt(0)" ::: "memory");
  __builtin_amdgcn_sched_barrier(0);
  ab[lane] = a;
  asm volatile("s_waitcnt lgkmcnt(0)" ::: "memory");
  __builtin_amdgcn_sched_barrier(0);
  float s = 0.f;
#pragma unroll 4
  for (int k0 = 0; k0 < 64; k0 += 4) {
    float4 a4 = *(const float4*)(const float*)(ab + k0);
#pragma unroll
    for (int u = 0; u < 4; ++u)
      s = fmaf(((const float*)&a4)[u], Wt[(k0 + u) * 65 + lane], s);
  }
  return s;
}

// stage Wt[k*65+j] = W[j][k] from row-major W[j*64+k]
__device__ __forceinline__ void stage_wt(const float* __restrict__ W, float* __restrict__ Wt) {
  for (int idx = threadIdx.x; idx < 64 * 64; idx += blockDim.x)
    Wt[(idx & 63) * 65 + (idx >> 6)] = W[idx];
  __syncthreads();
}

// ---------- init: emb_bf = [(u1+u2)/2 ; item]; out = 0.25 * same ----------
__global__ void k_init(const float* __restrict__ u1, const float* __restrict__ u2,
                       const float* __restrict__ item, ushort* __restrict__ emb_bf,
                       float* __restrict__ out_final) {
  int idx = blockIdx.x * blockDim.x + threadIdx.x;
  const int tot = NTOT * DD;
  const int nu = NU * DD;
  for (; idx < tot; idx += gridDim.x * blockDim.x) {
    float v;
    if (idx < nu) v = 0.5f * (u1[idx] + u2[idx]);
    else          v = item[idx - nu];
    emb_bf[idx] = f2bf(v);
    out_final[idx] = 0.25f * v;
  }
}

// ================= CSR build (counting sort, rank-in-hist) =================
__global__ void k_hist_rank(const int* __restrict__ rows, int* __restrict__ cnt,
                            int* __restrict__ rank, int nnz) {
  int tid = blockIdx.x * blockDim.x + threadIdx.x;
  int gsz = gridDim.x * blockDim.x;
  for (int b = tid; b < nnz; b += gsz * 8) {
#pragma unroll
    for (int u = 0; u < 8; ++u) {
      int i = b + u * gsz;
      if (i < nnz) rank[i] = atomicAdd(&cnt[rows[i]], 1);
    }
  }
}

__global__ void k_scan1(const int* __restrict__ cnt, int* __restrict__ bsum, int n) {
  __shared__ int sdata[256];
  int base = blockIdx.x * SCAN_CHUNK;
  int s = 0;
#pragma unroll
  for (int k = 0; k < 8; ++k) {
    int i = base + threadIdx.x * 8 + k;
    s += (i < n) ? cnt[i] : 0;
  }
  sdata[threadIdx.x] = s;
  __syncthreads();
  for (int off = 128; off > 0; off >>= 1) {
    if (threadIdx.x < off) sdata[threadIdx.x] += sdata[threadIdx.x + off];
    __syncthreads();
  }
  if (threadIdx.x == 0) bsum[blockIdx.x] = sdata[0];
}

__global__ void k_scan2(int* bsum, int nb) {
  __shared__ int sdata[256];
  int v = (threadIdx.x < nb) ? bsum[threadIdx.x] : 0;
  sdata[threadIdx.x] = v;
  __syncthreads();
  for (int off = 1; off < 256; off <<= 1) {
    int t = (threadIdx.x >= (unsigned)off) ? sdata[threadIdx.x - off] : 0;
    __syncthreads();
    sdata[threadIdx.x] += t;
    __syncthreads();
  }
  if (threadIdx.x < nb) bsum[threadIdx.x] = sdata[threadIdx.x] - v;
}

__global__ void k_scan3(const int* __restrict__ cnt, const int* __restrict__ bsum,
                        int* __restrict__ rowptr, int n, int nnz) {
  __shared__ int sdata[256];
  int base = blockIdx.x * SCAN_CHUNK;
  int loc[8];
  int s = 0;
#pragma unroll
  for (int k = 0; k < 8; ++k) {
    int i = base + threadIdx.x * 8 + k;
    loc[k] = (i < n) ? cnt[i] : 0;
    s += loc[k];
  }
  sdata[threadIdx.x] = s;
  __syncthreads();
  for (int off = 1; off < 256; off <<= 1) {
    int t = (threadIdx.x >= (unsigned)off) ? sdata[threadIdx.x - off] : 0;
    __syncthreads();
    sdata[threadIdx.x] += t;
    __syncthreads();
  }
  int pre = bsum[blockIdx.x] + sdata[threadIdx.x] - s;
#pragma unroll
  for (int k = 0; k < 8; ++k) {
    int i = base + threadIdx.x * 8 + k;
    if (i < n) { rowptr[i] = pre; pre += loc[k]; }
  }
  if (blockIdx.x == 0 && threadIdx.x == 0) rowptr[n] = nnz;
}

__global__ void k_scatter2(const int* __restrict__ rows, const int* __restrict__ cols,
                           const float* __restrict__ vals, const int* __restrict__ ptr,
                           const int* __restrict__ rank, int2* __restrict__ cv, int nnz) {
  int tid = blockIdx.x * blockDim.x + threadIdx.x;
  int gsz = gridDim.x * blockDim.x;
  for (int b = tid; b < nnz; b += gsz * 8) {
#pragma unroll
    for (int u = 0; u < 8; ++u) {
      int i = b + u * gsz;
      if (i < nnz) {
        int r = rows[i];
        cv[ptr[r] + rank[i]] = make_int2(cols[i], __float_as_int(vals[i]));
      }
    }
  }
}

// ================= dense pre-transform =================
__global__ LB void k_transform(const float* __restrict__ u1, const float* __restrict__ u2,
                               const float* __restrict__ Wc, uint* __restrict__ SOCPt) {
  __shared__ float Wt[64 * 65];
  __shared__ float AB[4][128];
  stage_wt(Wc, Wt);
  int lane = threadIdx.x & 63;
  volatile float* ab = AB[threadIdx.x >> 6];
  int wid = (blockIdx.x * blockDim.x + threadIdx.x) >> 6;
  int nw = (gridDim.x * blockDim.x) >> 6;
  for (int i = wid; i < NU; i += nw) {
    float a1 = u1[(size_t)i * DD + lane];
    float a2 = u2[(size_t)i * DD + lane];
    float o1, o2;
    gemm64x2_b(a1, a2, Wt, ab, lane, o1, o2);
    SOCPt[(size_t)i * DD + lane] = pack_bf16x2(o1, o2);
  }
}

// QUADP[i] = { SOCPt[i], lo16(SOCPt[s1[i]]) | hi16(SOCPt[s2[i]]) }
__global__ void k_negmap(const uint* __restrict__ SOCPt, const int* __restrict__ s1,
                         const int* __restrict__ s2, uint2* __restrict__ QUADP) {
  int idx = blockIdx.x * blockDim.x + threadIdx.x;
  const int tot = NU * DD;
  for (; idx < tot; idx += gridDim.x * blockDim.x) {
    int i = idx >> 6, j = idx & 63;
    uint soc = SOCPt[idx];
    uint lo = SOCPt[(size_t)s1[i] * DD + j];
    uint hi = SOCPt[(size_t)s2[i] * DD + j];
    QUADP[idx] = make_uint2(soc, (lo & 0xffffu) | (hi & 0xffff0000u));
  }
}

// ================= gather kernels =================
// Edge lists wave-uniform (RFL -> SGPR chains, s_load edges, saddr gathers).
__global__ LB void k_quadS(const int* __restrict__ rowptr, const int2* __restrict__ cv,
                           const uint2* __restrict__ QUADP, const float* __restrict__ Wc,
                           ushort* __restrict__ u1s, ushort* __restrict__ u2s,
                           ushort* __restrict__ n1o, ushort* __restrict__ n2o,
                           uint* __restrict__ NEGPa) {
  __shared__ float Wt[64 * 65];
  __shared__ float AB[4][128];
  stage_wt(Wc, Wt);
  int lane = threadIdx.x & 63;
  volatile float* ab = AB[threadIdx.x >> 6];
  int wid = (blockIdx.x * blockDim.x + threadIdx.x) >> 6;
  int nw = (gridDim.x * blockDim.x) >> 6;
  for (int r = wid; r < NU; r += nw) {
    int start = RFL(rowptr[r]);
    int n = RFL(rowptr[r + 1]) - start;
    float a1 = 0.f, a2 = 0.f, a3 = 0.f, a4 = 0.f;
    for (int k = 0; k < n; k += 8) {
      int2 e[8];
#pragma unroll
      for (int u = 0; u < 8; ++u) e[u] = cv[start + k + u];  // s_load (uniform)
      uint2 q[8];
#pragma unroll
      for (int u = 0; u < 8; ++u)
        q[u] = QUADP[(size_t)(uint)e[u].x * 64u + (uint)lane];  // saddr gather
#pragma unroll
      for (int u = 0; u < 8; ++u) {
        float sv = (k + u < n) ? __int_as_float(e[u].y) : 0.f;  // s_cselect
        a1 = fmaf(sv, unpk_lo(q[u].x), a1);
        a2 = fmaf(sv, unpk_hi(q[u].x), a2);
        a3 = fmaf(sv, unpk_lo(q[u].y), a3);
        a4 = fmaf(sv, unpk_hi(q[u].y), a4);
      }
    }
    float t1 = tanh_fast(a1), t2 = tanh_fast(a2), t3 = tanh_fast(a3), t4 = tanh_fast(a4);
    u1s[(size_t)r * DD + lane] = f2bf(t1);
    u2s[(size_t)r * DD + lane] = f2bf(t2);
    n1o[(size_t)r * DD + lane] = f2bf(t3);
    n2o[(size_t)r * DD + lane] = f2bf(t4);
    float o3, o4;
    gemm64x2_b(t3, t4, Wt, ab, lane, o3, o4);
    NEGPa[(size_t)r * DD + lane] = pack_bf16x2(o3, o4);
  }
}

// dual: 1 packed-table gather (2 chains); fast-tanh; fused false-logits; optional next table.
__global__ LB void k_dualS(const int* __restrict__ rowptr, const int2* __restrict__ cv,
                           const uint* __restrict__ T, const float* __restrict__ Wc,
                           const float* __restrict__ wva, const float* __restrict__ wvb,
                           const float* __restrict__ fkb, float* __restrict__ out_logits,
                           int slot, uint* __restrict__ Tnext) {
  __shared__ float Wt[64 * 65];
  __shared__ float AB[4][128];
  stage_wt(Wc, Wt);
  int lane = threadIdx.x & 63;
  volatile float* ab = AB[threadIdx.x >> 6];
  int wid = (blockIdx.x * blockDim.x + threadIdx.x) >> 6;
  int nw = (gridDim.x * blockDim.x) >> 6;
  float b = fkb[0];
  float wa = wva[lane], wb = wvb[lane];
  for (int r = wid; r < NU; r += nw) {
    int start = RFL(rowptr[r]);
    int n = RFL(rowptr[r + 1]) - start;
    float accA = 0.f, accB = 0.f;
    for (int k = 0; k < n; k += 8) {
      int2 e[8];
#pragma unroll
      for (int u = 0; u < 8; ++u) e[u] = cv[start + k + u];
      uint q[8];
#pragma unroll
      for (int u = 0; u < 8; ++u)
        q[u] = T[(size_t)(uint)e[u].x * 64u + (uint)lane];
#pragma unroll
      for (int u = 0; u < 8; ++u) {
        float sv = (k + u < n) ? __int_as_float(e[u].y) : 0.f;
        accA = fmaf(sv, unpk_lo(q[u]), accA);
        accB = fmaf(sv, unpk_hi(q[u]), accB);
      }
    }
    float ta = tanh_fast(accA), tb = tanh_fast(accB);
    float pa = ta * wa, pb = tb * wb;
#pragma unroll
    for (int off = 32; off > 0; off >>= 1) {
      pa += __shfl_xor(pa, off);
      pb += __shfl_xor(pb, off);
    }
    if (lane == 0) {
      out_logits[(size_t)(NU + r) * 6 + slot] = pa + b;  // sc4: u1_neg chain
      out_logits[(size_t)r * 6 + slot] = pb + b;          // sc3: u2_neg chain
    }
    if (Tnext) {
      float oa, ob;
      gemm64x2_b(ta, tb, Wt, ab, lane, oa, ob);
      Tnext[(size_t)r * DD + lane] = pack_bf16x2(oa, ob);
    }
  }
}

// A-type, bf16 table, 2 rows per wave (scalar edge fetch per row).
__global__ LB void k_spmm_fusedA2(const int* __restrict__ rowptr, const int2* __restrict__ cv,
                                  const ushort* __restrict__ X, const float* __restrict__ W,
                                  ushort* __restrict__ embNext, float* __restrict__ outF) {
  __shared__ float Wt[64 * 65];
  __shared__ float AB[4][128];
  stage_wt(W, Wt);
  int lane = threadIdx.x & 63;
  volatile float* ab = AB[threadIdx.x >> 6];
  int wid = (blockIdx.x * blockDim.x + threadIdx.x) >> 6;
  int nw = (gridDim.x * blockDim.x) >> 6;
  for (int r = wid * 2; r < NTOT; r += nw * 2) {
    float acc0 = 0.f, acc1 = 0.f;
#pragma unroll
    for (int rr = 0; rr < 2; ++rr) {
      int start = RFL(rowptr[r + rr]);
      int n = RFL(rowptr[r + rr + 1]) - start;
      float a = 0.f;
      for (int k = 0; k < n; k += 8) {
        int2 e[8];
#pragma unroll
        for (int u = 0; u < 8; ++u) e[u] = cv[start + k + u];
        uint h[8];
#pragma unroll
        for (int u = 0; u < 8; ++u)
          h[u] = X[(size_t)(uint)e[u].x * 64u + (uint)lane];
#pragma unroll
        for (int u = 0; u < 8; ++u) {
          float sv = (k + u < n) ? __int_as_float(e[u].y) : 0.f;
          a = fmaf(sv, __uint_as_float(h[u] << 16), a);
        }
      }
      if (rr == 0) acc0 = a; else acc1 = a;
    }
    if (r < NU) {  // NU even: pair never straddles
      float oA, oB;
      gemm64x2_b(acc0, acc1, Wt, ab, lane, oA, oB);
      embNext[(size_t)r * DD + lane] = f2bf(tanh_fast(oA));
      embNext[(size_t)(r + 1) * DD + lane] = f2bf(tanh_fast(oB));
    } else {
      embNext[(size_t)r * DD + lane] = f2bf(acc0);
      embNext[(size_t)(r + 1) * DD + lane] = f2bf(acc1);
      outF[(size_t)r * DD + lane] += 0.25f * acc0;        // fold final /4
      outF[(size_t)(r + 1) * DD + lane] += 0.25f * acc1;
    }
  }
}

// ---------- fused column sums (bf16 inputs) ----------
__global__ void k_colsum2(const ushort* __restrict__ x1, const ushort* __restrict__ x2,
                          float* __restrict__ c1, float* __restrict__ c2) {
  int lane = threadIdx.x & 63;
  int wid = (blockIdx.x * blockDim.x + threadIdx.x) >> 6;
  int nw = (gridDim.x * blockDim.x) >> 6;
  float a1 = 0.f, a2 = 0.f;
  for (int i = wid; i < NU; i += nw) {
    a1 += bf2f(x1[(size_t)i * DD + lane]);
    a2 += bf2f(x2[(size_t)i * DD + lane]);
  }
  atomicAdd(&c1[lane], a1);
  atomicAdd(&c2[lane], a2);
}

// ---------- w = fk_W @ (csum/NU) ----------
__global__ void k_wvec(const float* __restrict__ fkW, const float* __restrict__ c1r,
                       const float* __restrict__ c2r, float* __restrict__ w1,
                       float* __restrict__ w2) {
  int j = threadIdx.x;
  float a1 = 0.f, a2 = 0.f;
  for (int k = 0; k < 64; ++k) {
    float w = fkW[j * 64 + k];
    a1 += w * c1r[k];
    a2 += w * c2r[k];
  }
  w1[j] = a1 * (1.0f / NU);
  w2[j] = a2 * (1.0f / NU);
}

// ---------- logits: true slots 0-2 + false slot 3 (layer-0 negs) ----------
__global__ void k_logits4(const ushort* __restrict__ u1s, const ushort* __restrict__ u2s,
                          const ushort* __restrict__ n1o, const ushort* __restrict__ n2o,
                          const float* __restrict__ w1, const float* __restrict__ w2,
                          const float* __restrict__ fkb, float* __restrict__ out_logits) {
  int lane = threadIdx.x & 63;
  int wid = (blockIdx.x * blockDim.x + threadIdx.x) >> 6;
  int nw = (gridDim.x * blockDim.x) >> 6;
  float b = fkb[0];
  for (int i = wid; i < 2 * NU; i += nw) {
    bool lo = i < NU;
    int r = lo ? i : i - NU;
    const ushort* xs = lo ? u2s : u1s;
    const ushort* xn = lo ? n2o : n1o;
    const float* wv = lo ? w1 : w2;
    float wvl = wv[lane];
    float ps = bf2f(xs[(size_t)r * DD + lane]) * wvl;
    float pn = bf2f(xn[(size_t)r * DD + lane]) * wvl;
#pragma unroll
    for (int off = 32; off > 0; off >>= 1) {
      ps += __shfl_xor(ps, off);
      pn += __shfl_xor(pn, off);
    }
    if (lane == 0) {
      float vs = ps + b;
      out_logits[(size_t)i * 6 + 0] = vs;
      out_logits[(size_t)i * 6 + 1] = vs;
      out_logits[(size_t)i * 6 + 2] = vs;
      out_logits[(size_t)i * 6 + 3] = pn + b;
    }
  }
}

// ---------- UC[i] = (0.5*(u1s+u2s)) @ Ws[:,64:].T -> bf16 ----------
__global__ LB void k_comb_gemm(const ushort* __restrict__ u1s, const ushort* __restrict__ u2s,
                               const float* __restrict__ Ws, ushort* __restrict__ UC) {
  __shared__ float Wt[64 * 65];
  __shared__ float AB[4][128];
  for (int idx = threadIdx.x; idx < 64 * 64; idx += blockDim.x)
    Wt[(idx & 63) * 65 + (idx >> 6)] = Ws[(idx >> 6) * 128 + 64 + (idx & 63)];
  __syncthreads();
  int lane = threadIdx.x & 63;
  volatile float* ab = AB[threadIdx.x >> 6];
  int wid = (blockIdx.x * blockDim.x + threadIdx.x) >> 6;
  int nw = (gridDim.x * blockDim.x) >> 6;
  for (int i = wid; i < NU; i += nw) {
    float c = 0.5f * (bf2f(u1s[(size_t)i * DD + lane]) + bf2f(u2s[(size_t)i * DD + lane]));
    UC[(size_t)i * DD + lane] = f2bf(gemm64x1_b(c, Wt, ab, lane));
  }
}

// ---------- users_raw = u_next @ Ws[:,:64].T + UC ; sum of squares ----------
__global__ LB void k_users(const ushort* __restrict__ u_next, const ushort* __restrict__ uc,
                           const float* __restrict__ Ws, float* __restrict__ users_raw,
                           float* __restrict__ sumsq) {
  __shared__ float Wt[64 * 65];
  __shared__ float AB[4][128];
  for (int idx = threadIdx.x; idx < 64 * 64; idx += blockDim.x)
    Wt[(idx & 63) * 65 + (idx >> 6)] = Ws[(idx >> 6) * 128 + (idx & 63)];
  __syncthreads();
  int lane = threadIdx.x & 63;
  volatile float* ab = AB[threadIdx.x >> 6];
  int wid = (blockIdx.x * blockDim.x + threadIdx.x) >> 6;
  int nw = (gridDim.x * blockDim.x) >> 6;
  float ss = 0.f;
  for (int i = wid; i < NU; i += nw) {
    float va = bf2f(u_next[(size_t)i * DD + lane]);
    float acc = bf2f(uc[(size_t)i * DD + lane]) + gemm64x1_b(va, Wt, ab, lane);
    users_raw[(size_t)i * DD + lane] = acc;
    ss += acc * acc;
  }
#pragma unroll
  for (int off = 32; off > 0; off >>= 1) ss += __shfl_xor(ss, off);
  if (lane == 0) atomicAdd(sumsq, ss);
}

__global__ void k_users_acc(const float* __restrict__ users_raw,
                            const float* __restrict__ sumsq, float* __restrict__ out_final) {
  float scale = 0.25f / sqrtf(*sumsq);  // fold final /4
  int idx = blockIdx.x * blockDim.x + threadIdx.x;
  for (; idx < NU * DD; idx += gridDim.x * blockDim.x)
    out_final[idx] += users_raw[idx] * scale;
}

extern "C" void kernel_launch(void* const* d_in, const int* in_sizes, int n_in,
                              void* d_out, int out_size, void* d_ws, size_t ws_size,
                              hipStream_t stream) {
  const float* u1      = (const float*)d_in[0];
  const float* u2      = (const float*)d_in[1];
  const float* item    = (const float*)d_in[2];
  const float* Wi      = (const float*)d_in[3];
  const float* Wc      = (const float*)d_in[4];
  const float* Ws      = (const float*)d_in[5];
  const float* fk_W    = (const float*)d_in[6];
  const float* fk_b    = (const float*)d_in[7];
  const float* A_vals  = (const float*)d_in[8];
  const float* A2_vals = (const float*)d_in[9];
  const float* S_vals  = (const float*)d_in[10];
  const int*   A_rows  = (const int*)d_in[11];
  const int*   A_cols  = (const int*)d_in[12];
  const int*   A2_rows = (const int*)d_in[13];
  const int*   A2_cols = (const int*)d_in[14];
  const int*   S_rows  = (const int*)d_in[15];
  const int*   S_cols  = (const int*)d_in[16];
  const int*   sh1     = (const int*)d_in[17];
  const int*   sh2     = (const int*)d_in[18];

  // ---- workspace layout (float offsets); cv arrays padded +8 int2 ----
  float* ws = (float*)d_ws;
  ushort* embA_bf = (ushort*)ws;                   // [0, 8M)   16M ushorts
  ushort* embB_bf = (ushort*)(ws + 8000000);       // [8M, 16M)
  uint2*  QUADP   = (uint2*)(ws + 16000000);       // [16M, 28.8M) dead after quad
  uint*   NEGPb   = (uint*)(ws + 16000000);        //   overlay: written at l=1 dual
  float*  uraw    = ws + 22400000;                 //   overlay: fp32 users scratch
  uint*   NEGPa   = (uint*)(ws + 28800000);        // [28.8M, 35.2M)
  ushort* u1s     = (ushort*)(ws + 35200000);      // [35.2M, 38.4M) dead after comb
  ushort* u2s     = (ushort*)(ws + 38400000);      // [38.4M, 41.6M) dead after comb
  int2*   cvA2    = (int2*)(ws + 35200000);        //   overlay: 2,000,008 int2
  int*    ptrA2   = (int*)(ws + 39200016);         //   overlay (250,001)
  uint*   SOCPt   = (uint*)(ws + 41600000);        // [41.6M, 48M) dead after negmap
  ushort* n1o     = (ushort*)(ws + 41600000);      //   overlay: written by quadS
  ushort* UCb     = (ushort*)(ws + 41600000);      //   overlay: written by comb_gemm
  ushort* n2o     = (ushort*)(ws + 44800000);      //   overlay: written by quadS
  int2*   cvA     = (int2*)(ws + 48000000);        // 2,000,008 int2
  int2*   cvS     = (int2*)(ws + 52000016);        // 800,008 int2
  int*    ptrA    = (int*)(ws + 53600032);         // 250,001
  int*    ptrS    = ptrA + (NTOT + 1);             // 100,001
  int*    cnt     = ptrS + (NU + 1);               // 250,000
  int*    bsum    = cnt + NTOT;                    // 256
  float*  c1r     = (float*)(bsum + 256);          // 64
  float*  c2r     = c1r + 64;
  float*  w1      = c2r + 64;
  float*  w2      = w1 + 64;
  float*  sumsq   = w2 + 64;                       // 1
  int*    rank    = (int*)(ws + 54200580);         // 2,000,000 -> 56,200,580 (224.8MB)

  float* out        = (float*)d_out;
  float* out_logits = out + (size_t)NTOT * DD;

  auto build = [&](const int* rows, const int* cols, const float* vals,
                   int n, int nnz, int* ptr, int2* cv) {
    int nb = (n + SCAN_CHUNK - 1) / SCAN_CHUNK;
    int gb = (nnz + 2047) / 2048;  // 256 thr x 8 edges
    hipMemsetAsync(cnt, 0, (size_t)n * sizeof(int), stream);
    k_hist_rank<<<gb, 256, 0, stream>>>(rows, cnt, rank, nnz);
    k_scan1<<<nb, 256, 0, stream>>>(cnt, bsum, n);
    k_scan2<<<1, 256, 0, stream>>>(bsum, nb);
    k_scan3<<<nb, 256, 0, stream>>>(cnt, bsum, ptr, n, nnz);
    k_scatter2<<<gb, 256, 0, stream>>>(rows, cols, vals, ptr, rank, cv, nnz);
    hipMemsetAsync(cv + nnz, 0, 8 * sizeof(int2), stream);  // overshoot pad
  };

  // ---------- CSR builds (S, A) ----------
  build(S_rows, S_cols, S_vals, NU, NNZ_S, ptrS, cvS);
  build(A_rows, A_cols, A_vals, NTOT, NNZ_A, ptrA, cvA);

  // ---------- init + pre-transform (dense) + neg remap into QUADP ----------
  hipMemsetAsync(c1r, 0, 128 * sizeof(float), stream);
  k_init<<<2048, 256, 0, stream>>>(u1, u2, item, embA_bf, out);
  k_transform<<<1024, 256, 0, stream>>>(u1, u2, Wc, SOCPt);
  k_negmap<<<1024, 256, 0, stream>>>(SOCPt, sh1, sh2, QUADP);

  // ---------- quad gather: socials + layer-0 negs + layer-1 table ----------
  k_quadS<<<2048, 256, 0, stream>>>(ptrS, cvS, QUADP, Wc,
                                    u1s, u2s, n1o, n2o, NEGPa);
  k_colsum2<<<256, 256, 0, stream>>>(u1s, u2s, c1r, c2r);
  k_wvec<<<1, 64, 0, stream>>>(fk_W, c1r, c2r, w1, w2);
  k_logits4<<<1024, 256, 0, stream>>>(u1s, u2s, n1o, n2o, w1, w2, fk_b, out_logits);
  k_comb_gemm<<<1024, 256, 0, stream>>>(u1s, u2s, Ws, UCb);

  // A2 CSR into the dead u1s/u2s region (persistent for layers 1,2)
  build(A2_rows, A2_cols, A2_vals, NTOT, NNZ_A, ptrA2, cvA2);

  // ---------- layer loop ----------
  ushort* embCur = embA_bf;
  ushort* embNext = embB_bf;
  for (int l = 0; l < 3; ++l) {
    const int* pA = (l == 0) ? ptrA : ptrA2;
    const int2* cA = (l == 0) ? cvA : cvA2;

    k_spmm_fusedA2<<<4096, 256, 0, stream>>>(pA, cA, embCur, Wi, embNext, out);

    if (l == 1)  // false-logits slot 4 + table for layer 2
      k_dualS<<<2048, 256, 0, stream>>>(ptrS, cvS, NEGPa, Wc, w2, w1, fk_b,
                                        out_logits, 4, NEGPb);
    else if (l == 2)  // false-logits slot 5, no next table
      k_dualS<<<2048, 256, 0, stream>>>(ptrS, cvS, NEGPb, Wc, w2, w1, fk_b,
                                        out_logits, 5, (uint*)nullptr);

    hipMemsetAsync(sumsq, 0, sizeof(float), stream);
    k_users<<<1024, 256, 0, stream>>>(embNext, UCb, Ws, uraw, sumsq);
    k_users_acc<<<2048, 256, 0, stream>>>(uraw, sumsq, out);

    { ushort* t = embCur; embCur = embNext; embNext = t; }
  }
}

// Round 15
// 1505.687 us; speedup vs baseline: 2.0297x; 1.0063x over previous
//
#include <hip/hip_runtime.h>

#define NU 100000
#define NI 150000
#define NTOT 250000
#define DD 64
#define NNZ_A 2000000
#define NNZ_S 800000
#define SCAN_CHUNK 2048  // 256 threads x 8

typedef unsigned int uint;
typedef unsigned short ushort;

// launch bounds for gemm-style kernels: 256 threads, >=4 waves/EU -> 128 VGPR
#define LB __launch_bounds__(256, 4)

// ================= helpers =================
#define RFL(x) __builtin_amdgcn_readfirstlane(x)

__device__ __forceinline__ uint f2bf_bits(float x) {  // RNE round to bf16 (upper 16)
  uint a = __float_as_uint(x);
  return (a + 0x7fffu + ((a >> 16) & 1u)) >> 16;
}
__device__ __forceinline__ ushort f2bf(float x) { return (ushort)f2bf_bits(x); }
__device__ __forceinline__ float bf2f(ushort h) { return __uint_as_float(((uint)h) << 16); }
__device__ __forceinline__ uint pack_bf16x2(float lo, float hi) {
  return f2bf_bits(lo) | (f2bf_bits(hi) << 16);
}
__device__ __forceinline__ float unpk_lo(uint p) { return __uint_as_float(p << 16); }
__device__ __forceinline__ float unpk_hi(uint p) { return __uint_as_float(p & 0xffff0000u); }

// fast tanh: 1 - 2/(e^{2x}+1). Exact at +-inf; abs err ~1e-7 (<< bf16 rounding).
__device__ __forceinline__ float tanh_fast(float x) {
  float e = __expf(2.0f * x);
  return 1.0f - __fdividef(2.0f, e + 1.0f);
}

// ---- 64x64 GEMM with LDS-broadcast of the accumulator (per-wave buffer ab).
// FENCING (R11 post-mortem, guide rule #18): lgkmcnt(0) BEFORE write (WAR),
// lgkmcnt(0) AFTER write (RAW), sched_barrier(0) to pin. R14-proven stable.
__device__ __forceinline__ void gemm64x2_b(float aA, float aB,
                                           const float* __restrict__ Wt,
                                           volatile float* __restrict__ ab, int lane,
                                           float& oA, float& oB) {
  asm volatile("s_waitcnt lgkmcnt(0)" ::: "memory");
  __builtin_amdgcn_sched_barrier(0);
  ab[lane] = aA;
  ab[64 + lane] = aB;
  asm volatile("s_waitcnt lgkmcnt(0)" ::: "memory");
  __builtin_amdgcn_sched_barrier(0);
  float sA = 0.f, sB = 0.f;
#pragma unroll 4
  for (int k0 = 0; k0 < 64; k0 += 4) {
    float4 a4 = *(const float4*)(const float*)(ab + k0);
    float4 b4 = *(const float4*)(const float*)(ab + 64 + k0);
#pragma unroll
    for (int u = 0; u < 4; ++u) {
      float wk = Wt[(k0 + u) * 65 + lane];
      sA = fmaf(((const float*)&a4)[u], wk, sA);
      sB = fmaf(((const float*)&b4)[u], wk, sB);
    }
  }
  oA = sA; oB = sB;
}

__device__ __forceinline__ float gemm64x1_b(float a, const float* __restrict__ Wt,
                                            volatile float* __restrict__ ab, int lane) {
  asm volatile("s_waitcnt lgkmcnt(0)" ::: "memory");
  __builtin_amdgcn_sched_barrier(0);
  ab[lane] = a;
  asm volatile("s_waitcnt lgkmcnt(0)" ::: "memory");
  __builtin_amdgcn_sched_barrier(0);
  float s = 0.f;
#pragma unroll 4
  for (int k0 = 0; k0 < 64; k0 += 4) {
    float4 a4 = *(const float4*)(const float*)(ab + k0);
#pragma unroll
    for (int u = 0; u < 4; ++u)
      s = fmaf(((const float*)&a4)[u], Wt[(k0 + u) * 65 + lane], s);
  }
  return s;
}

// stage Wt[k*65+j] = W[j][k] from row-major W[j*64+k]
__device__ __forceinline__ void stage_wt(const float* __restrict__ W, float* __restrict__ Wt) {
  for (int idx = threadIdx.x; idx < 64 * 64; idx += blockDim.x)
    Wt[(idx & 63) * 65 + (idx >> 6)] = W[idx];
  __syncthreads();
}

// ---------- init: emb_bf = [(u1+u2)/2 ; item]; out = 0.25 * same ----------
__global__ void k_init(const float* __restrict__ u1, const float* __restrict__ u2,
                       const float* __restrict__ item, ushort* __restrict__ emb_bf,
                       float* __restrict__ out_final) {
  int idx = blockIdx.x * blockDim.x + threadIdx.x;
  const int tot = NTOT * DD;
  const int nu = NU * DD;
  for (; idx < tot; idx += gridDim.x * blockDim.x) {
    float v;
    if (idx < nu) v = 0.5f * (u1[idx] + u2[idx]);
    else          v = item[idx - nu];
    emb_bf[idx] = f2bf(v);
    out_final[idx] = 0.25f * v;
  }
}

// ================= CSR build (counting sort, rank-in-hist) =================
__global__ void k_hist_rank(const int* __restrict__ rows, int* __restrict__ cnt,
                            int* __restrict__ rank, int nnz) {
  int tid = blockIdx.x * blockDim.x + threadIdx.x;
  int gsz = gridDim.x * blockDim.x;
  for (int b = tid; b < nnz; b += gsz * 8) {
#pragma unroll
    for (int u = 0; u < 8; ++u) {
      int i = b + u * gsz;
      if (i < nnz) rank[i] = atomicAdd(&cnt[rows[i]], 1);
    }
  }
}

__global__ void k_scan1(const int* __restrict__ cnt, int* __restrict__ bsum, int n) {
  __shared__ int sdata[256];
  int base = blockIdx.x * SCAN_CHUNK;
  int s = 0;
#pragma unroll
  for (int k = 0; k < 8; ++k) {
    int i = base + threadIdx.x * 8 + k;
    s += (i < n) ? cnt[i] : 0;
  }
  sdata[threadIdx.x] = s;
  __syncthreads();
  for (int off = 128; off > 0; off >>= 1) {
    if (threadIdx.x < off) sdata[threadIdx.x] += sdata[threadIdx.x + off];
    __syncthreads();
  }
  if (threadIdx.x == 0) bsum[blockIdx.x] = sdata[0];
}

__global__ void k_scan2(int* bsum, int nb) {
  __shared__ int sdata[256];
  int v = (threadIdx.x < nb) ? bsum[threadIdx.x] : 0;
  sdata[threadIdx.x] = v;
  __syncthreads();
  for (int off = 1; off < 256; off <<= 1) {
    int t = (threadIdx.x >= (unsigned)off) ? sdata[threadIdx.x - off] : 0;
    __syncthreads();
    sdata[threadIdx.x] += t;
    __syncthreads();
  }
  if (threadIdx.x < nb) bsum[threadIdx.x] = sdata[threadIdx.x] - v;
}

__global__ void k_scan3(const int* __restrict__ cnt, const int* __restrict__ bsum,
                        int* __restrict__ rowptr, int n, int nnz) {
  __shared__ int sdata[256];
  int base = blockIdx.x * SCAN_CHUNK;
  int loc[8];
  int s = 0;
#pragma unroll
  for (int k = 0; k < 8; ++k) {
    int i = base + threadIdx.x * 8 + k;
    loc[k] = (i < n) ? cnt[i] : 0;
    s += loc[k];
  }
  sdata[threadIdx.x] = s;
  __syncthreads();
  for (int off = 1; off < 256; off <<= 1) {
    int t = (threadIdx.x >= (unsigned)off) ? sdata[threadIdx.x - off] : 0;
    __syncthreads();
    sdata[threadIdx.x] += t;
    __syncthreads();
  }
  int pre = bsum[blockIdx.x] + sdata[threadIdx.x] - s;
#pragma unroll
  for (int k = 0; k < 8; ++k) {
    int i = base + threadIdx.x * 8 + k;
    if (i < n) { rowptr[i] = pre; pre += loc[k]; }
  }
  if (blockIdx.x == 0 && threadIdx.x == 0) rowptr[n] = nnz;
}

__global__ void k_scatter2(const int* __restrict__ rows, const int* __restrict__ cols,
                           const float* __restrict__ vals, const int* __restrict__ ptr,
                           const int* __restrict__ rank, int2* __restrict__ cv, int nnz) {
  int tid = blockIdx.x * blockDim.x + threadIdx.x;
  int gsz = gridDim.x * blockDim.x;
  for (int b = tid; b < nnz; b += gsz * 8) {
#pragma unroll
    for (int u = 0; u < 8; ++u) {
      int i = b + u * gsz;
      if (i < nnz) {
        int r = rows[i];
        cv[ptr[r] + rank[i]] = make_int2(cols[i], __float_as_int(vals[i]));
      }
    }
  }
}

// ================= dense pre-transform =================
__global__ LB void k_transform(const float* __restrict__ u1, const float* __restrict__ u2,
                               const float* __restrict__ Wc, uint* __restrict__ SOCPt) {
  __shared__ float Wt[64 * 65];
  __shared__ float AB[4][128];
  stage_wt(Wc, Wt);
  int lane = threadIdx.x & 63;
  volatile float* ab = AB[threadIdx.x >> 6];
  int wid = (blockIdx.x * blockDim.x + threadIdx.x) >> 6;
  int nw = (gridDim.x * blockDim.x) >> 6;
  for (int i = wid; i < NU; i += nw) {
    float a1 = u1[(size_t)i * DD + lane];
    float a2 = u2[(size_t)i * DD + lane];
    float o1, o2;
    gemm64x2_b(a1, a2, Wt, ab, lane, o1, o2);
    SOCPt[(size_t)i * DD + lane] = pack_bf16x2(o1, o2);
  }
}

// QUADP[i] = { SOCPt[i], lo16(SOCPt[s1[i]]) | hi16(SOCPt[s2[i]]) }
__global__ void k_negmap(const uint* __restrict__ SOCPt, const int* __restrict__ s1,
                         const int* __restrict__ s2, uint2* __restrict__ QUADP) {
  int idx = blockIdx.x * blockDim.x + threadIdx.x;
  const int tot = NU * DD;
  for (; idx < tot; idx += gridDim.x * blockDim.x) {
    int i = idx >> 6, j = idx & 63;
    uint soc = SOCPt[idx];
    uint lo = SOCPt[(size_t)s1[i] * DD + j];
    uint hi = SOCPt[(size_t)s2[i] * DD + j];
    QUADP[idx] = make_uint2(soc, (lo & 0xffffu) | (hi & 0xffff0000u));
  }
}

// ================= gather kernels =================
// Edge lists wave-uniform (RFL -> SGPR chains, s_load edges, saddr gathers).
__global__ LB void k_quadS(const int* __restrict__ rowptr, const int2* __restrict__ cv,
                           const uint2* __restrict__ QUADP, const float* __restrict__ Wc,
                           ushort* __restrict__ u1s, ushort* __restrict__ u2s,
                           ushort* __restrict__ n1o, ushort* __restrict__ n2o,
                           uint* __restrict__ NEGPa) {
  __shared__ float Wt[64 * 65];
  __shared__ float AB[4][128];
  stage_wt(Wc, Wt);
  int lane = threadIdx.x & 63;
  volatile float* ab = AB[threadIdx.x >> 6];
  int wid = (blockIdx.x * blockDim.x + threadIdx.x) >> 6;
  int nw = (gridDim.x * blockDim.x) >> 6;
  for (int r = wid; r < NU; r += nw) {
    int start = RFL(rowptr[r]);
    int n = RFL(rowptr[r + 1]) - start;
    float a1 = 0.f, a2 = 0.f, a3 = 0.f, a4 = 0.f;
    for (int k = 0; k < n; k += 8) {
      int2 e[8];
#pragma unroll
      for (int u = 0; u < 8; ++u) e[u] = cv[start + k + u];  // s_load (uniform)
      uint2 q[8];
#pragma unroll
      for (int u = 0; u < 8; ++u)
        q[u] = QUADP[(size_t)(uint)e[u].x * 64u + (uint)lane];  // saddr gather
#pragma unroll
      for (int u = 0; u < 8; ++u) {
        float sv = (k + u < n) ? __int_as_float(e[u].y) : 0.f;  // s_cselect
        a1 = fmaf(sv, unpk_lo(q[u].x), a1);
        a2 = fmaf(sv, unpk_hi(q[u].x), a2);
        a3 = fmaf(sv, unpk_lo(q[u].y), a3);
        a4 = fmaf(sv, unpk_hi(q[u].y), a4);
      }
    }
    float t1 = tanh_fast(a1), t2 = tanh_fast(a2), t3 = tanh_fast(a3), t4 = tanh_fast(a4);
    u1s[(size_t)r * DD + lane] = f2bf(t1);
    u2s[(size_t)r * DD + lane] = f2bf(t2);
    n1o[(size_t)r * DD + lane] = f2bf(t3);
    n2o[(size_t)r * DD + lane] = f2bf(t4);
    float o3, o4;
    gemm64x2_b(t3, t4, Wt, ab, lane, o3, o4);
    NEGPa[(size_t)r * DD + lane] = pack_bf16x2(o3, o4);
  }
}

// dual: 1 packed-table gather (2 chains); fast-tanh; fused false-logits; optional next table.
__global__ LB void k_dualS(const int* __restrict__ rowptr, const int2* __restrict__ cv,
                           const uint* __restrict__ T, const float* __restrict__ Wc,
                           const float* __restrict__ wva, const float* __restrict__ wvb,
                           const float* __restrict__ fkb, float* __restrict__ out_logits,
                           int slot, uint* __restrict__ Tnext) {
  __shared__ float Wt[64 * 65];
  __shared__ float AB[4][128];
  stage_wt(Wc, Wt);
  int lane = threadIdx.x & 63;
  volatile float* ab = AB[threadIdx.x >> 6];
  int wid = (blockIdx.x * blockDim.x + threadIdx.x) >> 6;
  int nw = (gridDim.x * blockDim.x) >> 6;
  float b = fkb[0];
  float wa = wva[lane], wb = wvb[lane];
  for (int r = wid; r < NU; r += nw) {
    int start = RFL(rowptr[r]);
    int n = RFL(rowptr[r + 1]) - start;
    float accA = 0.f, accB = 0.f;
    for (int k = 0; k < n; k += 8) {
      int2 e[8];
#pragma unroll
      for (int u = 0; u < 8; ++u) e[u] = cv[start + k + u];
      uint q[8];
#pragma unroll
      for (int u = 0; u < 8; ++u)
        q[u] = T[(size_t)(uint)e[u].x * 64u + (uint)lane];
#pragma unroll
      for (int u = 0; u < 8; ++u) {
        float sv = (k + u < n) ? __int_as_float(e[u].y) : 0.f;
        accA = fmaf(sv, unpk_lo(q[u]), accA);
        accB = fmaf(sv, unpk_hi(q[u]), accB);
      }
    }
    float ta = tanh_fast(accA), tb = tanh_fast(accB);
    float pa = ta * wa, pb = tb * wb;
#pragma unroll
    for (int off = 32; off > 0; off >>= 1) {
      pa += __shfl_xor(pa, off);
      pb += __shfl_xor(pb, off);
    }
    if (lane == 0) {
      out_logits[(size_t)(NU + r) * 6 + slot] = pa + b;  // sc4: u1_neg chain
      out_logits[(size_t)r * 6 + slot] = pb + b;          // sc3: u2_neg chain
    }
    if (Tnext) {
      float oa, ob;
      gemm64x2_b(ta, tb, Wt, ab, lane, oa, ob);
      Tnext[(size_t)r * DD + lane] = pack_bf16x2(oa, ob);
    }
  }
}

// A-type, bf16 table, 2 rows per wave, JOINT interleaved k-loop:
// both rows' edge s_loads + 16 gathers issue before any wait (16-deep MLP,
// overlapping the two rows' L3 latencies). Overshoot: scalar base clamps to
// row start when k >= n_row (stays in-row); intra-batch overshoot <= 7 is
// covered by the 8-entry zero pad after cv; sv=0 kills all pad contributions.
__global__ LB void k_spmm_fusedA2(const int* __restrict__ rowptr, const int2* __restrict__ cv,
                                  const ushort* __restrict__ X, const float* __restrict__ W,
                                  ushort* __restrict__ embNext, float* __restrict__ outF) {
  __shared__ float Wt[64 * 65];
  __shared__ float AB[4][128];
  stage_wt(W, Wt);
  int lane = threadIdx.x & 63;
  volatile float* ab = AB[threadIdx.x >> 6];
  int wid = (blockIdx.x * blockDim.x + threadIdx.x) >> 6;
  int nw = (gridDim.x * blockDim.x) >> 6;
  for (int r = wid * 2; r < NTOT; r += nw * 2) {
    int s0 = RFL(rowptr[r]);
    int sm = RFL(rowptr[r + 1]);
    int s1e = RFL(rowptr[r + 2]);
    int n0 = sm - s0, n1 = s1e - sm;
    int kmax = max(n0, n1);
    float acc0 = 0.f, acc1 = 0.f;
    for (int k = 0; k < kmax; k += 8) {
      int b0 = (k < n0) ? s0 + k : s0;   // clamp: stay within row 0's edges
      int b1 = (k < n1) ? sm + k : sm;   // clamp: stay within row 1's edges
      int2 e0[8], e1[8];
#pragma unroll
      for (int u = 0; u < 8; ++u) e0[u] = cv[b0 + u];
#pragma unroll
      for (int u = 0; u < 8; ++u) e1[u] = cv[b1 + u];
      uint h0[8], h1[8];
#pragma unroll
      for (int u = 0; u < 8; ++u)
        h0[u] = X[(size_t)(uint)e0[u].x * 64u + (uint)lane];
#pragma unroll
      for (int u = 0; u < 8; ++u)
        h1[u] = X[(size_t)(uint)e1[u].x * 64u + (uint)lane];
#pragma unroll
      for (int u = 0; u < 8; ++u) {
        float sv0 = (k + u < n0) ? __int_as_float(e0[u].y) : 0.f;
        float sv1 = (k + u < n1) ? __int_as_float(e1[u].y) : 0.f;
        acc0 = fmaf(sv0, __uint_as_float(h0[u] << 16), acc0);
        acc1 = fmaf(sv1, __uint_as_float(h1[u] << 16), acc1);
      }
    }
    if (r < NU) {  // NU even: pair never straddles
      float oA, oB;
      gemm64x2_b(acc0, acc1, Wt, ab, lane, oA, oB);
      embNext[(size_t)r * DD + lane] = f2bf(tanh_fast(oA));
      embNext[(size_t)(r + 1) * DD + lane] = f2bf(tanh_fast(oB));
    } else {
      embNext[(size_t)r * DD + lane] = f2bf(acc0);
      embNext[(size_t)(r + 1) * DD + lane] = f2bf(acc1);
      outF[(size_t)r * DD + lane] += 0.25f * acc0;        // fold final /4
      outF[(size_t)(r + 1) * DD + lane] += 0.25f * acc1;
    }
  }
}

// ---------- fused column sums (bf16 inputs) ----------
__global__ void k_colsum2(const ushort* __restrict__ x1, const ushort* __restrict__ x2,
                          float* __restrict__ c1, float* __restrict__ c2) {
  int lane = threadIdx.x & 63;
  int wid = (blockIdx.x * blockDim.x + threadIdx.x) >> 6;
  int nw = (gridDim.x * blockDim.x) >> 6;
  float a1 = 0.f, a2 = 0.f;
  for (int i = wid; i < NU; i += nw) {
    a1 += bf2f(x1[(size_t)i * DD + lane]);
    a2 += bf2f(x2[(size_t)i * DD + lane]);
  }
  atomicAdd(&c1[lane], a1);
  atomicAdd(&c2[lane], a2);
}

// ---------- w = fk_W @ (csum/NU) ----------
__global__ void k_wvec(const float* __restrict__ fkW, const float* __restrict__ c1r,
                       const float* __restrict__ c2r, float* __restrict__ w1,
                       float* __restrict__ w2) {
  int j = threadIdx.x;
  float a1 = 0.f, a2 = 0.f;
  for (int k = 0; k < 64; ++k) {
    float w = fkW[j * 64 + k];
    a1 += w * c1r[k];
    a2 += w * c2r[k];
  }
  w1[j] = a1 * (1.0f / NU);
  w2[j] = a2 * (1.0f / NU);
}

// ---------- logits: true slots 0-2 + false slot 3 (layer-0 negs) ----------
__global__ void k_logits4(const ushort* __restrict__ u1s, const ushort* __restrict__ u2s,
                          const ushort* __restrict__ n1o, const ushort* __restrict__ n2o,
                          const float* __restrict__ w1, const float* __restrict__ w2,
                          const float* __restrict__ fkb, float* __restrict__ out_logits) {
  int lane = threadIdx.x & 63;
  int wid = (blockIdx.x * blockDim.x + threadIdx.x) >> 6;
  int nw = (gridDim.x * blockDim.x) >> 6;
  float b = fkb[0];
  for (int i = wid; i < 2 * NU; i += nw) {
    bool lo = i < NU;
    int r = lo ? i : i - NU;
    const ushort* xs = lo ? u2s : u1s;
    const ushort* xn = lo ? n2o : n1o;
    const float* wv = lo ? w1 : w2;
    float wvl = wv[lane];
    float ps = bf2f(xs[(size_t)r * DD + lane]) * wvl;
    float pn = bf2f(xn[(size_t)r * DD + lane]) * wvl;
#pragma unroll
    for (int off = 32; off > 0; off >>= 1) {
      ps += __shfl_xor(ps, off);
      pn += __shfl_xor(pn, off);
    }
    if (lane == 0) {
      float vs = ps + b;
      out_logits[(size_t)i * 6 + 0] = vs;
      out_logits[(size_t)i * 6 + 1] = vs;
      out_logits[(size_t)i * 6 + 2] = vs;
      out_logits[(size_t)i * 6 + 3] = pn + b;
    }
  }
}

// ---------- UC[i] = (0.5*(u1s+u2s)) @ Ws[:,64:].T -> bf16 ----------
__global__ LB void k_comb_gemm(const ushort* __restrict__ u1s, const ushort* __restrict__ u2s,
                               const float* __restrict__ Ws, ushort* __restrict__ UC) {
  __shared__ float Wt[64 * 65];
  __shared__ float AB[4][128];
  for (int idx = threadIdx.x; idx < 64 * 64; idx += blockDim.x)
    Wt[(idx & 63) * 65 + (idx >> 6)] = Ws[(idx >> 6) * 128 + 64 + (idx & 63)];
  __syncthreads();
  int lane = threadIdx.x & 63;
  volatile float* ab = AB[threadIdx.x >> 6];
  int wid = (blockIdx.x * blockDim.x + threadIdx.x) >> 6;
  int nw = (gridDim.x * blockDim.x) >> 6;
  for (int i = wid; i < NU; i += nw) {
    float c = 0.5f * (bf2f(u1s[(size_t)i * DD + lane]) + bf2f(u2s[(size_t)i * DD + lane]));
    UC[(size_t)i * DD + lane] = f2bf(gemm64x1_b(c, Wt, ab, lane));
  }
}

// ---------- users_raw = u_next @ Ws[:,:64].T + UC ; sum of squares ----------
__global__ LB void k_users(const ushort* __restrict__ u_next, const ushort* __restrict__ uc,
                           const float* __restrict__ Ws, float* __restrict__ users_raw,
                           float* __restrict__ sumsq) {
  __shared__ float Wt[64 * 65];
  __shared__ float AB[4][128];
  for (int idx = threadIdx.x; idx < 64 * 64; idx += blockDim.x)
    Wt[(idx & 63) * 65 + (idx >> 6)] = Ws[(idx >> 6) * 128 + (idx & 63)];
  __syncthreads();
  int lane = threadIdx.x & 63;
  volatile float* ab = AB[threadIdx.x >> 6];
  int wid = (blockIdx.x * blockDim.x + threadIdx.x) >> 6;
  int nw = (gridDim.x * blockDim.x) >> 6;
  float ss = 0.f;
  for (int i = wid; i < NU; i += nw) {
    float va = bf2f(u_next[(size_t)i * DD + lane]);
    float acc = bf2f(uc[(size_t)i * DD + lane]) + gemm64x1_b(va, Wt, ab, lane);
    users_raw[(size_t)i * DD + lane] = acc;
    ss += acc * acc;
  }
#pragma unroll
  for (int off = 32; off > 0; off >>= 1) ss += __shfl_xor(ss, off);
  if (lane == 0) atomicAdd(sumsq, ss);
}

__global__ void k_users_acc(const float* __restrict__ users_raw,
                            const float* __restrict__ sumsq, float* __restrict__ out_final) {
  float scale = 0.25f / sqrtf(*sumsq);  // fold final /4
  int idx = blockIdx.x * blockDim.x + threadIdx.x;
  for (; idx < NU * DD; idx += gridDim.x * blockDim.x)
    out_final[idx] += users_raw[idx] * scale;
}

extern "C" void kernel_launch(void* const* d_in, const int* in_sizes, int n_in,
                              void* d_out, int out_size, void* d_ws, size_t ws_size,
                              hipStream_t stream) {
  const float* u1      = (const float*)d_in[0];
  const float* u2      = (const float*)d_in[1];
  const float* item    = (const float*)d_in[2];
  const float* Wi      = (const float*)d_in[3];
  const float* Wc      = (const float*)d_in[4];
  const float* Ws      = (const float*)d_in[5];
  const float* fk_W    = (const float*)d_in[6];
  const float* fk_b    = (const float*)d_in[7];
  const float* A_vals  = (const float*)d_in[8];
  const float* A2_vals = (const float*)d_in[9];
  const float* S_vals  = (const float*)d_in[10];
  const int*   A_rows  = (const int*)d_in[11];
  const int*   A_cols  = (const int*)d_in[12];
  const int*   A2_rows = (const int*)d_in[13];
  const int*   A2_cols = (const int*)d_in[14];
  const int*   S_rows  = (const int*)d_in[15];
  const int*   S_cols  = (const int*)d_in[16];
  const int*   sh1     = (const int*)d_in[17];
  const int*   sh2     = (const int*)d_in[18];

  // ---- workspace layout (float offsets); cv arrays padded +8 int2 ----
  float* ws = (float*)d_ws;
  ushort* embA_bf = (ushort*)ws;                   // [0, 8M)   16M ushorts
  ushort* embB_bf = (ushort*)(ws + 8000000);       // [8M, 16M)
  uint2*  QUADP   = (uint2*)(ws + 16000000);       // [16M, 28.8M) dead after quad
  uint*   NEGPb   = (uint*)(ws + 16000000);        //   overlay: written at l=1 dual
  float*  uraw    = ws + 22400000;                 //   overlay: fp32 users scratch
  uint*   NEGPa   = (uint*)(ws + 28800000);        // [28.8M, 35.2M)
  ushort* u1s     = (ushort*)(ws + 35200000);      // [35.2M, 38.4M) dead after comb
  ushort* u2s     = (ushort*)(ws + 38400000);      // [38.4M, 41.6M) dead after comb
  int2*   cvA2    = (int2*)(ws + 35200000);        //   overlay: 2,000,008 int2
  int*    ptrA2   = (int*)(ws + 39200016);         //   overlay (250,001)
  uint*   SOCPt   = (uint*)(ws + 41600000);        // [41.6M, 48M) dead after negmap
  ushort* n1o     = (ushort*)(ws + 41600000);      //   overlay: written by quadS
  ushort* UCb     = (ushort*)(ws + 41600000);      //   overlay: written by comb_gemm
  ushort* n2o     = (ushort*)(ws + 44800000);      //   overlay: written by quadS
  int2*   cvA     = (int2*)(ws + 48000000);        // 2,000,008 int2
  int2*   cvS     = (int2*)(ws + 52000016);        // 800,008 int2
  int*    ptrA    = (int*)(ws + 53600032);         // 250,001
  int*    ptrS    = ptrA + (NTOT + 1);             // 100,001
  int*    cnt     = ptrS + (NU + 1);               // 250,000
  int*    bsum    = cnt + NTOT;                    // 256
  float*  c1r     = (float*)(bsum + 256);          // 64
  float*  c2r     = c1r + 64;
  float*  w1      = c2r + 64;
  float*  w2      = w1 + 64;
  float*  sumsq   = w2 + 64;                       // 1
  int*    rank    = (int*)(ws + 54200580);         // 2,000,000 -> 56,200,580 (224.8MB)

  float* out        = (float*)d_out;
  float* out_logits = out + (size_t)NTOT * DD;

  auto build = [&](const int* rows, const int* cols, const float* vals,
                   int n, int nnz, int* ptr, int2* cv) {
    int nb = (n + SCAN_CHUNK - 1) / SCAN_CHUNK;
    int gb = (nnz + 2047) / 2048;  // 256 thr x 8 edges
    hipMemsetAsync(cnt, 0, (size_t)n * sizeof(int), stream);
    k_hist_rank<<<gb, 256, 0, stream>>>(rows, cnt, rank, nnz);
    k_scan1<<<nb, 256, 0, stream>>>(cnt, bsum, n);
    k_scan2<<<1, 256, 0, stream>>>(bsum, nb);
    k_scan3<<<nb, 256, 0, stream>>>(cnt, bsum, ptr, n, nnz);
    k_scatter2<<<gb, 256, 0, stream>>>(rows, cols, vals, ptr, rank, cv, nnz);
    hipMemsetAsync(cv + nnz, 0, 8 * sizeof(int2), stream);  // overshoot pad
  };

  // ---------- CSR builds (S, A) ----------
  build(S_rows, S_cols, S_vals, NU, NNZ_S, ptrS, cvS);
  build(A_rows, A_cols, A_vals, NTOT, NNZ_A, ptrA, cvA);

  // ---------- init + pre-transform (dense) + neg remap into QUADP ----------
  hipMemsetAsync(c1r, 0, 128 * sizeof(float), stream);
  k_init<<<2048, 256, 0, stream>>>(u1, u2, item, embA_bf, out);
  k_transform<<<1024, 256, 0, stream>>>(u1, u2, Wc, SOCPt);
  k_negmap<<<1024, 256, 0, stream>>>(SOCPt, sh1, sh2, QUADP);

  // ---------- quad gather: socials + layer-0 negs + layer-1 table ----------
  k_quadS<<<2048, 256, 0, stream>>>(ptrS, cvS, QUADP, Wc,
                                    u1s, u2s, n1o, n2o, NEGPa);
  k_colsum2<<<256, 256, 0, stream>>>(u1s, u2s, c1r, c2r);
  k_wvec<<<1, 64, 0, stream>>>(fk_W, c1r, c2r, w1, w2);
  k_logits4<<<1024, 256, 0, stream>>>(u1s, u2s, n1o, n2o, w1, w2, fk_b, out_logits);
  k_comb_gemm<<<1024, 256, 0, stream>>>(u1s, u2s, Ws, UCb);

  // A2 CSR into the dead u1s/u2s region (persistent for layers 1,2)
  build(A2_rows, A2_cols, A2_vals, NTOT, NNZ_A, ptrA2, cvA2);

  // ---------- layer loop ----------
  ushort* embCur = embA_bf;
  ushort* embNext = embB_bf;
  for (int l = 0; l < 3; ++l) {
    const int* pA = (l == 0) ? ptrA : ptrA2;
    const int2* cA = (l == 0) ? cvA : cvA2;

    k_spmm_fusedA2<<<4096, 256, 0, stream>>>(pA, cA, embCur, Wi, embNext, out);

    if (l == 1)  // false-logits slot 4 + table for layer 2
      k_dualS<<<2048, 256, 0, stream>>>(ptrS, cvS, NEGPa, Wc, w2, w1, fk_b,
                                        out_logits, 4, NEGPb);
    else if (l == 2)  // false-logits slot 5, no next table
      k_dualS<<<2048, 256, 0, stream>>>(ptrS, cvS, NEGPb, Wc, w2, w1, fk_b,
                                        out_logits, 5, (uint*)nullptr);

    hipMemsetAsync(sumsq, 0, sizeof(float), stream);
    k_users<<<1024, 256, 0, stream>>>(embNext, UCb, Ws, uraw, sumsq);
    k_users_acc<<<2048, 256, 0, stream>>>(uraw, sumsq, out);

    { ushort* t = embCur; embCur = embNext; embNext = t; }
  }
}

// Round 16
// 1487.066 us; speedup vs baseline: 2.0551x; 1.0125x over previous
//
#include <hip/hip_runtime.h>

#define NU 100000
#define NI 150000
#define NTOT 250000
#define DD 64
#define NNZ_A 2000000
#define NNZ_S 800000
#define SCAN_CHUNK 2048  // 256 threads x 8

typedef unsigned int uint;
typedef unsigned short ushort;

// launch bounds for gemm-style kernels: 256 threads, >=4 waves/EU -> 128 VGPR
#define LB __launch_bounds__(256, 4)

// ================= helpers =================
#define RFL(x) __builtin_amdgcn_readfirstlane(x)

__device__ __forceinline__ uint f2bf_bits(float x) {  // RNE round to bf16 (upper 16)
  uint a = __float_as_uint(x);
  return (a + 0x7fffu + ((a >> 16) & 1u)) >> 16;
}
__device__ __forceinline__ ushort f2bf(float x) { return (ushort)f2bf_bits(x); }
__device__ __forceinline__ float bf2f(ushort h) { return __uint_as_float(((uint)h) << 16); }
__device__ __forceinline__ uint pack_bf16x2(float lo, float hi) {
  return f2bf_bits(lo) | (f2bf_bits(hi) << 16);
}
__device__ __forceinline__ float unpk_lo(uint p) { return __uint_as_float(p << 16); }
__device__ __forceinline__ float unpk_hi(uint p) { return __uint_as_float(p & 0xffff0000u); }

// fast tanh: 1 - 2/(e^{2x}+1). Exact at +-inf; abs err ~1e-7 (<< bf16 rounding).
__device__ __forceinline__ float tanh_fast(float x) {
  float e = __expf(2.0f * x);
  return 1.0f - __fdividef(2.0f, e + 1.0f);
}

// ---- 64x64 GEMM with LDS-broadcast of the accumulator (per-wave buffer ab).
// FENCING (R11 post-mortem, guide rule #18): lgkmcnt(0) BEFORE write (WAR),
// lgkmcnt(0) AFTER write (RAW), sched_barrier(0) to pin. R14-proven stable.
__device__ __forceinline__ void gemm64x2_b(float aA, float aB,
                                           const float* __restrict__ Wt,
                                           volatile float* __restrict__ ab, int lane,
                                           float& oA, float& oB) {
  asm volatile("s_waitcnt lgkmcnt(0)" ::: "memory");
  __builtin_amdgcn_sched_barrier(0);
  ab[lane] = aA;
  ab[64 + lane] = aB;
  asm volatile("s_waitcnt lgkmcnt(0)" ::: "memory");
  __builtin_amdgcn_sched_barrier(0);
  float sA = 0.f, sB = 0.f;
#pragma unroll 4
  for (int k0 = 0; k0 < 64; k0 += 4) {
    float4 a4 = *(const float4*)(const float*)(ab + k0);
    float4 b4 = *(const float4*)(const float*)(ab + 64 + k0);
#pragma unroll
    for (int u = 0; u < 4; ++u) {
      float wk = Wt[(k0 + u) * 65 + lane];
      sA = fmaf(((const float*)&a4)[u], wk, sA);
      sB = fmaf(((const float*)&b4)[u], wk, sB);
    }
  }
  oA = sA; oB = sB;
}

// 4-acc variant (ab buffer 256 floats/wave): Wt ds_read shared by 4 chains.
__device__ __forceinline__ void gemm64x4_b(float a0, float a1, float a2, float a3,
                                           const float* __restrict__ Wt,
                                           volatile float* __restrict__ ab, int lane,
                                           float& o0, float& o1, float& o2, float& o3) {
  asm volatile("s_waitcnt lgkmcnt(0)" ::: "memory");
  __builtin_amdgcn_sched_barrier(0);
  ab[lane] = a0;
  ab[64 + lane] = a1;
  ab[128 + lane] = a2;
  ab[192 + lane] = a3;
  asm volatile("s_waitcnt lgkmcnt(0)" ::: "memory");
  __builtin_amdgcn_sched_barrier(0);
  float s0 = 0.f, s1 = 0.f, s2 = 0.f, s3 = 0.f;
#pragma unroll 4
  for (int k0 = 0; k0 < 64; k0 += 4) {
    float4 x0 = *(const float4*)(const float*)(ab + k0);
    float4 x1 = *(const float4*)(const float*)(ab + 64 + k0);
    float4 x2 = *(const float4*)(const float*)(ab + 128 + k0);
    float4 x3 = *(const float4*)(const float*)(ab + 192 + k0);
#pragma unroll
    for (int u = 0; u < 4; ++u) {
      float wk = Wt[(k0 + u) * 65 + lane];
      s0 = fmaf(((const float*)&x0)[u], wk, s0);
      s1 = fmaf(((const float*)&x1)[u], wk, s1);
      s2 = fmaf(((const float*)&x2)[u], wk, s2);
      s3 = fmaf(((const float*)&x3)[u], wk, s3);
    }
  }
  o0 = s0; o1 = s1; o2 = s2; o3 = s3;
}

__device__ __forceinline__ float gemm64x1_b(float a, const float* __restrict__ Wt,
                                            volatile float* __restrict__ ab, int lane) {
  asm volatile("s_waitcnt lgkmcnt(0)" ::: "memory");
  __builtin_amdgcn_sched_barrier(0);
  ab[lane] = a;
  asm volatile("s_waitcnt lgkmcnt(0)" ::: "memory");
  __builtin_amdgcn_sched_barrier(0);
  float s = 0.f;
#pragma unroll 4
  for (int k0 = 0; k0 < 64; k0 += 4) {
    float4 a4 = *(const float4*)(const float*)(ab + k0);
#pragma unroll
    for (int u = 0; u < 4; ++u)
      s = fmaf(((const float*)&a4)[u], Wt[(k0 + u) * 65 + lane], s);
  }
  return s;
}

// stage Wt[k*65+j] = W[j][k] from row-major W[j*64+k]
__device__ __forceinline__ void stage_wt(const float* __restrict__ W, float* __restrict__ Wt) {
  for (int idx = threadIdx.x; idx < 64 * 64; idx += blockDim.x)
    Wt[(idx & 63) * 65 + (idx >> 6)] = W[idx];
  __syncthreads();
}

// ---------- init: emb_bf = [(u1+u2)/2 ; item]; out = 0.25 * same ----------
__global__ void k_init(const float* __restrict__ u1, const float* __restrict__ u2,
                       const float* __restrict__ item, ushort* __restrict__ emb_bf,
                       float* __restrict__ out_final) {
  int idx = blockIdx.x * blockDim.x + threadIdx.x;
  const int tot = NTOT * DD;
  const int nu = NU * DD;
  for (; idx < tot; idx += gridDim.x * blockDim.x) {
    float v;
    if (idx < nu) v = 0.5f * (u1[idx] + u2[idx]);
    else          v = item[idx - nu];
    emb_bf[idx] = f2bf(v);
    out_final[idx] = 0.25f * v;
  }
}

// ================= CSR build (counting sort, rank-in-hist) =================
__global__ void k_hist_rank(const int* __restrict__ rows, int* __restrict__ cnt,
                            int* __restrict__ rank, int nnz) {
  int tid = blockIdx.x * blockDim.x + threadIdx.x;
  int gsz = gridDim.x * blockDim.x;
  for (int b = tid; b < nnz; b += gsz * 8) {
#pragma unroll
    for (int u = 0; u < 8; ++u) {
      int i = b + u * gsz;
      if (i < nnz) rank[i] = atomicAdd(&cnt[rows[i]], 1);
    }
  }
}

__global__ void k_scan1(const int* __restrict__ cnt, int* __restrict__ bsum, int n) {
  __shared__ int sdata[256];
  int base = blockIdx.x * SCAN_CHUNK;
  int s = 0;
#pragma unroll
  for (int k = 0; k < 8; ++k) {
    int i = base + threadIdx.x * 8 + k;
    s += (i < n) ? cnt[i] : 0;
  }
  sdata[threadIdx.x] = s;
  __syncthreads();
  for (int off = 128; off > 0; off >>= 1) {
    if (threadIdx.x < off) sdata[threadIdx.x] += sdata[threadIdx.x + off];
    __syncthreads();
  }
  if (threadIdx.x == 0) bsum[blockIdx.x] = sdata[0];
}

__global__ void k_scan2(int* bsum, int nb) {
  __shared__ int sdata[256];
  int v = (threadIdx.x < nb) ? bsum[threadIdx.x] : 0;
  sdata[threadIdx.x] = v;
  __syncthreads();
  for (int off = 1; off < 256; off <<= 1) {
    int t = (threadIdx.x >= (unsigned)off) ? sdata[threadIdx.x - off] : 0;
    __syncthreads();
    sdata[threadIdx.x] += t;
    __syncthreads();
  }
  if (threadIdx.x < nb) bsum[threadIdx.x] = sdata[threadIdx.x] - v;
}

__global__ void k_scan3(const int* __restrict__ cnt, const int* __restrict__ bsum,
                        int* __restrict__ rowptr, int n, int nnz) {
  __shared__ int sdata[256];
  int base = blockIdx.x * SCAN_CHUNK;
  int loc[8];
  int s = 0;
#pragma unroll
  for (int k = 0; k < 8; ++k) {
    int i = base + threadIdx.x * 8 + k;
    loc[k] = (i < n) ? cnt[i] : 0;
    s += loc[k];
  }
  sdata[threadIdx.x] = s;
  __syncthreads();
  for (int off = 1; off < 256; off <<= 1) {
    int t = (threadIdx.x >= (unsigned)off) ? sdata[threadIdx.x - off] : 0;
    __syncthreads();
    sdata[threadIdx.x] += t;
    __syncthreads();
  }
  int pre = bsum[blockIdx.x] + sdata[threadIdx.x] - s;
#pragma unroll
  for (int k = 0; k < 8; ++k) {
    int i = base + threadIdx.x * 8 + k;
    if (i < n) { rowptr[i] = pre; pre += loc[k]; }
  }
  if (blockIdx.x == 0 && threadIdx.x == 0) rowptr[n] = nnz;
}

__global__ void k_scatter2(const int* __restrict__ rows, const int* __restrict__ cols,
                           const float* __restrict__ vals, const int* __restrict__ ptr,
                           const int* __restrict__ rank, int2* __restrict__ cv, int nnz) {
  int tid = blockIdx.x * blockDim.x + threadIdx.x;
  int gsz = gridDim.x * blockDim.x;
  for (int b = tid; b < nnz; b += gsz * 8) {
#pragma unroll
    for (int u = 0; u < 8; ++u) {
      int i = b + u * gsz;
      if (i < nnz) {
        int r = rows[i];
        cv[ptr[r] + rank[i]] = make_int2(cols[i], __float_as_int(vals[i]));
      }
    }
  }
}

// ================= dense pre-transform =================
__global__ LB void k_transform(const float* __restrict__ u1, const float* __restrict__ u2,
                               const float* __restrict__ Wc, uint* __restrict__ SOCPt) {
  __shared__ float Wt[64 * 65];
  __shared__ float AB[4][128];
  stage_wt(Wc, Wt);
  int lane = threadIdx.x & 63;
  volatile float* ab = AB[threadIdx.x >> 6];
  int wid = (blockIdx.x * blockDim.x + threadIdx.x) >> 6;
  int nw = (gridDim.x * blockDim.x) >> 6;
  for (int i = wid; i < NU; i += nw) {
    float a1 = u1[(size_t)i * DD + lane];
    float a2 = u2[(size_t)i * DD + lane];
    float o1, o2;
    gemm64x2_b(a1, a2, Wt, ab, lane, o1, o2);
    SOCPt[(size_t)i * DD + lane] = pack_bf16x2(o1, o2);
  }
}

// QUADP[i] = { SOCPt[i], lo16(SOCPt[s1[i]]) | hi16(SOCPt[s2[i]]) }
__global__ void k_negmap(const uint* __restrict__ SOCPt, const int* __restrict__ s1,
                         const int* __restrict__ s2, uint2* __restrict__ QUADP) {
  int idx = blockIdx.x * blockDim.x + threadIdx.x;
  const int tot = NU * DD;
  for (; idx < tot; idx += gridDim.x * blockDim.x) {
    int i = idx >> 6, j = idx & 63;
    uint soc = SOCPt[idx];
    uint lo = SOCPt[(size_t)s1[i] * DD + j];
    uint hi = SOCPt[(size_t)s2[i] * DD + j];
    QUADP[idx] = make_uint2(soc, (lo & 0xffffu) | (hi & 0xffff0000u));
  }
}

// ================= gather kernels =================
// Edge lists wave-uniform (RFL -> SGPR chains, s_load edges, saddr gathers).
__global__ LB void k_quadS(const int* __restrict__ rowptr, const int2* __restrict__ cv,
                           const uint2* __restrict__ QUADP, const float* __restrict__ Wc,
                           ushort* __restrict__ u1s, ushort* __restrict__ u2s,
                           ushort* __restrict__ n1o, ushort* __restrict__ n2o,
                           uint* __restrict__ NEGPa) {
  __shared__ float Wt[64 * 65];
  __shared__ float AB[4][128];
  stage_wt(Wc, Wt);
  int lane = threadIdx.x & 63;
  volatile float* ab = AB[threadIdx.x >> 6];
  int wid = (blockIdx.x * blockDim.x + threadIdx.x) >> 6;
  int nw = (gridDim.x * blockDim.x) >> 6;
  for (int r = wid; r < NU; r += nw) {
    int start = RFL(rowptr[r]);
    int n = RFL(rowptr[r + 1]) - start;
    float a1 = 0.f, a2 = 0.f, a3 = 0.f, a4 = 0.f;
    for (int k = 0; k < n; k += 8) {
      int2 e[8];
#pragma unroll
      for (int u = 0; u < 8; ++u) e[u] = cv[start + k + u];  // s_load (uniform)
      uint2 q[8];
#pragma unroll
      for (int u = 0; u < 8; ++u)
        q[u] = QUADP[(size_t)(uint)e[u].x * 64u + (uint)lane];  // saddr gather
#pragma unroll
      for (int u = 0; u < 8; ++u) {
        float sv = (k + u < n) ? __int_as_float(e[u].y) : 0.f;  // s_cselect
        a1 = fmaf(sv, unpk_lo(q[u].x), a1);
        a2 = fmaf(sv, unpk_hi(q[u].x), a2);
        a3 = fmaf(sv, unpk_lo(q[u].y), a3);
        a4 = fmaf(sv, unpk_hi(q[u].y), a4);
      }
    }
    float t1 = tanh_fast(a1), t2 = tanh_fast(a2), t3 = tanh_fast(a3), t4 = tanh_fast(a4);
    u1s[(size_t)r * DD + lane] = f2bf(t1);
    u2s[(size_t)r * DD + lane] = f2bf(t2);
    n1o[(size_t)r * DD + lane] = f2bf(t3);
    n2o[(size_t)r * DD + lane] = f2bf(t4);
    float o3, o4;
    gemm64x2_b(t3, t4, Wt, ab, lane, o3, o4);
    NEGPa[(size_t)r * DD + lane] = pack_bf16x2(o3, o4);
  }
}

// dual: 2 rows per wave (16 gathers in flight); fast-tanh; fused false-logits;
// both rows' next-layer transforms in one gemm64x4_b.
__global__ LB void k_dualS(const int* __restrict__ rowptr, const int2* __restrict__ cv,
                           const uint* __restrict__ T, const float* __restrict__ Wc,
                           const float* __restrict__ wva, const float* __restrict__ wvb,
                           const float* __restrict__ fkb, float* __restrict__ out_logits,
                           int slot, uint* __restrict__ Tnext) {
  __shared__ float Wt[64 * 65];
  __shared__ float AB[4][256];
  stage_wt(Wc, Wt);
  int lane = threadIdx.x & 63;
  volatile float* ab = AB[threadIdx.x >> 6];
  int wid = (blockIdx.x * blockDim.x + threadIdx.x) >> 6;
  int nw = (gridDim.x * blockDim.x) >> 6;
  float b = fkb[0];
  float wa = wva[lane], wb = wvb[lane];
  for (int r = wid * 2; r < NU; r += nw * 2) {
    int s0 = RFL(rowptr[r]);
    int sm = RFL(rowptr[r + 1]);
    int s1e = RFL(rowptr[r + 2]);
    int n0 = sm - s0, n1 = s1e - sm;
    int kmax = max(n0, n1);
    float a0A = 0.f, a0B = 0.f, a1A = 0.f, a1B = 0.f;
    for (int k = 0; k < kmax; k += 8) {
      int b0 = (k < n0) ? s0 + k : s0;
      int b1 = (k < n1) ? sm + k : sm;
      int2 e0[8], e1[8];
#pragma unroll
      for (int u = 0; u < 8; ++u) e0[u] = cv[b0 + u];
#pragma unroll
      for (int u = 0; u < 8; ++u) e1[u] = cv[b1 + u];
      uint q0[8], q1[8];
#pragma unroll
      for (int u = 0; u < 8; ++u)
        q0[u] = T[(size_t)(uint)e0[u].x * 64u + (uint)lane];
#pragma unroll
      for (int u = 0; u < 8; ++u)
        q1[u] = T[(size_t)(uint)e1[u].x * 64u + (uint)lane];
#pragma unroll
      for (int u = 0; u < 8; ++u) {
        float sv0 = (k + u < n0) ? __int_as_float(e0[u].y) : 0.f;
        float sv1 = (k + u < n1) ? __int_as_float(e1[u].y) : 0.f;
        a0A = fmaf(sv0, unpk_lo(q0[u]), a0A);
        a0B = fmaf(sv0, unpk_hi(q0[u]), a0B);
        a1A = fmaf(sv1, unpk_lo(q1[u]), a1A);
        a1B = fmaf(sv1, unpk_hi(q1[u]), a1B);
      }
    }
    float t0a = tanh_fast(a0A), t0b = tanh_fast(a0B);
    float t1a = tanh_fast(a1A), t1b = tanh_fast(a1B);
    float p0a = t0a * wa, p0b = t0b * wb, p1a = t1a * wa, p1b = t1b * wb;
#pragma unroll
    for (int off = 32; off > 0; off >>= 1) {
      p0a += __shfl_xor(p0a, off);
      p0b += __shfl_xor(p0b, off);
      p1a += __shfl_xor(p1a, off);
      p1b += __shfl_xor(p1b, off);
    }
    if (lane == 0) {
      out_logits[(size_t)(NU + r) * 6 + slot] = p0a + b;      // sc4 row r
      out_logits[(size_t)r * 6 + slot] = p0b + b;              // sc3 row r
      out_logits[(size_t)(NU + r + 1) * 6 + slot] = p1a + b;  // sc4 row r+1
      out_logits[(size_t)(r + 1) * 6 + slot] = p1b + b;        // sc3 row r+1
    }
    if (Tnext) {
      float o0a, o0b, o1a, o1b;
      gemm64x4_b(t0a, t0b, t1a, t1b, Wt, ab, lane, o0a, o0b, o1a, o1b);
      Tnext[(size_t)r * DD + lane] = pack_bf16x2(o0a, o0b);
      Tnext[(size_t)(r + 1) * DD + lane] = pack_bf16x2(o1a, o1b);
    }
  }
}

// A-type, bf16 table, 4 rows per wave: 4 uniform edge-batches (SGPRs) + 32
// gathers in flight before any wait. Overshoot: clamped bases stay in-bounds
// (8-entry zero pad after cv); sv=0 kills pad contributions. NU%4==0.
__global__ LB void k_spmm_fusedA2(const int* __restrict__ rowptr, const int2* __restrict__ cv,
                                  const ushort* __restrict__ X, const float* __restrict__ W,
                                  ushort* __restrict__ embNext, float* __restrict__ outF) {
  __shared__ float Wt[64 * 65];
  __shared__ float AB[4][256];
  stage_wt(W, Wt);
  int lane = threadIdx.x & 63;
  volatile float* ab = AB[threadIdx.x >> 6];
  int wid = (blockIdx.x * blockDim.x + threadIdx.x) >> 6;
  int nw = (gridDim.x * blockDim.x) >> 6;
  for (int r = wid * 4; r < NTOT; r += nw * 4) {
    int sp[5];
#pragma unroll
    for (int i = 0; i < 5; ++i) sp[i] = RFL(rowptr[r + i]);
    int n0 = sp[1] - sp[0], n1 = sp[2] - sp[1];
    int n2 = sp[3] - sp[2], n3 = sp[4] - sp[3];
    int kmax = max(max(n0, n1), max(n2, n3));
    float acc0 = 0.f, acc1 = 0.f, acc2 = 0.f, acc3 = 0.f;
    for (int k = 0; k < kmax; k += 8) {
      int b0 = (k < n0) ? sp[0] + k : sp[0];
      int b1 = (k < n1) ? sp[1] + k : sp[1];
      int b2 = (k < n2) ? sp[2] + k : sp[2];
      int b3 = (k < n3) ? sp[3] + k : sp[3];
      int2 e0[8], e1[8], e2[8], e3[8];
#pragma unroll
      for (int u = 0; u < 8; ++u) e0[u] = cv[b0 + u];
#pragma unroll
      for (int u = 0; u < 8; ++u) e1[u] = cv[b1 + u];
#pragma unroll
      for (int u = 0; u < 8; ++u) e2[u] = cv[b2 + u];
#pragma unroll
      for (int u = 0; u < 8; ++u) e3[u] = cv[b3 + u];
      uint h0[8], h1[8], h2[8], h3[8];
#pragma unroll
      for (int u = 0; u < 8; ++u)
        h0[u] = X[(size_t)(uint)e0[u].x * 64u + (uint)lane];
#pragma unroll
      for (int u = 0; u < 8; ++u)
        h1[u] = X[(size_t)(uint)e1[u].x * 64u + (uint)lane];
#pragma unroll
      for (int u = 0; u < 8; ++u)
        h2[u] = X[(size_t)(uint)e2[u].x * 64u + (uint)lane];
#pragma unroll
      for (int u = 0; u < 8; ++u)
        h3[u] = X[(size_t)(uint)e3[u].x * 64u + (uint)lane];
#pragma unroll
      for (int u = 0; u < 8; ++u) {
        float sv0 = (k + u < n0) ? __int_as_float(e0[u].y) : 0.f;
        float sv1 = (k + u < n1) ? __int_as_float(e1[u].y) : 0.f;
        float sv2 = (k + u < n2) ? __int_as_float(e2[u].y) : 0.f;
        float sv3 = (k + u < n3) ? __int_as_float(e3[u].y) : 0.f;
        acc0 = fmaf(sv0, __uint_as_float(h0[u] << 16), acc0);
        acc1 = fmaf(sv1, __uint_as_float(h1[u] << 16), acc1);
        acc2 = fmaf(sv2, __uint_as_float(h2[u] << 16), acc2);
        acc3 = fmaf(sv3, __uint_as_float(h3[u] << 16), acc3);
      }
    }
    if (r < NU) {  // NU % 4 == 0: group never straddles
      float o0, o1, o2, o3;
      gemm64x4_b(acc0, acc1, acc2, acc3, Wt, ab, lane, o0, o1, o2, o3);
      embNext[(size_t)r * DD + lane] = f2bf(tanh_fast(o0));
      embNext[(size_t)(r + 1) * DD + lane] = f2bf(tanh_fast(o1));
      embNext[(size_t)(r + 2) * DD + lane] = f2bf(tanh_fast(o2));
      embNext[(size_t)(r + 3) * DD + lane] = f2bf(tanh_fast(o3));
    } else {
      embNext[(size_t)r * DD + lane] = f2bf(acc0);
      embNext[(size_t)(r + 1) * DD + lane] = f2bf(acc1);
      embNext[(size_t)(r + 2) * DD + lane] = f2bf(acc2);
      embNext[(size_t)(r + 3) * DD + lane] = f2bf(acc3);
      outF[(size_t)r * DD + lane] += 0.25f * acc0;        // fold final /4
      outF[(size_t)(r + 1) * DD + lane] += 0.25f * acc1;
      outF[(size_t)(r + 2) * DD + lane] += 0.25f * acc2;
      outF[(size_t)(r + 3) * DD + lane] += 0.25f * acc3;
    }
  }
}

// ---------- fused column sums (bf16 inputs) ----------
__global__ void k_colsum2(const ushort* __restrict__ x1, const ushort* __restrict__ x2,
                          float* __restrict__ c1, float* __restrict__ c2) {
  int lane = threadIdx.x & 63;
  int wid = (blockIdx.x * blockDim.x + threadIdx.x) >> 6;
  int nw = (gridDim.x * blockDim.x) >> 6;
  float a1 = 0.f, a2 = 0.f;
  for (int i = wid; i < NU; i += nw) {
    a1 += bf2f(x1[(size_t)i * DD + lane]);
    a2 += bf2f(x2[(size_t)i * DD + lane]);
  }
  atomicAdd(&c1[lane], a1);
  atomicAdd(&c2[lane], a2);
}

// ---------- w = fk_W @ (csum/NU) ----------
__global__ void k_wvec(const float* __restrict__ fkW, const float* __restrict__ c1r,
                       const float* __restrict__ c2r, float* __restrict__ w1,
                       float* __restrict__ w2) {
  int j = threadIdx.x;
  float a1 = 0.f, a2 = 0.f;
  for (int k = 0; k < 64; ++k) {
    float w = fkW[j * 64 + k];
    a1 += w * c1r[k];
    a2 += w * c2r[k];
  }
  w1[j] = a1 * (1.0f / NU);
  w2[j] = a2 * (1.0f / NU);
}

// ---------- logits: true slots 0-2 + false slot 3 (layer-0 negs) ----------
__global__ void k_logits4(const ushort* __restrict__ u1s, const ushort* __restrict__ u2s,
                          const ushort* __restrict__ n1o, const ushort* __restrict__ n2o,
                          const float* __restrict__ w1, const float* __restrict__ w2,
                          const float* __restrict__ fkb, float* __restrict__ out_logits) {
  int lane = threadIdx.x & 63;
  int wid = (blockIdx.x * blockDim.x + threadIdx.x) >> 6;
  int nw = (gridDim.x * blockDim.x) >> 6;
  float b = fkb[0];
  for (int i = wid; i < 2 * NU; i += nw) {
    bool lo = i < NU;
    int r = lo ? i : i - NU;
    const ushort* xs = lo ? u2s : u1s;
    const ushort* xn = lo ? n2o : n1o;
    const float* wv = lo ? w1 : w2;
    float wvl = wv[lane];
    float ps = bf2f(xs[(size_t)r * DD + lane]) * wvl;
    float pn = bf2f(xn[(size_t)r * DD + lane]) * wvl;
#pragma unroll
    for (int off = 32; off > 0; off >>= 1) {
      ps += __shfl_xor(ps, off);
      pn += __shfl_xor(pn, off);
    }
    if (lane == 0) {
      float vs = ps + b;
      out_logits[(size_t)i * 6 + 0] = vs;
      out_logits[(size_t)i * 6 + 1] = vs;
      out_logits[(size_t)i * 6 + 2] = vs;
      out_logits[(size_t)i * 6 + 3] = pn + b;
    }
  }
}

// ---------- UC[i] = (0.5*(u1s+u2s)) @ Ws[:,64:].T -> bf16 ----------
__global__ LB void k_comb_gemm(const ushort* __restrict__ u1s, const ushort* __restrict__ u2s,
                               const float* __restrict__ Ws, ushort* __restrict__ UC) {
  __shared__ float Wt[64 * 65];
  __shared__ float AB[4][128];
  for (int idx = threadIdx.x; idx < 64 * 64; idx += blockDim.x)
    Wt[(idx & 63) * 65 + (idx >> 6)] = Ws[(idx >> 6) * 128 + 64 + (idx & 63)];
  __syncthreads();
  int lane = threadIdx.x & 63;
  volatile float* ab = AB[threadIdx.x >> 6];
  int wid = (blockIdx.x * blockDim.x + threadIdx.x) >> 6;
  int nw = (gridDim.x * blockDim.x) >> 6;
  for (int i = wid; i < NU; i += nw) {
    float c = 0.5f * (bf2f(u1s[(size_t)i * DD + lane]) + bf2f(u2s[(size_t)i * DD + lane]));
    UC[(size_t)i * DD + lane] = f2bf(gemm64x1_b(c, Wt, ab, lane));
  }
}

// ---------- users_raw = u_next @ Ws[:,:64].T + UC ; sum of squares ----------
__global__ LB void k_users(const ushort* __restrict__ u_next, const ushort* __restrict__ uc,
                           const float* __restrict__ Ws, float* __restrict__ users_raw,
                           float* __restrict__ sumsq) {
  __shared__ float Wt[64 * 65];
  __shared__ float AB[4][128];
  for (int idx = threadIdx.x; idx < 64 * 64; idx += blockDim.x)
    Wt[(idx & 63) * 65 + (idx >> 6)] = Ws[(idx >> 6) * 128 + (idx & 63)];
  __syncthreads();
  int lane = threadIdx.x & 63;
  volatile float* ab = AB[threadIdx.x >> 6];
  int wid = (blockIdx.x * blockDim.x + threadIdx.x) >> 6;
  int nw = (gridDim.x * blockDim.x) >> 6;
  float ss = 0.f;
  for (int i = wid; i < NU; i += nw) {
    float va = bf2f(u_next[(size_t)i * DD + lane]);
    float acc = bf2f(uc[(size_t)i * DD + lane]) + gemm64x1_b(va, Wt, ab, lane);
    users_raw[(size_t)i * DD + lane] = acc;
    ss += acc * acc;
  }
#pragma unroll
  for (int off = 32; off > 0; off >>= 1) ss += __shfl_xor(ss, off);
  if (lane == 0) atomicAdd(sumsq, ss);
}

__global__ void k_users_acc(const float* __restrict__ users_raw,
                            const float* __restrict__ sumsq, float* __restrict__ out_final) {
  float scale = 0.25f / sqrtf(*sumsq);  // fold final /4
  int idx = blockIdx.x * blockDim.x + threadIdx.x;
  for (; idx < NU * DD; idx += gridDim.x * blockDim.x)
    out_final[idx] += users_raw[idx] * scale;
}

extern "C" void kernel_launch(void* const* d_in, const int* in_sizes, int n_in,
                              void* d_out, int out_size, void* d_ws, size_t ws_size,
                              hipStream_t stream) {
  const float* u1      = (const float*)d_in[0];
  const float* u2      = (const float*)d_in[1];
  const float* item    = (const float*)d_in[2];
  const float* Wi      = (const float*)d_in[3];
  const float* Wc      = (const float*)d_in[4];
  const float* Ws      = (const float*)d_in[5];
  const float* fk_W    = (const float*)d_in[6];
  const float* fk_b    = (const float*)d_in[7];
  const float* A_vals  = (const float*)d_in[8];
  const float* A2_vals = (const float*)d_in[9];
  const float* S_vals  = (const float*)d_in[10];
  const int*   A_rows  = (const int*)d_in[11];
  const int*   A_cols  = (const int*)d_in[12];
  const int*   A2_rows = (const int*)d_in[13];
  const int*   A2_cols = (const int*)d_in[14];
  const int*   S_rows  = (const int*)d_in[15];
  const int*   S_cols  = (const int*)d_in[16];
  const int*   sh1     = (const int*)d_in[17];
  const int*   sh2     = (const int*)d_in[18];

  // ---- workspace layout (float offsets); cv arrays padded +8 int2 ----
  float* ws = (float*)d_ws;
  ushort* embA_bf = (ushort*)ws;                   // [0, 8M)   16M ushorts
  ushort* embB_bf = (ushort*)(ws + 8000000);       // [8M, 16M)
  uint2*  QUADP   = (uint2*)(ws + 16000000);       // [16M, 28.8M) dead after quad
  uint*   NEGPb   = (uint*)(ws + 16000000);        //   overlay: written at l=1 dual
  float*  uraw    = ws + 22400000;                 //   overlay: fp32 users scratch
  uint*   NEGPa   = (uint*)(ws + 28800000);        // [28.8M, 35.2M)
  ushort* u1s     = (ushort*)(ws + 35200000);      // [35.2M, 38.4M) dead after comb
  ushort* u2s     = (ushort*)(ws + 38400000);      // [38.4M, 41.6M) dead after comb
  int2*   cvA2    = (int2*)(ws + 35200000);        //   overlay: 2,000,008 int2
  int*    ptrA2   = (int*)(ws + 39200016);         //   overlay (250,001)
  uint*   SOCPt   = (uint*)(ws + 41600000);        // [41.6M, 48M) dead after negmap
  ushort* n1o     = (ushort*)(ws + 41600000);      //   overlay: written by quadS
  ushort* UCb     = (ushort*)(ws + 41600000);      //   overlay: written by comb_gemm
  ushort* n2o     = (ushort*)(ws + 44800000);      //   overlay: written by quadS
  int2*   cvA     = (int2*)(ws + 48000000);        // 2,000,008 int2
  int2*   cvS     = (int2*)(ws + 52000016);        // 800,008 int2
  int*    ptrA    = (int*)(ws + 53600032);         // 250,001
  int*    ptrS    = ptrA + (NTOT + 1);             // 100,001
  int*    cnt     = ptrS + (NU + 1);               // 250,000
  int*    bsum    = cnt + NTOT;                    // 256
  float*  c1r     = (float*)(bsum + 256);          // 64
  float*  c2r     = c1r + 64;
  float*  w1      = c2r + 64;
  float*  w2      = w1 + 64;
  float*  sumsq   = w2 + 64;                       // 1
  int*    rank    = (int*)(ws + 54200580);         // 2,000,000 -> 56,200,580 (224.8MB)

  float* out        = (float*)d_out;
  float* out_logits = out + (size_t)NTOT * DD;

  auto build = [&](const int* rows, const int* cols, const float* vals,
                   int n, int nnz, int* ptr, int2* cv) {
    int nb = (n + SCAN_CHUNK - 1) / SCAN_CHUNK;
    int gb = (nnz + 2047) / 2048;  // 256 thr x 8 edges
    hipMemsetAsync(cnt, 0, (size_t)n * sizeof(int), stream);
    k_hist_rank<<<gb, 256, 0, stream>>>(rows, cnt, rank, nnz);
    k_scan1<<<nb, 256, 0, stream>>>(cnt, bsum, n);
    k_scan2<<<1, 256, 0, stream>>>(bsum, nb);
    k_scan3<<<nb, 256, 0, stream>>>(cnt, bsum, ptr, n, nnz);
    k_scatter2<<<gb, 256, 0, stream>>>(rows, cols, vals, ptr, rank, cv, nnz);
    hipMemsetAsync(cv + nnz, 0, 8 * sizeof(int2), stream);  // overshoot pad
  };

  // ---------- CSR builds (S, A) ----------
  build(S_rows, S_cols, S_vals, NU, NNZ_S, ptrS, cvS);
  build(A_rows, A_cols, A_vals, NTOT, NNZ_A, ptrA, cvA);

  // ---------- init + pre-transform (dense) + neg remap into QUADP ----------
  hipMemsetAsync(c1r, 0, 128 * sizeof(float), stream);
  k_init<<<2048, 256, 0, stream>>>(u1, u2, item, embA_bf, out);
  k_transform<<<1024, 256, 0, stream>>>(u1, u2, Wc, SOCPt);
  k_negmap<<<1024, 256, 0, stream>>>(SOCPt, sh1, sh2, QUADP);

  // ---------- quad gather: socials + layer-0 negs + layer-1 table ----------
  k_quadS<<<2048, 256, 0, stream>>>(ptrS, cvS, QUADP, Wc,
                                    u1s, u2s, n1o, n2o, NEGPa);
  k_colsum2<<<256, 256, 0, stream>>>(u1s, u2s, c1r, c2r);
  k_wvec<<<1, 64, 0, stream>>>(fk_W, c1r, c2r, w1, w2);
  k_logits4<<<1024, 256, 0, stream>>>(u1s, u2s, n1o, n2o, w1, w2, fk_b, out_logits);
  k_comb_gemm<<<1024, 256, 0, stream>>>(u1s, u2s, Ws, UCb);

  // A2 CSR into the dead u1s/u2s region (persistent for layers 1,2)
  build(A2_rows, A2_cols, A2_vals, NTOT, NNZ_A, ptrA2, cvA2);

  // ---------- layer loop ----------
  ushort* embCur = embA_bf;
  ushort* embNext = embB_bf;
  for (int l = 0; l < 3; ++l) {
    const int* pA = (l == 0) ? ptrA : ptrA2;
    const int2* cA = (l == 0) ? cvA : cvA2;

    k_spmm_fusedA2<<<4096, 256, 0, stream>>>(pA, cA, embCur, Wi, embNext, out);

    if (l == 1)  // false-logits slot 4 + table for layer 2
      k_dualS<<<2048, 256, 0, stream>>>(ptrS, cvS, NEGPa, Wc, w2, w1, fk_b,
                                        out_logits, 4, NEGPb);
    else if (l == 2)  // false-logits slot 5, no next table
      k_dualS<<<2048, 256, 0, stream>>>(ptrS, cvS, NEGPb, Wc, w2, w1, fk_b,
                                        out_logits, 5, (uint*)nullptr);

    hipMemsetAsync(sumsq, 0, sizeof(float), stream);
    k_users<<<1024, 256, 0, stream>>>(embNext, UCb, Ws, uraw, sumsq);
    k_users_acc<<<2048, 256, 0, stream>>>(uraw, sumsq, out);

    { ushort* t = embCur; embCur = embNext; embNext = t; }
  }
}

// Round 17
// 1461.315 us; speedup vs baseline: 2.0913x; 1.0176x over previous
//
#include <hip/hip_runtime.h>

#define NU 100000
#define NI 150000
#define NTOT 250000
#define DD 64
#define NNZ_A 2000000
#define NNZ_S 800000
#define SCAN_CHUNK 2048  // 256 threads x 8
#define NBS 49   // ceil(NU/2048)
#define NBA 123  // ceil(NTOT/2048)
#define GBS 391  // ceil(NNZ_S/2048)
#define GBA 977  // ceil(NNZ_A/2048)

typedef unsigned int uint;
typedef unsigned short ushort;

#define LB __launch_bounds__(256, 4)
#define RFL(x) __builtin_amdgcn_readfirstlane(x)

__device__ __forceinline__ uint f2bf_bits(float x) {  // RNE round to bf16
  uint a = __float_as_uint(x);
  return (a + 0x7fffu + ((a >> 16) & 1u)) >> 16;
}
__device__ __forceinline__ ushort f2bf(float x) { return (ushort)f2bf_bits(x); }
__device__ __forceinline__ float bf2f(ushort h) { return __uint_as_float(((uint)h) << 16); }
__device__ __forceinline__ uint pack_bf16x2(float lo, float hi) {
  return f2bf_bits(lo) | (f2bf_bits(hi) << 16);
}
__device__ __forceinline__ float unpk_lo(uint p) { return __uint_as_float(p << 16); }
__device__ __forceinline__ float unpk_hi(uint p) { return __uint_as_float(p & 0xffff0000u); }

__device__ __forceinline__ float tanh_fast(float x) {
  float e = __expf(2.0f * x);
  return 1.0f - __fdividef(2.0f, e + 1.0f);
}

// ---- 64x64 GEMM with LDS-broadcast accumulator (R14-proven fencing) ----
__device__ __forceinline__ void gemm64x2_b(float aA, float aB,
                                           const float* __restrict__ Wt,
                                           volatile float* __restrict__ ab, int lane,
                                           float& oA, float& oB) {
  asm volatile("s_waitcnt lgkmcnt(0)" ::: "memory");
  __builtin_amdgcn_sched_barrier(0);
  ab[lane] = aA;
  ab[64 + lane] = aB;
  asm volatile("s_waitcnt lgkmcnt(0)" ::: "memory");
  __builtin_amdgcn_sched_barrier(0);
  float sA = 0.f, sB = 0.f;
#pragma unroll 4
  for (int k0 = 0; k0 < 64; k0 += 4) {
    float4 a4 = *(const float4*)(const float*)(ab + k0);
    float4 b4 = *(const float4*)(const float*)(ab + 64 + k0);
#pragma unroll
    for (int u = 0; u < 4; ++u) {
      float wk = Wt[(k0 + u) * 65 + lane];
      sA = fmaf(((const float*)&a4)[u], wk, sA);
      sB = fmaf(((const float*)&b4)[u], wk, sB);
    }
  }
  oA = sA; oB = sB;
}

__device__ __forceinline__ void gemm64x4_b(float a0, float a1, float a2, float a3,
                                           const float* __restrict__ Wt,
                                           volatile float* __restrict__ ab, int lane,
                                           float& o0, float& o1, float& o2, float& o3) {
  asm volatile("s_waitcnt lgkmcnt(0)" ::: "memory");
  __builtin_amdgcn_sched_barrier(0);
  ab[lane] = a0;
  ab[64 + lane] = a1;
  ab[128 + lane] = a2;
  ab[192 + lane] = a3;
  asm volatile("s_waitcnt lgkmcnt(0)" ::: "memory");
  __builtin_amdgcn_sched_barrier(0);
  float s0 = 0.f, s1 = 0.f, s2 = 0.f, s3 = 0.f;
#pragma unroll 4
  for (int k0 = 0; k0 < 64; k0 += 4) {
    float4 x0 = *(const float4*)(const float*)(ab + k0);
    float4 x1 = *(const float4*)(const float*)(ab + 64 + k0);
    float4 x2 = *(const float4*)(const float*)(ab + 128 + k0);
    float4 x3 = *(const float4*)(const float*)(ab + 192 + k0);
#pragma unroll
    for (int u = 0; u < 4; ++u) {
      float wk = Wt[(k0 + u) * 65 + lane];
      s0 = fmaf(((const float*)&x0)[u], wk, s0);
      s1 = fmaf(((const float*)&x1)[u], wk, s1);
      s2 = fmaf(((const float*)&x2)[u], wk, s2);
      s3 = fmaf(((const float*)&x3)[u], wk, s3);
    }
  }
  o0 = s0; o1 = s1; o2 = s2; o3 = s3;
}

__device__ __forceinline__ float gemm64x1_b(float a, const float* __restrict__ Wt,
                                            volatile float* __restrict__ ab, int lane) {
  asm volatile("s_waitcnt lgkmcnt(0)" ::: "memory");
  __builtin_amdgcn_sched_barrier(0);
  ab[lane] = a;
  asm volatile("s_waitcnt lgkmcnt(0)" ::: "memory");
  __builtin_amdgcn_sched_barrier(0);
  float s = 0.f;
#pragma unroll 4
  for (int k0 = 0; k0 < 64; k0 += 4) {
    float4 a4 = *(const float4*)(const float*)(ab + k0);
#pragma unroll
    for (int u = 0; u < 4; ++u)
      s = fmaf(((const float*)&a4)[u], Wt[(k0 + u) * 65 + lane], s);
  }
  return s;
}

__device__ __forceinline__ void stage_wt(const float* __restrict__ W, float* __restrict__ Wt) {
  for (int idx = threadIdx.x; idx < 64 * 64; idx += blockDim.x)
    Wt[(idx & 63) * 65 + (idx >> 6)] = W[idx];
  __syncthreads();
}

// ---------- items init only (user half folded into k_transform) ----------
__global__ void k_init_items(const float* __restrict__ item, ushort* __restrict__ emb_bf,
                             float* __restrict__ out_final) {
  int idx = blockIdx.x * blockDim.x + threadIdx.x;
  const int tot = NI * DD;
  const int nu = NU * DD;
  for (; idx < tot; idx += gridDim.x * blockDim.x) {
    float v = item[idx];
    emb_bf[nu + idx] = f2bf(v);
    out_final[nu + idx] = 0.25f * v;
  }
}

// ================= CSR build (counting sort, rank-in-hist) =================
__device__ __forceinline__ void hist_body(const int* rows, int* cnt, int* rank,
                                          int nnz, int bid, int nb) {
  int tid = bid * 256 + threadIdx.x;
  int gsz = nb * 256;
  for (int b = tid; b < nnz; b += gsz * 8) {
#pragma unroll
    for (int u = 0; u < 8; ++u) {
      int i = b + u * gsz;
      if (i < nnz) rank[i] = atomicAdd(&cnt[rows[i]], 1);
    }
  }
}

__global__ void k_hist1(const int* __restrict__ rows, int* __restrict__ cnt,
                        int* __restrict__ rank, int nnz) {
  hist_body(rows, cnt, rank, nnz, blockIdx.x, gridDim.x);
}

// batched S+A: blocks [0,GBS) -> S, [GBS,GBS+GBA) -> A
__global__ void k_hist2(const int* __restrict__ rowsS, int* __restrict__ cntS,
                        int* __restrict__ rankS,
                        const int* __restrict__ rowsA, int* __restrict__ cntA,
                        int* __restrict__ rankA) {
  if ((int)blockIdx.x < GBS) hist_body(rowsS, cntS, rankS, NNZ_S, blockIdx.x, GBS);
  else                       hist_body(rowsA, cntA, rankA, NNZ_A, blockIdx.x - GBS, GBA);
}

__device__ __forceinline__ void scan1_body(const int* cnt, int* bsum, int n, int bid) {
  __shared__ int sdata[256];
  int base = bid * SCAN_CHUNK;
  int s = 0;
#pragma unroll
  for (int k = 0; k < 8; ++k) {
    int i = base + threadIdx.x * 8 + k;
    s += (i < n) ? cnt[i] : 0;
  }
  sdata[threadIdx.x] = s;
  __syncthreads();
  for (int off = 128; off > 0; off >>= 1) {
    if (threadIdx.x < off) sdata[threadIdx.x] += sdata[threadIdx.x + off];
    __syncthreads();
  }
  if (threadIdx.x == 0) bsum[bid] = sdata[0];
}

__global__ void k_scan1(const int* __restrict__ cnt, int* __restrict__ bsum, int n) {
  scan1_body(cnt, bsum, n, blockIdx.x);
}

__global__ void k_scan1_2(const int* __restrict__ cntS, int* __restrict__ bsumS,
                          const int* __restrict__ cntA, int* __restrict__ bsumA) {
  if ((int)blockIdx.x < NBS) scan1_body(cntS, bsumS, NU, blockIdx.x);
  else                       scan1_body(cntA, bsumA, NTOT, blockIdx.x - NBS);
}

__device__ __forceinline__ void scan2_body(int* bsum, int nb) {
  __shared__ int sdata[256];
  int v = (threadIdx.x < nb) ? bsum[threadIdx.x] : 0;
  sdata[threadIdx.x] = v;
  __syncthreads();
  for (int off = 1; off < 256; off <<= 1) {
    int t = (threadIdx.x >= (unsigned)off) ? sdata[threadIdx.x - off] : 0;
    __syncthreads();
    sdata[threadIdx.x] += t;
    __syncthreads();
  }
  if (threadIdx.x < nb) bsum[threadIdx.x] = sdata[threadIdx.x] - v;
}

__global__ void k_scan2(int* bsum, int nb) { scan2_body(bsum, nb); }

__global__ void k_scan2_2(int* bsumS, int* bsumA) {
  if (blockIdx.x == 0) scan2_body(bsumS, NBS);
  else                 scan2_body(bsumA, NBA);
}

__device__ __forceinline__ void scan3_body(const int* cnt, const int* bsum,
                                           int* rowptr, int n, int nnz, int bid) {
  __shared__ int sdata[256];
  int base = bid * SCAN_CHUNK;
  int loc[8];
  int s = 0;
#pragma unroll
  for (int k = 0; k < 8; ++k) {
    int i = base + threadIdx.x * 8 + k;
    loc[k] = (i < n) ? cnt[i] : 0;
    s += loc[k];
  }
  sdata[threadIdx.x] = s;
  __syncthreads();
  for (int off = 1; off < 256; off <<= 1) {
    int t = (threadIdx.x >= (unsigned)off) ? sdata[threadIdx.x - off] : 0;
    __syncthreads();
    sdata[threadIdx.x] += t;
    __syncthreads();
  }
  int pre = bsum[bid] + sdata[threadIdx.x] - s;
#pragma unroll
  for (int k = 0; k < 8; ++k) {
    int i = base + threadIdx.x * 8 + k;
    if (i < n) { rowptr[i] = pre; pre += loc[k]; }
  }
  if (bid == 0 && threadIdx.x == 0) rowptr[n] = nnz;
}

__global__ void k_scan3(const int* __restrict__ cnt, const int* __restrict__ bsum,
                        int* __restrict__ rowptr, int n, int nnz) {
  scan3_body(cnt, bsum, rowptr, n, nnz, blockIdx.x);
}

__global__ void k_scan3_2(const int* __restrict__ cntS, const int* __restrict__ bsumS,
                          int* __restrict__ ptrS,
                          const int* __restrict__ cntA, const int* __restrict__ bsumA,
                          int* __restrict__ ptrA) {
  if ((int)blockIdx.x < NBS) scan3_body(cntS, bsumS, ptrS, NU, NNZ_S, blockIdx.x);
  else                       scan3_body(cntA, bsumA, ptrA, NTOT, NNZ_A, blockIdx.x - NBS);
}

__device__ __forceinline__ void scatter_body(const int* rows, const int* cols,
                                             const float* vals, const int* ptr,
                                             const int* rank, int2* cv, int nnz,
                                             int bid, int nb) {
  int tid = bid * 256 + threadIdx.x;
  int gsz = nb * 256;
  for (int b = tid; b < nnz; b += gsz * 8) {
#pragma unroll
    for (int u = 0; u < 8; ++u) {
      int i = b + u * gsz;
      if (i < nnz) {
        int r = rows[i];
        cv[ptr[r] + rank[i]] = make_int2(cols[i], __float_as_int(vals[i]));
      }
    }
  }
  if (bid == 0 && threadIdx.x < 8) cv[nnz + threadIdx.x] = make_int2(0, 0);  // pad
}

__global__ void k_scatter1(const int* __restrict__ rows, const int* __restrict__ cols,
                           const float* __restrict__ vals, const int* __restrict__ ptr,
                           const int* __restrict__ rank, int2* __restrict__ cv, int nnz) {
  scatter_body(rows, cols, vals, ptr, rank, cv, nnz, blockIdx.x, gridDim.x);
}

__global__ void k_scatter2_2(const int* __restrict__ rowsS, const int* __restrict__ colsS,
                             const float* __restrict__ valsS, const int* __restrict__ ptrS,
                             const int* __restrict__ rankS, int2* __restrict__ cvS,
                             const int* __restrict__ rowsA, const int* __restrict__ colsA,
                             const float* __restrict__ valsA, const int* __restrict__ ptrA,
                             const int* __restrict__ rankA, int2* __restrict__ cvA) {
  if ((int)blockIdx.x < GBS)
    scatter_body(rowsS, colsS, valsS, ptrS, rankS, cvS, NNZ_S, blockIdx.x, GBS);
  else
    scatter_body(rowsA, colsA, valsA, ptrA, rankA, cvA, NNZ_A, blockIdx.x - GBS, GBA);
}

// ================= dense pre-transform (+ fused user init) =================
__global__ LB void k_transform(const float* __restrict__ u1, const float* __restrict__ u2,
                               const float* __restrict__ Wc, uint* __restrict__ SOCPt,
                               ushort* __restrict__ emb_bf, float* __restrict__ out_final) {
  __shared__ float Wt[64 * 65];
  __shared__ float AB[4][128];
  stage_wt(Wc, Wt);
  int lane = threadIdx.x & 63;
  volatile float* ab = AB[threadIdx.x >> 6];
  int wid = (blockIdx.x * blockDim.x + threadIdx.x) >> 6;
  int nw = (gridDim.x * blockDim.x) >> 6;
  for (int i = wid; i < NU; i += nw) {
    float a1 = u1[(size_t)i * DD + lane];
    float a2 = u2[(size_t)i * DD + lane];
    float v = 0.5f * (a1 + a2);                     // fused user-init
    emb_bf[(size_t)i * DD + lane] = f2bf(v);
    out_final[(size_t)i * DD + lane] = 0.25f * v;
    float o1, o2;
    gemm64x2_b(a1, a2, Wt, ab, lane, o1, o2);
    SOCPt[(size_t)i * DD + lane] = pack_bf16x2(o1, o2);
  }
}

// QUADP[i] = { SOCPt[i], lo16(SOCPt[s1[i]]) | hi16(SOCPt[s2[i]]) }
__global__ void k_negmap(const uint* __restrict__ SOCPt, const int* __restrict__ s1,
                         const int* __restrict__ s2, uint2* __restrict__ QUADP) {
  int idx = blockIdx.x * blockDim.x + threadIdx.x;
  const int tot = NU * DD;
  for (; idx < tot; idx += gridDim.x * blockDim.x) {
    int i = idx >> 6, j = idx & 63;
    uint soc = SOCPt[idx];
    uint lo = SOCPt[(size_t)s1[i] * DD + j];
    uint hi = SOCPt[(size_t)s2[i] * DD + j];
    QUADP[idx] = make_uint2(soc, (lo & 0xffffu) | (hi & 0xffff0000u));
  }
}

// ================= gather kernels (R16-validated, frozen) =================
__global__ LB void k_quadS(const int* __restrict__ rowptr, const int2* __restrict__ cv,
                           const uint2* __restrict__ QUADP, const float* __restrict__ Wc,
                           ushort* __restrict__ u1s, ushort* __restrict__ u2s,
                           ushort* __restrict__ n1o, ushort* __restrict__ n2o,
                           uint* __restrict__ NEGPa) {
  __shared__ float Wt[64 * 65];
  __shared__ float AB[4][128];
  stage_wt(Wc, Wt);
  int lane = threadIdx.x & 63;
  volatile float* ab = AB[threadIdx.x >> 6];
  int wid = (blockIdx.x * blockDim.x + threadIdx.x) >> 6;
  int nw = (gridDim.x * blockDim.x) >> 6;
  for (int r = wid; r < NU; r += nw) {
    int start = RFL(rowptr[r]);
    int n = RFL(rowptr[r + 1]) - start;
    float a1 = 0.f, a2 = 0.f, a3 = 0.f, a4 = 0.f;
    for (int k = 0; k < n; k += 8) {
      int2 e[8];
#pragma unroll
      for (int u = 0; u < 8; ++u) e[u] = cv[start + k + u];
      uint2 q[8];
#pragma unroll
      for (int u = 0; u < 8; ++u)
        q[u] = QUADP[(size_t)(uint)e[u].x * 64u + (uint)lane];
#pragma unroll
      for (int u = 0; u < 8; ++u) {
        float sv = (k + u < n) ? __int_as_float(e[u].y) : 0.f;
        a1 = fmaf(sv, unpk_lo(q[u].x), a1);
        a2 = fmaf(sv, unpk_hi(q[u].x), a2);
        a3 = fmaf(sv, unpk_lo(q[u].y), a3);
        a4 = fmaf(sv, unpk_hi(q[u].y), a4);
      }
    }
    float t1 = tanh_fast(a1), t2 = tanh_fast(a2), t3 = tanh_fast(a3), t4 = tanh_fast(a4);
    u1s[(size_t)r * DD + lane] = f2bf(t1);
    u2s[(size_t)r * DD + lane] = f2bf(t2);
    n1o[(size_t)r * DD + lane] = f2bf(t3);
    n2o[(size_t)r * DD + lane] = f2bf(t4);
    float o3, o4;
    gemm64x2_b(t3, t4, Wt, ab, lane, o3, o4);
    NEGPa[(size_t)r * DD + lane] = pack_bf16x2(o3, o4);
  }
}

__global__ LB void k_dualS(const int* __restrict__ rowptr, const int2* __restrict__ cv,
                           const uint* __restrict__ T, const float* __restrict__ Wc,
                           const float* __restrict__ wva, const float* __restrict__ wvb,
                           const float* __restrict__ fkb, float* __restrict__ out_logits,
                           int slot, uint* __restrict__ Tnext) {
  __shared__ float Wt[64 * 65];
  __shared__ float AB[4][256];
  stage_wt(Wc, Wt);
  int lane = threadIdx.x & 63;
  volatile float* ab = AB[threadIdx.x >> 6];
  int wid = (blockIdx.x * blockDim.x + threadIdx.x) >> 6;
  int nw = (gridDim.x * blockDim.x) >> 6;
  float b = fkb[0];
  float wa = wva[lane], wb = wvb[lane];
  for (int r = wid * 2; r < NU; r += nw * 2) {
    int s0 = RFL(rowptr[r]);
    int sm = RFL(rowptr[r + 1]);
    int s1e = RFL(rowptr[r + 2]);
    int n0 = sm - s0, n1 = s1e - sm;
    int kmax = max(n0, n1);
    float a0A = 0.f, a0B = 0.f, a1A = 0.f, a1B = 0.f;
    for (int k = 0; k < kmax; k += 8) {
      int b0 = (k < n0) ? s0 + k : s0;
      int b1 = (k < n1) ? sm + k : sm;
      int2 e0[8], e1[8];
#pragma unroll
      for (int u = 0; u < 8; ++u) e0[u] = cv[b0 + u];
#pragma unroll
      for (int u = 0; u < 8; ++u) e1[u] = cv[b1 + u];
      uint q0[8], q1[8];
#pragma unroll
      for (int u = 0; u < 8; ++u)
        q0[u] = T[(size_t)(uint)e0[u].x * 64u + (uint)lane];
#pragma unroll
      for (int u = 0; u < 8; ++u)
        q1[u] = T[(size_t)(uint)e1[u].x * 64u + (uint)lane];
#pragma unroll
      for (int u = 0; u < 8; ++u) {
        float sv0 = (k + u < n0) ? __int_as_float(e0[u].y) : 0.f;
        float sv1 = (k + u < n1) ? __int_as_float(e1[u].y) : 0.f;
        a0A = fmaf(sv0, unpk_lo(q0[u]), a0A);
        a0B = fmaf(sv0, unpk_hi(q0[u]), a0B);
        a1A = fmaf(sv1, unpk_lo(q1[u]), a1A);
        a1B = fmaf(sv1, unpk_hi(q1[u]), a1B);
      }
    }
    float t0a = tanh_fast(a0A), t0b = tanh_fast(a0B);
    float t1a = tanh_fast(a1A), t1b = tanh_fast(a1B);
    float p0a = t0a * wa, p0b = t0b * wb, p1a = t1a * wa, p1b = t1b * wb;
#pragma unroll
    for (int off = 32; off > 0; off >>= 1) {
      p0a += __shfl_xor(p0a, off);
      p0b += __shfl_xor(p0b, off);
      p1a += __shfl_xor(p1a, off);
      p1b += __shfl_xor(p1b, off);
    }
    if (lane == 0) {
      out_logits[(size_t)(NU + r) * 6 + slot] = p0a + b;
      out_logits[(size_t)r * 6 + slot] = p0b + b;
      out_logits[(size_t)(NU + r + 1) * 6 + slot] = p1a + b;
      out_logits[(size_t)(r + 1) * 6 + slot] = p1b + b;
    }
    if (Tnext) {
      float o0a, o0b, o1a, o1b;
      gemm64x4_b(t0a, t0b, t1a, t1b, Wt, ab, lane, o0a, o0b, o1a, o1b);
      Tnext[(size_t)r * DD + lane] = pack_bf16x2(o0a, o0b);
      Tnext[(size_t)(r + 1) * DD + lane] = pack_bf16x2(o1a, o1b);
    }
  }
}

__global__ LB void k_spmm_fusedA2(const int* __restrict__ rowptr, const int2* __restrict__ cv,
                                  const ushort* __restrict__ X, const float* __restrict__ W,
                                  ushort* __restrict__ embNext, float* __restrict__ outF) {
  __shared__ float Wt[64 * 65];
  __shared__ float AB[4][256];
  stage_wt(W, Wt);
  int lane = threadIdx.x & 63;
  volatile float* ab = AB[threadIdx.x >> 6];
  int wid = (blockIdx.x * blockDim.x + threadIdx.x) >> 6;
  int nw = (gridDim.x * blockDim.x) >> 6;
  for (int r = wid * 4; r < NTOT; r += nw * 4) {
    int sp[5];
#pragma unroll
    for (int i = 0; i < 5; ++i) sp[i] = RFL(rowptr[r + i]);
    int n0 = sp[1] - sp[0], n1 = sp[2] - sp[1];
    int n2 = sp[3] - sp[2], n3 = sp[4] - sp[3];
    int kmax = max(max(n0, n1), max(n2, n3));
    float acc0 = 0.f, acc1 = 0.f, acc2 = 0.f, acc3 = 0.f;
    for (int k = 0; k < kmax; k += 8) {
      int b0 = (k < n0) ? sp[0] + k : sp[0];
      int b1 = (k < n1) ? sp[1] + k : sp[1];
      int b2 = (k < n2) ? sp[2] + k : sp[2];
      int b3 = (k < n3) ? sp[3] + k : sp[3];
      int2 e0[8], e1[8], e2[8], e3[8];
#pragma unroll
      for (int u = 0; u < 8; ++u) e0[u] = cv[b0 + u];
#pragma unroll
      for (int u = 0; u < 8; ++u) e1[u] = cv[b1 + u];
#pragma unroll
      for (int u = 0; u < 8; ++u) e2[u] = cv[b2 + u];
#pragma unroll
      for (int u = 0; u < 8; ++u) e3[u] = cv[b3 + u];
      uint h0[8], h1[8], h2[8], h3[8];
#pragma unroll
      for (int u = 0; u < 8; ++u)
        h0[u] = X[(size_t)(uint)e0[u].x * 64u + (uint)lane];
#pragma unroll
      for (int u = 0; u < 8; ++u)
        h1[u] = X[(size_t)(uint)e1[u].x * 64u + (uint)lane];
#pragma unroll
      for (int u = 0; u < 8; ++u)
        h2[u] = X[(size_t)(uint)e2[u].x * 64u + (uint)lane];
#pragma unroll
      for (int u = 0; u < 8; ++u)
        h3[u] = X[(size_t)(uint)e3[u].x * 64u + (uint)lane];
#pragma unroll
      for (int u = 0; u < 8; ++u) {
        float sv0 = (k + u < n0) ? __int_as_float(e0[u].y) : 0.f;
        float sv1 = (k + u < n1) ? __int_as_float(e1[u].y) : 0.f;
        float sv2 = (k + u < n2) ? __int_as_float(e2[u].y) : 0.f;
        float sv3 = (k + u < n3) ? __int_as_float(e3[u].y) : 0.f;
        acc0 = fmaf(sv0, __uint_as_float(h0[u] << 16), acc0);
        acc1 = fmaf(sv1, __uint_as_float(h1[u] << 16), acc1);
        acc2 = fmaf(sv2, __uint_as_float(h2[u] << 16), acc2);
        acc3 = fmaf(sv3, __uint_as_float(h3[u] << 16), acc3);
      }
    }
    if (r < NU) {  // NU % 4 == 0: group never straddles
      float o0, o1, o2, o3;
      gemm64x4_b(acc0, acc1, acc2, acc3, Wt, ab, lane, o0, o1, o2, o3);
      embNext[(size_t)r * DD + lane] = f2bf(tanh_fast(o0));
      embNext[(size_t)(r + 1) * DD + lane] = f2bf(tanh_fast(o1));
      embNext[(size_t)(r + 2) * DD + lane] = f2bf(tanh_fast(o2));
      embNext[(size_t)(r + 3) * DD + lane] = f2bf(tanh_fast(o3));
    } else {
      embNext[(size_t)r * DD + lane] = f2bf(acc0);
      embNext[(size_t)(r + 1) * DD + lane] = f2bf(acc1);
      embNext[(size_t)(r + 2) * DD + lane] = f2bf(acc2);
      embNext[(size_t)(r + 3) * DD + lane] = f2bf(acc3);
      outF[(size_t)r * DD + lane] += 0.25f * acc0;
      outF[(size_t)(r + 1) * DD + lane] += 0.25f * acc1;
      outF[(size_t)(r + 2) * DD + lane] += 0.25f * acc2;
      outF[(size_t)(r + 3) * DD + lane] += 0.25f * acc3;
    }
  }
}

// ---------- fused column sums (bf16 inputs) ----------
__global__ void k_colsum2(const ushort* __restrict__ x1, const ushort* __restrict__ x2,
                          float* __restrict__ c1, float* __restrict__ c2) {
  int lane = threadIdx.x & 63;
  int wid = (blockIdx.x * blockDim.x + threadIdx.x) >> 6;
  int nw = (gridDim.x * blockDim.x) >> 6;
  float a1 = 0.f, a2 = 0.f;
  for (int i = wid; i < NU; i += nw) {
    a1 += bf2f(x1[(size_t)i * DD + lane]);
    a2 += bf2f(x2[(size_t)i * DD + lane]);
  }
  atomicAdd(&c1[lane], a1);
  atomicAdd(&c2[lane], a2);
}

__global__ void k_wvec(const float* __restrict__ fkW, const float* __restrict__ c1r,
                       const float* __restrict__ c2r, float* __restrict__ w1,
                       float* __restrict__ w2) {
  int j = threadIdx.x;
  float a1 = 0.f, a2 = 0.f;
  for (int k = 0; k < 64; ++k) {
    float w = fkW[j * 64 + k];
    a1 += w * c1r[k];
    a2 += w * c2r[k];
  }
  w1[j] = a1 * (1.0f / NU);
  w2[j] = a2 * (1.0f / NU);
}

__global__ void k_logits4(const ushort* __restrict__ u1s, const ushort* __restrict__ u2s,
                          const ushort* __restrict__ n1o, const ushort* __restrict__ n2o,
                          const float* __restrict__ w1, const float* __restrict__ w2,
                          const float* __restrict__ fkb, float* __restrict__ out_logits) {
  int lane = threadIdx.x & 63;
  int wid = (blockIdx.x * blockDim.x + threadIdx.x) >> 6;
  int nw = (gridDim.x * blockDim.x) >> 6;
  float b = fkb[0];
  for (int i = wid; i < 2 * NU; i += nw) {
    bool lo = i < NU;
    int r = lo ? i : i - NU;
    const ushort* xs = lo ? u2s : u1s;
    const ushort* xn = lo ? n2o : n1o;
    const float* wv = lo ? w1 : w2;
    float wvl = wv[lane];
    float ps = bf2f(xs[(size_t)r * DD + lane]) * wvl;
    float pn = bf2f(xn[(size_t)r * DD + lane]) * wvl;
#pragma unroll
    for (int off = 32; off > 0; off >>= 1) {
      ps += __shfl_xor(ps, off);
      pn += __shfl_xor(pn, off);
    }
    if (lane == 0) {
      float vs = ps + b;
      out_logits[(size_t)i * 6 + 0] = vs;
      out_logits[(size_t)i * 6 + 1] = vs;
      out_logits[(size_t)i * 6 + 2] = vs;
      out_logits[(size_t)i * 6 + 3] = pn + b;
    }
  }
}

__global__ LB void k_comb_gemm(const ushort* __restrict__ u1s, const ushort* __restrict__ u2s,
                               const float* __restrict__ Ws, ushort* __restrict__ UC) {
  __shared__ float Wt[64 * 65];
  __shared__ float AB[4][128];
  for (int idx = threadIdx.x; idx < 64 * 64; idx += blockDim.x)
    Wt[(idx & 63) * 65 + (idx >> 6)] = Ws[(idx >> 6) * 128 + 64 + (idx & 63)];
  __syncthreads();
  int lane = threadIdx.x & 63;
  volatile float* ab = AB[threadIdx.x >> 6];
  int wid = (blockIdx.x * blockDim.x + threadIdx.x) >> 6;
  int nw = (gridDim.x * blockDim.x) >> 6;
  for (int i = wid; i < NU; i += nw) {
    float c = 0.5f * (bf2f(u1s[(size_t)i * DD + lane]) + bf2f(u2s[(size_t)i * DD + lane]));
    UC[(size_t)i * DD + lane] = f2bf(gemm64x1_b(c, Wt, ab, lane));
  }
}

__global__ LB void k_users(const ushort* __restrict__ u_next, const ushort* __restrict__ uc,
                           const float* __restrict__ Ws, float* __restrict__ users_raw,
                           float* __restrict__ sumsq) {
  __shared__ float Wt[64 * 65];
  __shared__ float AB[4][128];
  for (int idx = threadIdx.x; idx < 64 * 64; idx += blockDim.x)
    Wt[(idx & 63) * 65 + (idx >> 6)] = Ws[(idx >> 6) * 128 + (idx & 63)];
  __syncthreads();
  int lane = threadIdx.x & 63;
  volatile float* ab = AB[threadIdx.x >> 6];
  int wid = (blockIdx.x * blockDim.x + threadIdx.x) >> 6;
  int nw = (gridDim.x * blockDim.x) >> 6;
  float ss = 0.f;
  for (int i = wid; i < NU; i += nw) {
    float va = bf2f(u_next[(size_t)i * DD + lane]);
    float acc = bf2f(uc[(size_t)i * DD + lane]) + gemm64x1_b(va, Wt, ab, lane);
    users_raw[(size_t)i * DD + lane] = acc;
    ss += acc * acc;
  }
#pragma unroll
  for (int off = 32; off > 0; off >>= 1) ss += __shfl_xor(ss, off);
  if (lane == 0) atomicAdd(sumsq, ss);
}

__global__ void k_users_acc(const float* __restrict__ users_raw,
                            const float* __restrict__ sumsq, float* __restrict__ out_final) {
  float scale = 0.25f / sqrtf(*sumsq);
  int idx = blockIdx.x * blockDim.x + threadIdx.x;
  for (; idx < NU * DD; idx += gridDim.x * blockDim.x)
    out_final[idx] += users_raw[idx] * scale;
}

extern "C" void kernel_launch(void* const* d_in, const int* in_sizes, int n_in,
                              void* d_out, int out_size, void* d_ws, size_t ws_size,
                              hipStream_t stream) {
  const float* u1      = (const float*)d_in[0];
  const float* u2      = (const float*)d_in[1];
  const float* item    = (const float*)d_in[2];
  const float* Wi      = (const float*)d_in[3];
  const float* Wc      = (const float*)d_in[4];
  const float* Ws      = (const float*)d_in[5];
  const float* fk_W    = (const float*)d_in[6];
  const float* fk_b    = (const float*)d_in[7];
  const float* A_vals  = (const float*)d_in[8];
  const float* A2_vals = (const float*)d_in[9];
  const float* S_vals  = (const float*)d_in[10];
  const int*   A_rows  = (const int*)d_in[11];
  const int*   A_cols  = (const int*)d_in[12];
  const int*   A2_rows = (const int*)d_in[13];
  const int*   A2_cols = (const int*)d_in[14];
  const int*   S_rows  = (const int*)d_in[15];
  const int*   S_cols  = (const int*)d_in[16];
  const int*   sh1     = (const int*)d_in[17];
  const int*   sh2     = (const int*)d_in[18];

  // ---- workspace layout (float-word offsets); cv arrays padded +8 int2 ----
  float* ws = (float*)d_ws;
  ushort* embA_bf = (ushort*)ws;                   // [0, 8M)
  ushort* embB_bf = (ushort*)(ws + 8000000);       // [8M, 16M)
  uint2*  QUADP   = (uint2*)(ws + 16000000);       // [16M, 28.8M) live negmap..quadS
  //  build-time overlays inside QUADP region (dead until negmap):
  int*    rankS2  = (int*)(ws + 16000000);         // 800,000
  int*    rankA   = (int*)(ws + 16800000);         // 2,000,000
  int*    cntS    = (int*)(ws + 18800000);         // 100,000 } contiguous
  int*    cntA    = (int*)(ws + 18900000);         // 250,000 } one memset
  int*    bsumS   = (int*)(ws + 19150000);         // 256
  int*    bsumA   = (int*)(ws + 19150256);         // 256
  uint*   NEGPb   = (uint*)(ws + 16000000);        //  overlay: l=1 dual output
  float*  uraw    = ws + 22400000;                 //  overlay: fp32 users scratch
  uint*   NEGPa   = (uint*)(ws + 28800000);        // [28.8M, 35.2M)
  ushort* u1s     = (ushort*)(ws + 35200000);      // [35.2M, 38.4M) dead after comb
  ushort* u2s     = (ushort*)(ws + 38400000);      // [38.4M, 41.6M) dead after comb
  int2*   cvA2    = (int2*)(ws + 35200000);        //  overlay: built after comb
  int*    ptrA2   = (int*)(ws + 39200016);         //  overlay
  uint*   SOCPt   = (uint*)(ws + 41600000);        // [41.6M, 48M) dead after negmap
  ushort* n1o     = (ushort*)(ws + 41600000);      //  overlay: quadS output
  ushort* UCb     = (ushort*)(ws + 41600000);      //  overlay: comb output
  ushort* n2o     = (ushort*)(ws + 44800000);      //  overlay: quadS output
  int2*   cvA     = (int2*)(ws + 48000000);        // 2,000,008 int2
  int2*   cvS     = (int2*)(ws + 52000016);        // 800,008 int2
  int*    ptrA    = (int*)(ws + 53600032);         // 250,001
  int*    ptrS    = ptrA + (NTOT + 1);             // 100,001
  int*    cnt     = ptrS + (NU + 1);               // 250,000 (A2 build)
  int*    bsum    = cnt + NTOT;                    // 256
  float*  c1r     = (float*)(bsum + 256);          // 64
  float*  c2r     = c1r + 64;
  float*  w1      = c2r + 64;
  float*  w2      = w1 + 64;
  float*  sumsq   = w2 + 64;                       // 1
  int*    rank    = (int*)(ws + 54200580);         // 2,000,000 (A2 build)

  float* out        = (float*)d_out;
  float* out_logits = out + (size_t)NTOT * DD;

  // ---------- batched S+A CSR build ----------
  hipMemsetAsync(cntS, 0, 350000 * sizeof(int), stream);
  k_hist2<<<GBS + GBA, 256, 0, stream>>>(S_rows, cntS, rankS2, A_rows, cntA, rankA);
  k_scan1_2<<<NBS + NBA, 256, 0, stream>>>(cntS, bsumS, cntA, bsumA);
  k_scan2_2<<<2, 256, 0, stream>>>(bsumS, bsumA);
  k_scan3_2<<<NBS + NBA, 256, 0, stream>>>(cntS, bsumS, ptrS, cntA, bsumA, ptrA);
  k_scatter2_2<<<GBS + GBA, 256, 0, stream>>>(S_rows, S_cols, S_vals, ptrS, rankS2, cvS,
                                              A_rows, A_cols, A_vals, ptrA, rankA, cvA);

  // ---------- init(items) + transform(+user init) + negmap ----------
  hipMemsetAsync(c1r, 0, 128 * sizeof(float), stream);
  k_init_items<<<1024, 256, 0, stream>>>(item, embA_bf, out);
  k_transform<<<1024, 256, 0, stream>>>(u1, u2, Wc, SOCPt, embA_bf, out);
  k_negmap<<<1024, 256, 0, stream>>>(SOCPt, sh1, sh2, QUADP);

  // ---------- quad gather: socials + layer-0 negs + layer-1 table ----------
  k_quadS<<<2048, 256, 0, stream>>>(ptrS, cvS, QUADP, Wc, u1s, u2s, n1o, n2o, NEGPa);
  k_colsum2<<<256, 256, 0, stream>>>(u1s, u2s, c1r, c2r);
  k_wvec<<<1, 64, 0, stream>>>(fk_W, c1r, c2r, w1, w2);
  k_logits4<<<1024, 256, 0, stream>>>(u1s, u2s, n1o, n2o, w1, w2, fk_b, out_logits);
  k_comb_gemm<<<1024, 256, 0, stream>>>(u1s, u2s, Ws, UCb);

  // ---------- A2 CSR build (deferred: cvA2 overlays dead u1s/u2s) ----------
  {
    int nb = (NTOT + SCAN_CHUNK - 1) / SCAN_CHUNK;
    int gb = (NNZ_A + 2047) / 2048;
    hipMemsetAsync(cnt, 0, (size_t)NTOT * sizeof(int), stream);
    k_hist1<<<gb, 256, 0, stream>>>(A2_rows, cnt, rank, NNZ_A);
    k_scan1<<<nb, 256, 0, stream>>>(cnt, bsum, NTOT);
    k_scan2<<<1, 256, 0, stream>>>(bsum, nb);
    k_scan3<<<nb, 256, 0, stream>>>(cnt, bsum, ptrA2, NTOT, NNZ_A);
    k_scatter1<<<gb, 256, 0, stream>>>(A2_rows, A2_cols, A2_vals, ptrA2, rank, cvA2, NNZ_A);
  }

  // ---------- layer loop ----------
  ushort* embCur = embA_bf;
  ushort* embNext = embB_bf;
  for (int l = 0; l < 3; ++l) {
    const int* pA = (l == 0) ? ptrA : ptrA2;
    const int2* cA = (l == 0) ? cvA : cvA2;

    k_spmm_fusedA2<<<4096, 256, 0, stream>>>(pA, cA, embCur, Wi, embNext, out);

    if (l == 1)
      k_dualS<<<2048, 256, 0, stream>>>(ptrS, cvS, NEGPa, Wc, w2, w1, fk_b,
                                        out_logits, 4, NEGPb);
    else if (l == 2)
      k_dualS<<<2048, 256, 0, stream>>>(ptrS, cvS, NEGPb, Wc, w2, w1, fk_b,
                                        out_logits, 5, (uint*)nullptr);

    hipMemsetAsync(sumsq, 0, sizeof(float), stream);
    k_users<<<1024, 256, 0, stream>>>(embNext, UCb, Ws, uraw, sumsq);
    k_users_acc<<<2048, 256, 0, stream>>>(uraw, sumsq, out);

    { ushort* t = embCur; embCur = embNext; embNext = t; }
  }
}

// Round 18
// 1458.174 us; speedup vs baseline: 2.0958x; 1.0022x over previous
//
#include <hip/hip_runtime.h>

#define NU 100000
#define NI 150000
#define NTOT 250000
#define DD 64
#define NNZ_A 2000000
#define NNZ_S 800000
#define SCAN_CHUNK 2048  // 256 threads x 8
#define NBS 49   // ceil(NU/2048)
#define NBA 123  // ceil(NTOT/2048)
#define GBS 391  // ceil(NNZ_S/2048)
#define GBA 977  // ceil(NNZ_A/2048)

typedef unsigned int uint;
typedef unsigned short ushort;

#define LB __launch_bounds__(256, 4)
#define RFL(x) __builtin_amdgcn_readfirstlane(x)

__device__ __forceinline__ uint f2bf_bits(float x) {  // RNE round to bf16
  uint a = __float_as_uint(x);
  return (a + 0x7fffu + ((a >> 16) & 1u)) >> 16;
}
__device__ __forceinline__ ushort f2bf(float x) { return (ushort)f2bf_bits(x); }
__device__ __forceinline__ float bf2f(ushort h) { return __uint_as_float(((uint)h) << 16); }
__device__ __forceinline__ uint pack_bf16x2(float lo, float hi) {
  return f2bf_bits(lo) | (f2bf_bits(hi) << 16);
}
__device__ __forceinline__ float unpk_lo(uint p) { return __uint_as_float(p << 16); }
__device__ __forceinline__ float unpk_hi(uint p) { return __uint_as_float(p & 0xffff0000u); }

__device__ __forceinline__ float tanh_fast(float x) {
  float e = __expf(2.0f * x);
  return 1.0f - __fdividef(2.0f, e + 1.0f);
}

// ---- 64x64 GEMM with LDS-broadcast accumulator (R14-proven fencing) ----
__device__ __forceinline__ void gemm64x2_b(float aA, float aB,
                                           const float* __restrict__ Wt,
                                           volatile float* __restrict__ ab, int lane,
                                           float& oA, float& oB) {
  asm volatile("s_waitcnt lgkmcnt(0)" ::: "memory");
  __builtin_amdgcn_sched_barrier(0);
  ab[lane] = aA;
  ab[64 + lane] = aB;
  asm volatile("s_waitcnt lgkmcnt(0)" ::: "memory");
  __builtin_amdgcn_sched_barrier(0);
  float sA = 0.f, sB = 0.f;
#pragma unroll 4
  for (int k0 = 0; k0 < 64; k0 += 4) {
    float4 a4 = *(const float4*)(const float*)(ab + k0);
    float4 b4 = *(const float4*)(const float*)(ab + 64 + k0);
#pragma unroll
    for (int u = 0; u < 4; ++u) {
      float wk = Wt[(k0 + u) * 65 + lane];
      sA = fmaf(((const float*)&a4)[u], wk, sA);
      sB = fmaf(((const float*)&b4)[u], wk, sB);
    }
  }
  oA = sA; oB = sB;
}

__device__ __forceinline__ void gemm64x4_b(float a0, float a1, float a2, float a3,
                                           const float* __restrict__ Wt,
                                           volatile float* __restrict__ ab, int lane,
                                           float& o0, float& o1, float& o2, float& o3) {
  asm volatile("s_waitcnt lgkmcnt(0)" ::: "memory");
  __builtin_amdgcn_sched_barrier(0);
  ab[lane] = a0;
  ab[64 + lane] = a1;
  ab[128 + lane] = a2;
  ab[192 + lane] = a3;
  asm volatile("s_waitcnt lgkmcnt(0)" ::: "memory");
  __builtin_amdgcn_sched_barrier(0);
  float s0 = 0.f, s1 = 0.f, s2 = 0.f, s3 = 0.f;
#pragma unroll 4
  for (int k0 = 0; k0 < 64; k0 += 4) {
    float4 x0 = *(const float4*)(const float*)(ab + k0);
    float4 x1 = *(const float4*)(const float*)(ab + 64 + k0);
    float4 x2 = *(const float4*)(const float*)(ab + 128 + k0);
    float4 x3 = *(const float4*)(const float*)(ab + 192 + k0);
#pragma unroll
    for (int u = 0; u < 4; ++u) {
      float wk = Wt[(k0 + u) * 65 + lane];
      s0 = fmaf(((const float*)&x0)[u], wk, s0);
      s1 = fmaf(((const float*)&x1)[u], wk, s1);
      s2 = fmaf(((const float*)&x2)[u], wk, s2);
      s3 = fmaf(((const float*)&x3)[u], wk, s3);
    }
  }
  o0 = s0; o1 = s1; o2 = s2; o3 = s3;
}

__device__ __forceinline__ float gemm64x1_b(float a, const float* __restrict__ Wt,
                                            volatile float* __restrict__ ab, int lane) {
  asm volatile("s_waitcnt lgkmcnt(0)" ::: "memory");
  __builtin_amdgcn_sched_barrier(0);
  ab[lane] = a;
  asm volatile("s_waitcnt lgkmcnt(0)" ::: "memory");
  __builtin_amdgcn_sched_barrier(0);
  float s = 0.f;
#pragma unroll 4
  for (int k0 = 0; k0 < 64; k0 += 4) {
    float4 a4 = *(const float4*)(const float*)(ab + k0);
#pragma unroll
    for (int u = 0; u < 4; ++u)
      s = fmaf(((const float*)&a4)[u], Wt[(k0 + u) * 65 + lane], s);
  }
  return s;
}

__device__ __forceinline__ void stage_wt(const float* __restrict__ W, float* __restrict__ Wt) {
  for (int idx = threadIdx.x; idx < 64 * 64; idx += blockDim.x)
    Wt[(idx & 63) * 65 + (idx >> 6)] = W[idx];
  __syncthreads();
}

// ---------- items init only (user half folded into k_transform) ----------
__global__ void k_init_items(const float* __restrict__ item, ushort* __restrict__ emb_bf,
                             float* __restrict__ out_final) {
  int idx = blockIdx.x * blockDim.x + threadIdx.x;
  const int tot = NI * DD;
  const int nu = NU * DD;
  for (; idx < tot; idx += gridDim.x * blockDim.x) {
    float v = item[idx];
    emb_bf[nu + idx] = f2bf(v);
    out_final[nu + idx] = 0.25f * v;
  }
}

// ================= CSR build (counting sort, rank-in-hist) =================
__device__ __forceinline__ void hist_body(const int* rows, int* cnt, int* rank,
                                          int nnz, int bid, int nb) {
  int tid = bid * 256 + threadIdx.x;
  int gsz = nb * 256;
  for (int b = tid; b < nnz; b += gsz * 8) {
#pragma unroll
    for (int u = 0; u < 8; ++u) {
      int i = b + u * gsz;
      if (i < nnz) rank[i] = atomicAdd(&cnt[rows[i]], 1);
    }
  }
}

// 3-way batched: blocks [0,GBS) -> S, [GBS,GBS+GBA) -> A, rest -> A2
__global__ void k_hist3(const int* __restrict__ rowsS, int* __restrict__ cntS,
                        int* __restrict__ rankS,
                        const int* __restrict__ rowsA, int* __restrict__ cntA,
                        int* __restrict__ rankA,
                        const int* __restrict__ rowsA2, int* __restrict__ cntA2,
                        int* __restrict__ rankA2) {
  if ((int)blockIdx.x < GBS)
    hist_body(rowsS, cntS, rankS, NNZ_S, blockIdx.x, GBS);
  else if ((int)blockIdx.x < GBS + GBA)
    hist_body(rowsA, cntA, rankA, NNZ_A, blockIdx.x - GBS, GBA);
  else
    hist_body(rowsA2, cntA2, rankA2, NNZ_A, blockIdx.x - GBS - GBA, GBA);
}

__device__ __forceinline__ void scan1_body(const int* cnt, int* bsum, int n, int bid) {
  __shared__ int sdata[256];
  int base = bid * SCAN_CHUNK;
  int s = 0;
#pragma unroll
  for (int k = 0; k < 8; ++k) {
    int i = base + threadIdx.x * 8 + k;
    s += (i < n) ? cnt[i] : 0;
  }
  sdata[threadIdx.x] = s;
  __syncthreads();
  for (int off = 128; off > 0; off >>= 1) {
    if (threadIdx.x < off) sdata[threadIdx.x] += sdata[threadIdx.x + off];
    __syncthreads();
  }
  if (threadIdx.x == 0) bsum[bid] = sdata[0];
}

__global__ void k_scan1_3(const int* __restrict__ cntS, int* __restrict__ bsumS,
                          const int* __restrict__ cntA, int* __restrict__ bsumA,
                          const int* __restrict__ cntA2, int* __restrict__ bsumA2) {
  if ((int)blockIdx.x < NBS)            scan1_body(cntS, bsumS, NU, blockIdx.x);
  else if ((int)blockIdx.x < NBS + NBA) scan1_body(cntA, bsumA, NTOT, blockIdx.x - NBS);
  else                                  scan1_body(cntA2, bsumA2, NTOT, blockIdx.x - NBS - NBA);
}

__device__ __forceinline__ void scan2_body(int* bsum, int nb) {
  __shared__ int sdata[256];
  int v = (threadIdx.x < nb) ? bsum[threadIdx.x] : 0;
  sdata[threadIdx.x] = v;
  __syncthreads();
  for (int off = 1; off < 256; off <<= 1) {
    int t = (threadIdx.x >= (unsigned)off) ? sdata[threadIdx.x - off] : 0;
    __syncthreads();
    sdata[threadIdx.x] += t;
    __syncthreads();
  }
  if (threadIdx.x < nb) bsum[threadIdx.x] = sdata[threadIdx.x] - v;
}

__global__ void k_scan2_3(int* bsumS, int* bsumA, int* bsumA2) {
  if (blockIdx.x == 0)      scan2_body(bsumS, NBS);
  else if (blockIdx.x == 1) scan2_body(bsumA, NBA);
  else                      scan2_body(bsumA2, NBA);
}

__device__ __forceinline__ void scan3_body(const int* cnt, const int* bsum,
                                           int* rowptr, int n, int nnz, int bid) {
  __shared__ int sdata[256];
  int base = bid * SCAN_CHUNK;
  int loc[8];
  int s = 0;
#pragma unroll
  for (int k = 0; k < 8; ++k) {
    int i = base + threadIdx.x * 8 + k;
    loc[k] = (i < n) ? cnt[i] : 0;
    s += loc[k];
  }
  sdata[threadIdx.x] = s;
  __syncthreads();
  for (int off = 1; off < 256; off <<= 1) {
    int t = (threadIdx.x >= (unsigned)off) ? sdata[threadIdx.x - off] : 0;
    __syncthreads();
    sdata[threadIdx.x] += t;
    __syncthreads();
  }
  int pre = bsum[bid] + sdata[threadIdx.x] - s;
#pragma unroll
  for (int k = 0; k < 8; ++k) {
    int i = base + threadIdx.x * 8 + k;
    if (i < n) { rowptr[i] = pre; pre += loc[k]; }
  }
  if (bid == 0 && threadIdx.x == 0) rowptr[n] = nnz;
}

__global__ void k_scan3_3(const int* __restrict__ cntS, const int* __restrict__ bsumS,
                          int* __restrict__ ptrS,
                          const int* __restrict__ cntA, const int* __restrict__ bsumA,
                          int* __restrict__ ptrA,
                          const int* __restrict__ cntA2, const int* __restrict__ bsumA2,
                          int* __restrict__ ptrA2) {
  if ((int)blockIdx.x < NBS)            scan3_body(cntS, bsumS, ptrS, NU, NNZ_S, blockIdx.x);
  else if ((int)blockIdx.x < NBS + NBA) scan3_body(cntA, bsumA, ptrA, NTOT, NNZ_A, blockIdx.x - NBS);
  else                                  scan3_body(cntA2, bsumA2, ptrA2, NTOT, NNZ_A, blockIdx.x - NBS - NBA);
}

__device__ __forceinline__ void scatter_body(const int* rows, const int* cols,
                                             const float* vals, const int* ptr,
                                             const int* rank, int2* cv, int nnz,
                                             int bid, int nb) {
  int tid = bid * 256 + threadIdx.x;
  int gsz = nb * 256;
  for (int b = tid; b < nnz; b += gsz * 8) {
#pragma unroll
    for (int u = 0; u < 8; ++u) {
      int i = b + u * gsz;
      if (i < nnz) {
        int r = rows[i];
        cv[ptr[r] + rank[i]] = make_int2(cols[i], __float_as_int(vals[i]));
      }
    }
  }
  if (bid == 0 && threadIdx.x < 8) cv[nnz + threadIdx.x] = make_int2(0, 0);  // pad
}

__global__ void k_scatter1(const int* __restrict__ rows, const int* __restrict__ cols,
                           const float* __restrict__ vals, const int* __restrict__ ptr,
                           const int* __restrict__ rank, int2* __restrict__ cv, int nnz) {
  scatter_body(rows, cols, vals, ptr, rank, cv, nnz, blockIdx.x, gridDim.x);
}

__global__ void k_scatter2_2(const int* __restrict__ rowsS, const int* __restrict__ colsS,
                             const float* __restrict__ valsS, const int* __restrict__ ptrS,
                             const int* __restrict__ rankS, int2* __restrict__ cvS,
                             const int* __restrict__ rowsA, const int* __restrict__ colsA,
                             const float* __restrict__ valsA, const int* __restrict__ ptrA,
                             const int* __restrict__ rankA, int2* __restrict__ cvA) {
  if ((int)blockIdx.x < GBS)
    scatter_body(rowsS, colsS, valsS, ptrS, rankS, cvS, NNZ_S, blockIdx.x, GBS);
  else
    scatter_body(rowsA, colsA, valsA, ptrA, rankA, cvA, NNZ_A, blockIdx.x - GBS, GBA);
}

// ================= dense pre-transform (+ fused user init) =================
__global__ LB void k_transform(const float* __restrict__ u1, const float* __restrict__ u2,
                               const float* __restrict__ Wc, uint* __restrict__ SOCPt,
                               ushort* __restrict__ emb_bf, float* __restrict__ out_final) {
  __shared__ float Wt[64 * 65];
  __shared__ float AB[4][128];
  stage_wt(Wc, Wt);
  int lane = threadIdx.x & 63;
  volatile float* ab = AB[threadIdx.x >> 6];
  int wid = (blockIdx.x * blockDim.x + threadIdx.x) >> 6;
  int nw = (gridDim.x * blockDim.x) >> 6;
  for (int i = wid; i < NU; i += nw) {
    float a1 = u1[(size_t)i * DD + lane];
    float a2 = u2[(size_t)i * DD + lane];
    float v = 0.5f * (a1 + a2);
    emb_bf[(size_t)i * DD + lane] = f2bf(v);
    out_final[(size_t)i * DD + lane] = 0.25f * v;
    float o1, o2;
    gemm64x2_b(a1, a2, Wt, ab, lane, o1, o2);
    SOCPt[(size_t)i * DD + lane] = pack_bf16x2(o1, o2);
  }
}

// QUADP[i] = { SOCPt[i], lo16(SOCPt[s1[i]]) | hi16(SOCPt[s2[i]]) }
__global__ void k_negmap(const uint* __restrict__ SOCPt, const int* __restrict__ s1,
                         const int* __restrict__ s2, uint2* __restrict__ QUADP) {
  int idx = blockIdx.x * blockDim.x + threadIdx.x;
  const int tot = NU * DD;
  for (; idx < tot; idx += gridDim.x * blockDim.x) {
    int i = idx >> 6, j = idx & 63;
    uint soc = SOCPt[idx];
    uint lo = SOCPt[(size_t)s1[i] * DD + j];
    uint hi = SOCPt[(size_t)s2[i] * DD + j];
    QUADP[idx] = make_uint2(soc, (lo & 0xffffu) | (hi & 0xffff0000u));
  }
}

// ================= gather kernels (R16-validated, frozen) =================
__global__ LB void k_quadS(const int* __restrict__ rowptr, const int2* __restrict__ cv,
                           const uint2* __restrict__ QUADP, const float* __restrict__ Wc,
                           ushort* __restrict__ u1s, ushort* __restrict__ u2s,
                           ushort* __restrict__ n1o, ushort* __restrict__ n2o,
                           uint* __restrict__ NEGPa) {
  __shared__ float Wt[64 * 65];
  __shared__ float AB[4][128];
  stage_wt(Wc, Wt);
  int lane = threadIdx.x & 63;
  volatile float* ab = AB[threadIdx.x >> 6];
  int wid = (blockIdx.x * blockDim.x + threadIdx.x) >> 6;
  int nw = (gridDim.x * blockDim.x) >> 6;
  for (int r = wid; r < NU; r += nw) {
    int start = RFL(rowptr[r]);
    int n = RFL(rowptr[r + 1]) - start;
    float a1 = 0.f, a2 = 0.f, a3 = 0.f, a4 = 0.f;
    for (int k = 0; k < n; k += 8) {
      int2 e[8];
#pragma unroll
      for (int u = 0; u < 8; ++u) e[u] = cv[start + k + u];
      uint2 q[8];
#pragma unroll
      for (int u = 0; u < 8; ++u)
        q[u] = QUADP[(size_t)(uint)e[u].x * 64u + (uint)lane];
#pragma unroll
      for (int u = 0; u < 8; ++u) {
        float sv = (k + u < n) ? __int_as_float(e[u].y) : 0.f;
        a1 = fmaf(sv, unpk_lo(q[u].x), a1);
        a2 = fmaf(sv, unpk_hi(q[u].x), a2);
        a3 = fmaf(sv, unpk_lo(q[u].y), a3);
        a4 = fmaf(sv, unpk_hi(q[u].y), a4);
      }
    }
    float t1 = tanh_fast(a1), t2 = tanh_fast(a2), t3 = tanh_fast(a3), t4 = tanh_fast(a4);
    u1s[(size_t)r * DD + lane] = f2bf(t1);
    u2s[(size_t)r * DD + lane] = f2bf(t2);
    n1o[(size_t)r * DD + lane] = f2bf(t3);
    n2o[(size_t)r * DD + lane] = f2bf(t4);
    float o3, o4;
    gemm64x2_b(t3, t4, Wt, ab, lane, o3, o4);
    NEGPa[(size_t)r * DD + lane] = pack_bf16x2(o3, o4);
  }
}

__global__ LB void k_dualS(const int* __restrict__ rowptr, const int2* __restrict__ cv,
                           const uint* __restrict__ T, const float* __restrict__ Wc,
                           const float* __restrict__ wva, const float* __restrict__ wvb,
                           const float* __restrict__ fkb, float* __restrict__ out_logits,
                           int slot, uint* __restrict__ Tnext) {
  __shared__ float Wt[64 * 65];
  __shared__ float AB[4][256];
  stage_wt(Wc, Wt);
  int lane = threadIdx.x & 63;
  volatile float* ab = AB[threadIdx.x >> 6];
  int wid = (blockIdx.x * blockDim.x + threadIdx.x) >> 6;
  int nw = (gridDim.x * blockDim.x) >> 6;
  float b = fkb[0];
  float wa = wva[lane], wb = wvb[lane];
  for (int r = wid * 2; r < NU; r += nw * 2) {
    int s0 = RFL(rowptr[r]);
    int sm = RFL(rowptr[r + 1]);
    int s1e = RFL(rowptr[r + 2]);
    int n0 = sm - s0, n1 = s1e - sm;
    int kmax = max(n0, n1);
    float a0A = 0.f, a0B = 0.f, a1A = 0.f, a1B = 0.f;
    for (int k = 0; k < kmax; k += 8) {
      int b0 = (k < n0) ? s0 + k : s0;
      int b1 = (k < n1) ? sm + k : sm;
      int2 e0[8], e1[8];
#pragma unroll
      for (int u = 0; u < 8; ++u) e0[u] = cv[b0 + u];
#pragma unroll
      for (int u = 0; u < 8; ++u) e1[u] = cv[b1 + u];
      uint q0[8], q1[8];
#pragma unroll
      for (int u = 0; u < 8; ++u)
        q0[u] = T[(size_t)(uint)e0[u].x * 64u + (uint)lane];
#pragma unroll
      for (int u = 0; u < 8; ++u)
        q1[u] = T[(size_t)(uint)e1[u].x * 64u + (uint)lane];
#pragma unroll
      for (int u = 0; u < 8; ++u) {
        float sv0 = (k + u < n0) ? __int_as_float(e0[u].y) : 0.f;
        float sv1 = (k + u < n1) ? __int_as_float(e1[u].y) : 0.f;
        a0A = fmaf(sv0, unpk_lo(q0[u]), a0A);
        a0B = fmaf(sv0, unpk_hi(q0[u]), a0B);
        a1A = fmaf(sv1, unpk_lo(q1[u]), a1A);
        a1B = fmaf(sv1, unpk_hi(q1[u]), a1B);
      }
    }
    float t0a = tanh_fast(a0A), t0b = tanh_fast(a0B);
    float t1a = tanh_fast(a1A), t1b = tanh_fast(a1B);
    float p0a = t0a * wa, p0b = t0b * wb, p1a = t1a * wa, p1b = t1b * wb;
#pragma unroll
    for (int off = 32; off > 0; off >>= 1) {
      p0a += __shfl_xor(p0a, off);
      p0b += __shfl_xor(p0b, off);
      p1a += __shfl_xor(p1a, off);
      p1b += __shfl_xor(p1b, off);
    }
    if (lane == 0) {
      out_logits[(size_t)(NU + r) * 6 + slot] = p0a + b;
      out_logits[(size_t)r * 6 + slot] = p0b + b;
      out_logits[(size_t)(NU + r + 1) * 6 + slot] = p1a + b;
      out_logits[(size_t)(r + 1) * 6 + slot] = p1b + b;
    }
    if (Tnext) {
      float o0a, o0b, o1a, o1b;
      gemm64x4_b(t0a, t0b, t1a, t1b, Wt, ab, lane, o0a, o0b, o1a, o1b);
      Tnext[(size_t)r * DD + lane] = pack_bf16x2(o0a, o0b);
      Tnext[(size_t)(r + 1) * DD + lane] = pack_bf16x2(o1a, o1b);
    }
  }
}

__global__ LB void k_spmm_fusedA2(const int* __restrict__ rowptr, const int2* __restrict__ cv,
                                  const ushort* __restrict__ X, const float* __restrict__ W,
                                  ushort* __restrict__ embNext, float* __restrict__ outF) {
  __shared__ float Wt[64 * 65];
  __shared__ float AB[4][256];
  stage_wt(W, Wt);
  int lane = threadIdx.x & 63;
  volatile float* ab = AB[threadIdx.x >> 6];
  int wid = (blockIdx.x * blockDim.x + threadIdx.x) >> 6;
  int nw = (gridDim.x * blockDim.x) >> 6;
  for (int r = wid * 4; r < NTOT; r += nw * 4) {
    int sp[5];
#pragma unroll
    for (int i = 0; i < 5; ++i) sp[i] = RFL(rowptr[r + i]);
    int n0 = sp[1] - sp[0], n1 = sp[2] - sp[1];
    int n2 = sp[3] - sp[2], n3 = sp[4] - sp[3];
    int kmax = max(max(n0, n1), max(n2, n3));
    float acc0 = 0.f, acc1 = 0.f, acc2 = 0.f, acc3 = 0.f;
    for (int k = 0; k < kmax; k += 8) {
      int b0 = (k < n0) ? sp[0] + k : sp[0];
      int b1 = (k < n1) ? sp[1] + k : sp[1];
      int b2 = (k < n2) ? sp[2] + k : sp[2];
      int b3 = (k < n3) ? sp[3] + k : sp[3];
      int2 e0[8], e1[8], e2[8], e3[8];
#pragma unroll
      for (int u = 0; u < 8; ++u) e0[u] = cv[b0 + u];
#pragma unroll
      for (int u = 0; u < 8; ++u) e1[u] = cv[b1 + u];
#pragma unroll
      for (int u = 0; u < 8; ++u) e2[u] = cv[b2 + u];
#pragma unroll
      for (int u = 0; u < 8; ++u) e3[u] = cv[b3 + u];
      uint h0[8], h1[8], h2[8], h3[8];
#pragma unroll
      for (int u = 0; u < 8; ++u)
        h0[u] = X[(size_t)(uint)e0[u].x * 64u + (uint)lane];
#pragma unroll
      for (int u = 0; u < 8; ++u)
        h1[u] = X[(size_t)(uint)e1[u].x * 64u + (uint)lane];
#pragma unroll
      for (int u = 0; u < 8; ++u)
        h2[u] = X[(size_t)(uint)e2[u].x * 64u + (uint)lane];
#pragma unroll
      for (int u = 0; u < 8; ++u)
        h3[u] = X[(size_t)(uint)e3[u].x * 64u + (uint)lane];
#pragma unroll
      for (int u = 0; u < 8; ++u) {
        float sv0 = (k + u < n0) ? __int_as_float(e0[u].y) : 0.f;
        float sv1 = (k + u < n1) ? __int_as_float(e1[u].y) : 0.f;
        float sv2 = (k + u < n2) ? __int_as_float(e2[u].y) : 0.f;
        float sv3 = (k + u < n3) ? __int_as_float(e3[u].y) : 0.f;
        acc0 = fmaf(sv0, __uint_as_float(h0[u] << 16), acc0);
        acc1 = fmaf(sv1, __uint_as_float(h1[u] << 16), acc1);
        acc2 = fmaf(sv2, __uint_as_float(h2[u] << 16), acc2);
        acc3 = fmaf(sv3, __uint_as_float(h3[u] << 16), acc3);
      }
    }
    if (r < NU) {  // NU % 4 == 0: group never straddles
      float o0, o1, o2, o3;
      gemm64x4_b(acc0, acc1, acc2, acc3, Wt, ab, lane, o0, o1, o2, o3);
      embNext[(size_t)r * DD + lane] = f2bf(tanh_fast(o0));
      embNext[(size_t)(r + 1) * DD + lane] = f2bf(tanh_fast(o1));
      embNext[(size_t)(r + 2) * DD + lane] = f2bf(tanh_fast(o2));
      embNext[(size_t)(r + 3) * DD + lane] = f2bf(tanh_fast(o3));
    } else {
      embNext[(size_t)r * DD + lane] = f2bf(acc0);
      embNext[(size_t)(r + 1) * DD + lane] = f2bf(acc1);
      embNext[(size_t)(r + 2) * DD + lane] = f2bf(acc2);
      embNext[(size_t)(r + 3) * DD + lane] = f2bf(acc3);
      outF[(size_t)r * DD + lane] += 0.25f * acc0;
      outF[(size_t)(r + 1) * DD + lane] += 0.25f * acc1;
      outF[(size_t)(r + 2) * DD + lane] += 0.25f * acc2;
      outF[(size_t)(r + 3) * DD + lane] += 0.25f * acc3;
    }
  }
}

// ---------- fused column sums (bf16 inputs) ----------
__global__ void k_colsum2(const ushort* __restrict__ x1, const ushort* __restrict__ x2,
                          float* __restrict__ c1, float* __restrict__ c2) {
  int lane = threadIdx.x & 63;
  int wid = (blockIdx.x * blockDim.x + threadIdx.x) >> 6;
  int nw = (gridDim.x * blockDim.x) >> 6;
  float a1 = 0.f, a2 = 0.f;
  for (int i = wid; i < NU; i += nw) {
    a1 += bf2f(x1[(size_t)i * DD + lane]);
    a2 += bf2f(x2[(size_t)i * DD + lane]);
  }
  atomicAdd(&c1[lane], a1);
  atomicAdd(&c2[lane], a2);
}

__global__ void k_wvec(const float* __restrict__ fkW, const float* __restrict__ c1r,
                       const float* __restrict__ c2r, float* __restrict__ w1,
                       float* __restrict__ w2) {
  int j = threadIdx.x;
  float a1 = 0.f, a2 = 0.f;
  for (int k = 0; k < 64; ++k) {
    float w = fkW[j * 64 + k];
    a1 += w * c1r[k];
    a2 += w * c2r[k];
  }
  w1[j] = a1 * (1.0f / NU);
  w2[j] = a2 * (1.0f / NU);
}

__global__ void k_logits4(const ushort* __restrict__ u1s, const ushort* __restrict__ u2s,
                          const ushort* __restrict__ n1o, const ushort* __restrict__ n2o,
                          const float* __restrict__ w1, const float* __restrict__ w2,
                          const float* __restrict__ fkb, float* __restrict__ out_logits) {
  int lane = threadIdx.x & 63;
  int wid = (blockIdx.x * blockDim.x + threadIdx.x) >> 6;
  int nw = (gridDim.x * blockDim.x) >> 6;
  float b = fkb[0];
  for (int i = wid; i < 2 * NU; i += nw) {
    bool lo = i < NU;
    int r = lo ? i : i - NU;
    const ushort* xs = lo ? u2s : u1s;
    const ushort* xn = lo ? n2o : n1o;
    const float* wv = lo ? w1 : w2;
    float wvl = wv[lane];
    float ps = bf2f(xs[(size_t)r * DD + lane]) * wvl;
    float pn = bf2f(xn[(size_t)r * DD + lane]) * wvl;
#pragma unroll
    for (int off = 32; off > 0; off >>= 1) {
      ps += __shfl_xor(ps, off);
      pn += __shfl_xor(pn, off);
    }
    if (lane == 0) {
      float vs = ps + b;
      out_logits[(size_t)i * 6 + 0] = vs;
      out_logits[(size_t)i * 6 + 1] = vs;
      out_logits[(size_t)i * 6 + 2] = vs;
      out_logits[(size_t)i * 6 + 3] = pn + b;
    }
  }
}

__global__ LB void k_comb_gemm(const ushort* __restrict__ u1s, const ushort* __restrict__ u2s,
                               const float* __restrict__ Ws, ushort* __restrict__ UC) {
  __shared__ float Wt[64 * 65];
  __shared__ float AB[4][128];
  for (int idx = threadIdx.x; idx < 64 * 64; idx += blockDim.x)
    Wt[(idx & 63) * 65 + (idx >> 6)] = Ws[(idx >> 6) * 128 + 64 + (idx & 63)];
  __syncthreads();
  int lane = threadIdx.x & 63;
  volatile float* ab = AB[threadIdx.x >> 6];
  int wid = (blockIdx.x * blockDim.x + threadIdx.x) >> 6;
  int nw = (gridDim.x * blockDim.x) >> 6;
  for (int i = wid; i < NU; i += nw) {
    float c = 0.5f * (bf2f(u1s[(size_t)i * DD + lane]) + bf2f(u2s[(size_t)i * DD + lane]));
    UC[(size_t)i * DD + lane] = f2bf(gemm64x1_b(c, Wt, ab, lane));
  }
}

__global__ LB void k_users(const ushort* __restrict__ u_next, const ushort* __restrict__ uc,
                           const float* __restrict__ Ws, float* __restrict__ users_raw,
                           float* __restrict__ sumsq) {
  __shared__ float Wt[64 * 65];
  __shared__ float AB[4][128];
  for (int idx = threadIdx.x; idx < 64 * 64; idx += blockDim.x)
    Wt[(idx & 63) * 65 + (idx >> 6)] = Ws[(idx >> 6) * 128 + (idx & 63)];
  __syncthreads();
  int lane = threadIdx.x & 63;
  volatile float* ab = AB[threadIdx.x >> 6];
  int wid = (blockIdx.x * blockDim.x + threadIdx.x) >> 6;
  int nw = (gridDim.x * blockDim.x) >> 6;
  float ss = 0.f;
  for (int i = wid; i < NU; i += nw) {
    float va = bf2f(u_next[(size_t)i * DD + lane]);
    float acc = bf2f(uc[(size_t)i * DD + lane]) + gemm64x1_b(va, Wt, ab, lane);
    users_raw[(size_t)i * DD + lane] = acc;
    ss += acc * acc;
  }
#pragma unroll
  for (int off = 32; off > 0; off >>= 1) ss += __shfl_xor(ss, off);
  if (lane == 0) atomicAdd(sumsq, ss);
}

__global__ void k_users_acc(const float* __restrict__ users_raw,
                            const float* __restrict__ sumsq, float* __restrict__ out_final) {
  float scale = 0.25f / sqrtf(*sumsq);
  int idx = blockIdx.x * blockDim.x + threadIdx.x;
  for (; idx < NU * DD; idx += gridDim.x * blockDim.x)
    out_final[idx] += users_raw[idx] * scale;
}

extern "C" void kernel_launch(void* const* d_in, const int* in_sizes, int n_in,
                              void* d_out, int out_size, void* d_ws, size_t ws_size,
                              hipStream_t stream) {
  const float* u1      = (const float*)d_in[0];
  const float* u2      = (const float*)d_in[1];
  const float* item    = (const float*)d_in[2];
  const float* Wi      = (const float*)d_in[3];
  const float* Wc      = (const float*)d_in[4];
  const float* Ws      = (const float*)d_in[5];
  const float* fk_W    = (const float*)d_in[6];
  const float* fk_b    = (const float*)d_in[7];
  const float* A_vals  = (const float*)d_in[8];
  const float* A2_vals = (const float*)d_in[9];
  const float* S_vals  = (const float*)d_in[10];
  const int*   A_rows  = (const int*)d_in[11];
  const int*   A_cols  = (const int*)d_in[12];
  const int*   A2_rows = (const int*)d_in[13];
  const int*   A2_cols = (const int*)d_in[14];
  const int*   S_rows  = (const int*)d_in[15];
  const int*   S_cols  = (const int*)d_in[16];
  const int*   sh1     = (const int*)d_in[17];
  const int*   sh2     = (const int*)d_in[18];

  // ---- workspace layout (float-word offsets); cv arrays padded +8 int2 ----
  float* ws = (float*)d_ws;
  ushort* embA_bf = (ushort*)ws;                   // [0, 8M)
  ushort* embB_bf = (ushort*)(ws + 8000000);       // [8M, 16M)
  uint2*  QUADP   = (uint2*)(ws + 16000000);       // [16M, 28.8M) live negmap..quadS
  //  build-time overlays inside QUADP region (dead until negmap):
  int*    rankS2  = (int*)(ws + 16000000);         // 800,000
  int*    rankA   = (int*)(ws + 16800000);         // 2,000,000
  int*    cntS    = (int*)(ws + 18800000);         // 100,000 } contiguous
  int*    cntA    = (int*)(ws + 18900000);         // 250,000 } one memset
  int*    bsumS   = (int*)(ws + 19150000);         // 256
  int*    bsumA   = (int*)(ws + 19150256);         // 256
  int*    bsumA2  = (int*)(ws + 19150512);         // 256 (QUADP overlay too)
  uint*   NEGPb   = (uint*)(ws + 16000000);        //  overlay: l=1 dual output
  float*  uraw    = ws + 22400000;                 //  overlay: fp32 users scratch
  uint*   NEGPa   = (uint*)(ws + 28800000);        // [28.8M, 35.2M)
  ushort* u1s     = (ushort*)(ws + 35200000);      // [35.2M, 38.4M) dead after comb
  ushort* u2s     = (ushort*)(ws + 38400000);      // [38.4M, 41.6M) dead after comb
  int2*   cvA2    = (int2*)(ws + 35200000);        //  overlay: scatter after comb
  uint*   SOCPt   = (uint*)(ws + 41600000);        // [41.6M, 48M) dead after negmap
  ushort* n1o     = (ushort*)(ws + 41600000);      //  overlay: quadS output
  ushort* UCb     = (ushort*)(ws + 41600000);      //  overlay: comb output
  ushort* n2o     = (ushort*)(ws + 44800000);      //  overlay: quadS output
  int2*   cvA     = (int2*)(ws + 48000000);        // 2,000,008 int2
  int2*   cvS     = (int2*)(ws + 52000016);        // 800,008 int2
  int*    ptrA    = (int*)(ws + 53600032);         // 250,001
  int*    ptrS    = ptrA + (NTOT + 1);             // 100,001
  int*    cntA2   = ptrS + (NU + 1);               // 250,000 (permanent, A2)
  int*    bsum_un = cntA2 + NTOT;                  // 256 (unused spare)
  float*  c1r     = (float*)(bsum_un + 256);       // 64
  float*  c2r     = c1r + 64;
  float*  w1      = c2r + 64;
  float*  w2      = w1 + 64;
  float*  sumsq   = w2 + 64;                       // 1
  int*    rankA2  = (int*)(ws + 54200580);         // 2,000,000
  int*    ptrA2   = (int*)(ws + 56200580);         // 250,001 -> 56,450,581 (225.8MB)

  float* out        = (float*)d_out;
  float* out_logits = out + (size_t)NTOT * DD;

  // ---------- 3-way batched CSR build (S, A, A2); only A2 scatter deferred ----------
  hipMemsetAsync(cntS, 0, 350000 * sizeof(int), stream);          // cntS+cntA
  hipMemsetAsync(cntA2, 0, (size_t)NTOT * sizeof(int), stream);   // cntA2
  k_hist3<<<GBS + 2 * GBA, 256, 0, stream>>>(S_rows, cntS, rankS2,
                                             A_rows, cntA, rankA,
                                             A2_rows, cntA2, rankA2);
  k_scan1_3<<<NBS + 2 * NBA, 256, 0, stream>>>(cntS, bsumS, cntA, bsumA, cntA2, bsumA2);
  k_scan2_3<<<3, 256, 0, stream>>>(bsumS, bsumA, bsumA2);
  k_scan3_3<<<NBS + 2 * NBA, 256, 0, stream>>>(cntS, bsumS, ptrS,
                                               cntA, bsumA, ptrA,
                                               cntA2, bsumA2, ptrA2);
  k_scatter2_2<<<GBS + GBA, 256, 0, stream>>>(S_rows, S_cols, S_vals, ptrS, rankS2, cvS,
                                              A_rows, A_cols, A_vals, ptrA, rankA, cvA);

  // ---------- init(items) + transform(+user init) + negmap ----------
  hipMemsetAsync(c1r, 0, 128 * sizeof(float), stream);
  k_init_items<<<1024, 256, 0, stream>>>(item, embA_bf, out);
  k_transform<<<1024, 256, 0, stream>>>(u1, u2, Wc, SOCPt, embA_bf, out);
  k_negmap<<<1024, 256, 0, stream>>>(SOCPt, sh1, sh2, QUADP);

  // ---------- quad gather: socials + layer-0 negs + layer-1 table ----------
  k_quadS<<<2048, 256, 0, stream>>>(ptrS, cvS, QUADP, Wc, u1s, u2s, n1o, n2o, NEGPa);
  k_colsum2<<<256, 256, 0, stream>>>(u1s, u2s, c1r, c2r);
  k_wvec<<<1, 64, 0, stream>>>(fk_W, c1r, c2r, w1, w2);
  k_logits4<<<1024, 256, 0, stream>>>(u1s, u2s, n1o, n2o, w1, w2, fk_b, out_logits);
  k_comb_gemm<<<1024, 256, 0, stream>>>(u1s, u2s, Ws, UCb);

  // ---------- A2 scatter (deferred: cvA2 overlays dead u1s/u2s) ----------
  k_scatter1<<<GBA, 256, 0, stream>>>(A2_rows, A2_cols, A2_vals, ptrA2, rankA2,
                                      cvA2, NNZ_A);

  // ---------- layer loop ----------
  ushort* embCur = embA_bf;
  ushort* embNext = embB_bf;
  for (int l = 0; l < 3; ++l) {
    const int* pA = (l == 0) ? ptrA : ptrA2;
    const int2* cA = (l == 0) ? cvA : cvA2;

    k_spmm_fusedA2<<<4096, 256, 0, stream>>>(pA, cA, embCur, Wi, embNext, out);

    if (l == 1)
      k_dualS<<<2048, 256, 0, stream>>>(ptrS, cvS, NEGPa, Wc, w2, w1, fk_b,
                                        out_logits, 4, NEGPb);
    else if (l == 2)
      k_dualS<<<2048, 256, 0, stream>>>(ptrS, cvS, NEGPb, Wc, w2, w1, fk_b,
                                        out_logits, 5, (uint*)nullptr);

    hipMemsetAsync(sumsq, 0, sizeof(float), stream);
    k_users<<<1024, 256, 0, stream>>>(embNext, UCb, Ws, uraw, sumsq);
    k_users_acc<<<2048, 256, 0, stream>>>(uraw, sumsq, out);

    { ushort* t = embCur; embCur = embNext; embNext = t; }
  }
}

// Round 19
// 1444.454 us; speedup vs baseline: 2.1157x; 1.0095x over previous
//
#include <hip/hip_runtime.h>

#define NU 100000
#define NI 150000
#define NTOT 250000
#define DD 64
#define NNZ_A 2000000
#define NNZ_S 800000
#define SCAN_CHUNK 2048  // 256 threads x 8
#define NBS 49   // ceil(NU/2048)
#define NBA 123  // ceil(NTOT/2048)
#define GBS 391  // ceil(NNZ_S/2048)
#define GBA 977  // ceil(NNZ_A/2048)
#define HB (GBS + 2 * GBA)   // hist blocks in mega1
#define TB 1024              // transform blocks in mega1
#define IB 512               // item-init blocks in mega1

typedef unsigned int uint;
typedef unsigned short ushort;

#define LB __launch_bounds__(256, 4)
#define RFL(x) __builtin_amdgcn_readfirstlane(x)

__device__ __forceinline__ uint f2bf_bits(float x) {  // RNE round to bf16
  uint a = __float_as_uint(x);
  return (a + 0x7fffu + ((a >> 16) & 1u)) >> 16;
}
__device__ __forceinline__ ushort f2bf(float x) { return (ushort)f2bf_bits(x); }
__device__ __forceinline__ float bf2f(ushort h) { return __uint_as_float(((uint)h) << 16); }
__device__ __forceinline__ uint pack_bf16x2(float lo, float hi) {
  return f2bf_bits(lo) | (f2bf_bits(hi) << 16);
}
__device__ __forceinline__ float unpk_lo(uint p) { return __uint_as_float(p << 16); }
__device__ __forceinline__ float unpk_hi(uint p) { return __uint_as_float(p & 0xffff0000u); }

__device__ __forceinline__ float tanh_fast(float x) {
  float e = __expf(2.0f * x);
  return 1.0f - __fdividef(2.0f, e + 1.0f);
}

// ---- 64x64 GEMM with LDS-broadcast accumulator (R14-proven fencing) ----
__device__ __forceinline__ void gemm64x2_b(float aA, float aB,
                                           const float* __restrict__ Wt,
                                           volatile float* __restrict__ ab, int lane,
                                           float& oA, float& oB) {
  asm volatile("s_waitcnt lgkmcnt(0)" ::: "memory");
  __builtin_amdgcn_sched_barrier(0);
  ab[lane] = aA;
  ab[64 + lane] = aB;
  asm volatile("s_waitcnt lgkmcnt(0)" ::: "memory");
  __builtin_amdgcn_sched_barrier(0);
  float sA = 0.f, sB = 0.f;
#pragma unroll 4
  for (int k0 = 0; k0 < 64; k0 += 4) {
    float4 a4 = *(const float4*)(const float*)(ab + k0);
    float4 b4 = *(const float4*)(const float*)(ab + 64 + k0);
#pragma unroll
    for (int u = 0; u < 4; ++u) {
      float wk = Wt[(k0 + u) * 65 + lane];
      sA = fmaf(((const float*)&a4)[u], wk, sA);
      sB = fmaf(((const float*)&b4)[u], wk, sB);
    }
  }
  oA = sA; oB = sB;
}

__device__ __forceinline__ void gemm64x4_b(float a0, float a1, float a2, float a3,
                                           const float* __restrict__ Wt,
                                           volatile float* __restrict__ ab, int lane,
                                           float& o0, float& o1, float& o2, float& o3) {
  asm volatile("s_waitcnt lgkmcnt(0)" ::: "memory");
  __builtin_amdgcn_sched_barrier(0);
  ab[lane] = a0;
  ab[64 + lane] = a1;
  ab[128 + lane] = a2;
  ab[192 + lane] = a3;
  asm volatile("s_waitcnt lgkmcnt(0)" ::: "memory");
  __builtin_amdgcn_sched_barrier(0);
  float s0 = 0.f, s1 = 0.f, s2 = 0.f, s3 = 0.f;
#pragma unroll 4
  for (int k0 = 0; k0 < 64; k0 += 4) {
    float4 x0 = *(const float4*)(const float*)(ab + k0);
    float4 x1 = *(const float4*)(const float*)(ab + 64 + k0);
    float4 x2 = *(const float4*)(const float*)(ab + 128 + k0);
    float4 x3 = *(const float4*)(const float*)(ab + 192 + k0);
#pragma unroll
    for (int u = 0; u < 4; ++u) {
      float wk = Wt[(k0 + u) * 65 + lane];
      s0 = fmaf(((const float*)&x0)[u], wk, s0);
      s1 = fmaf(((const float*)&x1)[u], wk, s1);
      s2 = fmaf(((const float*)&x2)[u], wk, s2);
      s3 = fmaf(((const float*)&x3)[u], wk, s3);
    }
  }
  o0 = s0; o1 = s1; o2 = s2; o3 = s3;
}

__device__ __forceinline__ float gemm64x1_b(float a, const float* __restrict__ Wt,
                                            volatile float* __restrict__ ab, int lane) {
  asm volatile("s_waitcnt lgkmcnt(0)" ::: "memory");
  __builtin_amdgcn_sched_barrier(0);
  ab[lane] = a;
  asm volatile("s_waitcnt lgkmcnt(0)" ::: "memory");
  __builtin_amdgcn_sched_barrier(0);
  float s = 0.f;
#pragma unroll 4
  for (int k0 = 0; k0 < 64; k0 += 4) {
    float4 a4 = *(const float4*)(const float*)(ab + k0);
#pragma unroll
    for (int u = 0; u < 4; ++u)
      s = fmaf(((const float*)&a4)[u], Wt[(k0 + u) * 65 + lane], s);
  }
  return s;
}

__device__ __forceinline__ void stage_wt(const float* __restrict__ W, float* __restrict__ Wt) {
  for (int idx = threadIdx.x; idx < 64 * 64; idx += blockDim.x)
    Wt[(idx & 63) * 65 + (idx >> 6)] = W[idx];
  __syncthreads();
}

// ================= CSR build bodies =================
__device__ __forceinline__ void hist_body(const int* rows, int* cnt, int* rank,
                                          int nnz, int bid, int nb) {
  int tid = bid * 256 + threadIdx.x;
  int gsz = nb * 256;
  for (int b = tid; b < nnz; b += gsz * 8) {
#pragma unroll
    for (int u = 0; u < 8; ++u) {
      int i = b + u * gsz;
      if (i < nnz) rank[i] = atomicAdd(&cnt[rows[i]], 1);
    }
  }
}

__device__ __forceinline__ void scatter_body(const int* rows, const int* cols,
                                             const float* vals, const int* ptr,
                                             const int* rank, int2* cv, int nnz,
                                             int bid, int nb) {
  int tid = bid * 256 + threadIdx.x;
  int gsz = nb * 256;
  for (int b = tid; b < nnz; b += gsz * 8) {
#pragma unroll
    for (int u = 0; u < 8; ++u) {
      int i = b + u * gsz;
      if (i < nnz) {
        int r = rows[i];
        cv[ptr[r] + rank[i]] = make_int2(cols[i], __float_as_int(vals[i]));
      }
    }
  }
  if (bid == 0 && threadIdx.x < 8) cv[nnz + threadIdx.x] = make_int2(0, 0);  // pad
}

// ================= mega1: hist3 || transform(+user init) || items init =================
__global__ LB void k_mega1(const int* __restrict__ rowsS, int* __restrict__ cntS,
                           int* __restrict__ rankS,
                           const int* __restrict__ rowsA, int* __restrict__ cntA,
                           int* __restrict__ rankA,
                           const int* __restrict__ rowsA2, int* __restrict__ cntA2,
                           int* __restrict__ rankA2,
                           const float* __restrict__ u1, const float* __restrict__ u2,
                           const float* __restrict__ Wc, uint* __restrict__ SOCPt,
                           const float* __restrict__ item,
                           ushort* __restrict__ emb_bf, float* __restrict__ out_final) {
  __shared__ float Wt[64 * 65];
  __shared__ float AB[4][128];
  int bid = blockIdx.x;
  if (bid < GBS) {
    hist_body(rowsS, cntS, rankS, NNZ_S, bid, GBS);
  } else if (bid < GBS + GBA) {
    hist_body(rowsA, cntA, rankA, NNZ_A, bid - GBS, GBA);
  } else if (bid < HB) {
    hist_body(rowsA2, cntA2, rankA2, NNZ_A, bid - GBS - GBA, GBA);
  } else if (bid < HB + TB) {
    // transform + fused user-init
    stage_wt(Wc, Wt);
    int lane = threadIdx.x & 63;
    volatile float* ab = AB[threadIdx.x >> 6];
    int wid = ((bid - HB) * 256 + (int)threadIdx.x) >> 6;
    int nw = (TB * 256) >> 6;
    for (int i = wid; i < NU; i += nw) {
      float a1 = u1[(size_t)i * DD + lane];
      float a2 = u2[(size_t)i * DD + lane];
      float v = 0.5f * (a1 + a2);
      emb_bf[(size_t)i * DD + lane] = f2bf(v);
      out_final[(size_t)i * DD + lane] = 0.25f * v;
      float o1, o2;
      gemm64x2_b(a1, a2, Wt, ab, lane, o1, o2);
      SOCPt[(size_t)i * DD + lane] = pack_bf16x2(o1, o2);
    }
  } else {
    // items init
    int idx = (bid - HB - TB) * 256 + threadIdx.x;
    const int tot = NI * DD;
    const int nu = NU * DD;
    for (; idx < tot; idx += IB * 256) {
      float v = item[idx];
      emb_bf[nu + idx] = f2bf(v);
      out_final[nu + idx] = 0.25f * v;
    }
  }
}

// ================= scans (3-way batched, R18-proven) =================
__device__ __forceinline__ void scan1_body(const int* cnt, int* bsum, int n, int bid) {
  __shared__ int sdata[256];
  int base = bid * SCAN_CHUNK;
  int s = 0;
#pragma unroll
  for (int k = 0; k < 8; ++k) {
    int i = base + threadIdx.x * 8 + k;
    s += (i < n) ? cnt[i] : 0;
  }
  sdata[threadIdx.x] = s;
  __syncthreads();
  for (int off = 128; off > 0; off >>= 1) {
    if (threadIdx.x < off) sdata[threadIdx.x] += sdata[threadIdx.x + off];
    __syncthreads();
  }
  if (threadIdx.x == 0) bsum[bid] = sdata[0];
}

__global__ void k_scan1_3(const int* __restrict__ cntS, int* __restrict__ bsumS,
                          const int* __restrict__ cntA, int* __restrict__ bsumA,
                          const int* __restrict__ cntA2, int* __restrict__ bsumA2) {
  if ((int)blockIdx.x < NBS)            scan1_body(cntS, bsumS, NU, blockIdx.x);
  else if ((int)blockIdx.x < NBS + NBA) scan1_body(cntA, bsumA, NTOT, blockIdx.x - NBS);
  else                                  scan1_body(cntA2, bsumA2, NTOT, blockIdx.x - NBS - NBA);
}

__device__ __forceinline__ void scan2_body(int* bsum, int nb) {
  __shared__ int sdata[256];
  int v = (threadIdx.x < nb) ? bsum[threadIdx.x] : 0;
  sdata[threadIdx.x] = v;
  __syncthreads();
  for (int off = 1; off < 256; off <<= 1) {
    int t = (threadIdx.x >= (unsigned)off) ? sdata[threadIdx.x - off] : 0;
    __syncthreads();
    sdata[threadIdx.x] += t;
    __syncthreads();
  }
  if (threadIdx.x < nb) bsum[threadIdx.x] = sdata[threadIdx.x] - v;
}

__global__ void k_scan2_3(int* bsumS, int* bsumA, int* bsumA2) {
  if (blockIdx.x == 0)      scan2_body(bsumS, NBS);
  else if (blockIdx.x == 1) scan2_body(bsumA, NBA);
  else                      scan2_body(bsumA2, NBA);
}

__device__ __forceinline__ void scan3_body(const int* cnt, const int* bsum,
                                           int* rowptr, int n, int nnz, int bid) {
  __shared__ int sdata[256];
  int base = bid * SCAN_CHUNK;
  int loc[8];
  int s = 0;
#pragma unroll
  for (int k = 0; k < 8; ++k) {
    int i = base + threadIdx.x * 8 + k;
    loc[k] = (i < n) ? cnt[i] : 0;
    s += loc[k];
  }
  sdata[threadIdx.x] = s;
  __syncthreads();
  for (int off = 1; off < 256; off <<= 1) {
    int t = (threadIdx.x >= (unsigned)off) ? sdata[threadIdx.x - off] : 0;
    __syncthreads();
    sdata[threadIdx.x] += t;
    __syncthreads();
  }
  int pre = bsum[bid] + sdata[threadIdx.x] - s;
#pragma unroll
  for (int k = 0; k < 8; ++k) {
    int i = base + threadIdx.x * 8 + k;
    if (i < n) { rowptr[i] = pre; pre += loc[k]; }
  }
  if (bid == 0 && threadIdx.x == 0) rowptr[n] = nnz;
}

__global__ void k_scan3_3(const int* __restrict__ cntS, const int* __restrict__ bsumS,
                          int* __restrict__ ptrS,
                          const int* __restrict__ cntA, const int* __restrict__ bsumA,
                          int* __restrict__ ptrA,
                          const int* __restrict__ cntA2, const int* __restrict__ bsumA2,
                          int* __restrict__ ptrA2) {
  if ((int)blockIdx.x < NBS)            scan3_body(cntS, bsumS, ptrS, NU, NNZ_S, blockIdx.x);
  else if ((int)blockIdx.x < NBS + NBA) scan3_body(cntA, bsumA, ptrA, NTOT, NNZ_A, blockIdx.x - NBS);
  else                                  scan3_body(cntA2, bsumA2, ptrA2, NTOT, NNZ_A, blockIdx.x - NBS - NBA);
}

__global__ void k_scatter2_2(const int* __restrict__ rowsS, const int* __restrict__ colsS,
                             const float* __restrict__ valsS, const int* __restrict__ ptrS,
                             const int* __restrict__ rankS, int2* __restrict__ cvS,
                             const int* __restrict__ rowsA, const int* __restrict__ colsA,
                             const float* __restrict__ valsA, const int* __restrict__ ptrA,
                             const int* __restrict__ rankA, int2* __restrict__ cvA) {
  if ((int)blockIdx.x < GBS)
    scatter_body(rowsS, colsS, valsS, ptrS, rankS, cvS, NNZ_S, blockIdx.x, GBS);
  else
    scatter_body(rowsA, colsA, valsA, ptrA, rankA, cvA, NNZ_A, blockIdx.x - GBS, GBA);
}

// QUADP[i] = { SOCPt[i], lo16(SOCPt[s1[i]]) | hi16(SOCPt[s2[i]]) }
__global__ void k_negmap(const uint* __restrict__ SOCPt, const int* __restrict__ s1,
                         const int* __restrict__ s2, uint2* __restrict__ QUADP) {
  int idx = blockIdx.x * blockDim.x + threadIdx.x;
  const int tot = NU * DD;
  for (; idx < tot; idx += gridDim.x * blockDim.x) {
    int i = idx >> 6, j = idx & 63;
    uint soc = SOCPt[idx];
    uint lo = SOCPt[(size_t)s1[i] * DD + j];
    uint hi = SOCPt[(size_t)s2[i] * DD + j];
    QUADP[idx] = make_uint2(soc, (lo & 0xffffu) | (hi & 0xffff0000u));
  }
}

// ================= gather kernels (R16-validated, frozen) =================
__global__ LB void k_quadS(const int* __restrict__ rowptr, const int2* __restrict__ cv,
                           const uint2* __restrict__ QUADP, const float* __restrict__ Wc,
                           ushort* __restrict__ u1s, ushort* __restrict__ u2s,
                           ushort* __restrict__ n1o, ushort* __restrict__ n2o,
                           uint* __restrict__ NEGPa) {
  __shared__ float Wt[64 * 65];
  __shared__ float AB[4][128];
  stage_wt(Wc, Wt);
  int lane = threadIdx.x & 63;
  volatile float* ab = AB[threadIdx.x >> 6];
  int wid = (blockIdx.x * blockDim.x + threadIdx.x) >> 6;
  int nw = (gridDim.x * blockDim.x) >> 6;
  for (int r = wid; r < NU; r += nw) {
    int start = RFL(rowptr[r]);
    int n = RFL(rowptr[r + 1]) - start;
    float a1 = 0.f, a2 = 0.f, a3 = 0.f, a4 = 0.f;
    for (int k = 0; k < n; k += 8) {
      int2 e[8];
#pragma unroll
      for (int u = 0; u < 8; ++u) e[u] = cv[start + k + u];
      uint2 q[8];
#pragma unroll
      for (int u = 0; u < 8; ++u)
        q[u] = QUADP[(size_t)(uint)e[u].x * 64u + (uint)lane];
#pragma unroll
      for (int u = 0; u < 8; ++u) {
        float sv = (k + u < n) ? __int_as_float(e[u].y) : 0.f;
        a1 = fmaf(sv, unpk_lo(q[u].x), a1);
        a2 = fmaf(sv, unpk_hi(q[u].x), a2);
        a3 = fmaf(sv, unpk_lo(q[u].y), a3);
        a4 = fmaf(sv, unpk_hi(q[u].y), a4);
      }
    }
    float t1 = tanh_fast(a1), t2 = tanh_fast(a2), t3 = tanh_fast(a3), t4 = tanh_fast(a4);
    u1s[(size_t)r * DD + lane] = f2bf(t1);
    u2s[(size_t)r * DD + lane] = f2bf(t2);
    n1o[(size_t)r * DD + lane] = f2bf(t3);
    n2o[(size_t)r * DD + lane] = f2bf(t4);
    float o3, o4;
    gemm64x2_b(t3, t4, Wt, ab, lane, o3, o4);
    NEGPa[(size_t)r * DD + lane] = pack_bf16x2(o3, o4);
  }
}

__global__ LB void k_dualS(const int* __restrict__ rowptr, const int2* __restrict__ cv,
                           const uint* __restrict__ T, const float* __restrict__ Wc,
                           const float* __restrict__ wva, const float* __restrict__ wvb,
                           const float* __restrict__ fkb, float* __restrict__ out_logits,
                           int slot, uint* __restrict__ Tnext) {
  __shared__ float Wt[64 * 65];
  __shared__ float AB[4][256];
  stage_wt(Wc, Wt);
  int lane = threadIdx.x & 63;
  volatile float* ab = AB[threadIdx.x >> 6];
  int wid = (blockIdx.x * blockDim.x + threadIdx.x) >> 6;
  int nw = (gridDim.x * blockDim.x) >> 6;
  float b = fkb[0];
  float wa = wva[lane], wb = wvb[lane];
  for (int r = wid * 2; r < NU; r += nw * 2) {
    int s0 = RFL(rowptr[r]);
    int sm = RFL(rowptr[r + 1]);
    int s1e = RFL(rowptr[r + 2]);
    int n0 = sm - s0, n1 = s1e - sm;
    int kmax = max(n0, n1);
    float a0A = 0.f, a0B = 0.f, a1A = 0.f, a1B = 0.f;
    for (int k = 0; k < kmax; k += 8) {
      int b0 = (k < n0) ? s0 + k : s0;
      int b1 = (k < n1) ? sm + k : sm;
      int2 e0[8], e1[8];
#pragma unroll
      for (int u = 0; u < 8; ++u) e0[u] = cv[b0 + u];
#pragma unroll
      for (int u = 0; u < 8; ++u) e1[u] = cv[b1 + u];
      uint q0[8], q1[8];
#pragma unroll
      for (int u = 0; u < 8; ++u)
        q0[u] = T[(size_t)(uint)e0[u].x * 64u + (uint)lane];
#pragma unroll
      for (int u = 0; u < 8; ++u)
        q1[u] = T[(size_t)(uint)e1[u].x * 64u + (uint)lane];
#pragma unroll
      for (int u = 0; u < 8; ++u) {
        float sv0 = (k + u < n0) ? __int_as_float(e0[u].y) : 0.f;
        float sv1 = (k + u < n1) ? __int_as_float(e1[u].y) : 0.f;
        a0A = fmaf(sv0, unpk_lo(q0[u]), a0A);
        a0B = fmaf(sv0, unpk_hi(q0[u]), a0B);
        a1A = fmaf(sv1, unpk_lo(q1[u]), a1A);
        a1B = fmaf(sv1, unpk_hi(q1[u]), a1B);
      }
    }
    float t0a = tanh_fast(a0A), t0b = tanh_fast(a0B);
    float t1a = tanh_fast(a1A), t1b = tanh_fast(a1B);
    float p0a = t0a * wa, p0b = t0b * wb, p1a = t1a * wa, p1b = t1b * wb;
#pragma unroll
    for (int off = 32; off > 0; off >>= 1) {
      p0a += __shfl_xor(p0a, off);
      p0b += __shfl_xor(p0b, off);
      p1a += __shfl_xor(p1a, off);
      p1b += __shfl_xor(p1b, off);
    }
    if (lane == 0) {
      out_logits[(size_t)(NU + r) * 6 + slot] = p0a + b;
      out_logits[(size_t)r * 6 + slot] = p0b + b;
      out_logits[(size_t)(NU + r + 1) * 6 + slot] = p1a + b;
      out_logits[(size_t)(r + 1) * 6 + slot] = p1b + b;
    }
    if (Tnext) {
      float o0a, o0b, o1a, o1b;
      gemm64x4_b(t0a, t0b, t1a, t1b, Wt, ab, lane, o0a, o0b, o1a, o1b);
      Tnext[(size_t)r * DD + lane] = pack_bf16x2(o0a, o0b);
      Tnext[(size_t)(r + 1) * DD + lane] = pack_bf16x2(o1a, o1b);
    }
  }
}

// fusedA2 body shared by k_spmm_fusedA2 and k_l0
__device__ __forceinline__ void fusedA2_body(const int* __restrict__ rowptr,
                                             const int2* __restrict__ cv,
                                             const ushort* __restrict__ X,
                                             float* __restrict__ Wt,
                                             volatile float* __restrict__ ab,
                                             ushort* __restrict__ embNext,
                                             float* __restrict__ outF,
                                             int wid, int nw) {
  int lane = threadIdx.x & 63;
  for (int r = wid * 4; r < NTOT; r += nw * 4) {
    int sp[5];
#pragma unroll
    for (int i = 0; i < 5; ++i) sp[i] = RFL(rowptr[r + i]);
    int n0 = sp[1] - sp[0], n1 = sp[2] - sp[1];
    int n2 = sp[3] - sp[2], n3 = sp[4] - sp[3];
    int kmax = max(max(n0, n1), max(n2, n3));
    float acc0 = 0.f, acc1 = 0.f, acc2 = 0.f, acc3 = 0.f;
    for (int k = 0; k < kmax; k += 8) {
      int b0 = (k < n0) ? sp[0] + k : sp[0];
      int b1 = (k < n1) ? sp[1] + k : sp[1];
      int b2 = (k < n2) ? sp[2] + k : sp[2];
      int b3 = (k < n3) ? sp[3] + k : sp[3];
      int2 e0[8], e1[8], e2[8], e3[8];
#pragma unroll
      for (int u = 0; u < 8; ++u) e0[u] = cv[b0 + u];
#pragma unroll
      for (int u = 0; u < 8; ++u) e1[u] = cv[b1 + u];
#pragma unroll
      for (int u = 0; u < 8; ++u) e2[u] = cv[b2 + u];
#pragma unroll
      for (int u = 0; u < 8; ++u) e3[u] = cv[b3 + u];
      uint h0[8], h1[8], h2[8], h3[8];
#pragma unroll
      for (int u = 0; u < 8; ++u)
        h0[u] = X[(size_t)(uint)e0[u].x * 64u + (uint)lane];
#pragma unroll
      for (int u = 0; u < 8; ++u)
        h1[u] = X[(size_t)(uint)e1[u].x * 64u + (uint)lane];
#pragma unroll
      for (int u = 0; u < 8; ++u)
        h2[u] = X[(size_t)(uint)e2[u].x * 64u + (uint)lane];
#pragma unroll
      for (int u = 0; u < 8; ++u)
        h3[u] = X[(size_t)(uint)e3[u].x * 64u + (uint)lane];
#pragma unroll
      for (int u = 0; u < 8; ++u) {
        float sv0 = (k + u < n0) ? __int_as_float(e0[u].y) : 0.f;
        float sv1 = (k + u < n1) ? __int_as_float(e1[u].y) : 0.f;
        float sv2 = (k + u < n2) ? __int_as_float(e2[u].y) : 0.f;
        float sv3 = (k + u < n3) ? __int_as_float(e3[u].y) : 0.f;
        acc0 = fmaf(sv0, __uint_as_float(h0[u] << 16), acc0);
        acc1 = fmaf(sv1, __uint_as_float(h1[u] << 16), acc1);
        acc2 = fmaf(sv2, __uint_as_float(h2[u] << 16), acc2);
        acc3 = fmaf(sv3, __uint_as_float(h3[u] << 16), acc3);
      }
    }
    if (r < NU) {  // NU % 4 == 0: group never straddles
      float o0, o1, o2, o3;
      gemm64x4_b(acc0, acc1, acc2, acc3, Wt, ab, lane, o0, o1, o2, o3);
      embNext[(size_t)r * DD + lane] = f2bf(tanh_fast(o0));
      embNext[(size_t)(r + 1) * DD + lane] = f2bf(tanh_fast(o1));
      embNext[(size_t)(r + 2) * DD + lane] = f2bf(tanh_fast(o2));
      embNext[(size_t)(r + 3) * DD + lane] = f2bf(tanh_fast(o3));
    } else {
      embNext[(size_t)r * DD + lane] = f2bf(acc0);
      embNext[(size_t)(r + 1) * DD + lane] = f2bf(acc1);
      embNext[(size_t)(r + 2) * DD + lane] = f2bf(acc2);
      embNext[(size_t)(r + 3) * DD + lane] = f2bf(acc3);
      outF[(size_t)r * DD + lane] += 0.25f * acc0;
      outF[(size_t)(r + 1) * DD + lane] += 0.25f * acc1;
      outF[(size_t)(r + 2) * DD + lane] += 0.25f * acc2;
      outF[(size_t)(r + 3) * DD + lane] += 0.25f * acc3;
    }
  }
}

__global__ LB void k_spmm_fusedA2(const int* __restrict__ rowptr, const int2* __restrict__ cv,
                                  const ushort* __restrict__ X, const float* __restrict__ W,
                                  ushort* __restrict__ embNext, float* __restrict__ outF) {
  __shared__ float Wt[64 * 65];
  __shared__ float AB[4][256];
  stage_wt(W, Wt);
  int wid = (blockIdx.x * blockDim.x + threadIdx.x) >> 6;
  int nw = (gridDim.x * blockDim.x) >> 6;
  fusedA2_body(rowptr, cv, X, Wt, AB[threadIdx.x >> 6], embNext, outF, wid, nw);
}

// layer-0 fusedA2 || A2 scatter (independent: fusedA2 reads cvA, scatter writes cvA2)
__global__ LB void k_l0(const int* __restrict__ rowsA2, const int* __restrict__ colsA2,
                        const float* __restrict__ valsA2, const int* __restrict__ ptrA2,
                        const int* __restrict__ rankA2, int2* __restrict__ cvA2,
                        const int* __restrict__ rowptr, const int2* __restrict__ cv,
                        const ushort* __restrict__ X, const float* __restrict__ W,
                        ushort* __restrict__ embNext, float* __restrict__ outF) {
  __shared__ float Wt[64 * 65];
  __shared__ float AB[4][256];
  if ((int)blockIdx.x < GBA) {
    scatter_body(rowsA2, colsA2, valsA2, ptrA2, rankA2, cvA2, NNZ_A, blockIdx.x, GBA);
  } else {
    stage_wt(W, Wt);
    int wid = (((int)blockIdx.x - GBA) * 256 + (int)threadIdx.x) >> 6;
    int nw = (4096 * 256) >> 6;
    fusedA2_body(rowptr, cv, X, Wt, AB[threadIdx.x >> 6], embNext, outF, wid, nw);
  }
}

// ---------- fused column sums (bf16 inputs) ----------
__global__ void k_colsum2(const ushort* __restrict__ x1, const ushort* __restrict__ x2,
                          float* __restrict__ c1, float* __restrict__ c2) {
  int lane = threadIdx.x & 63;
  int wid = (blockIdx.x * blockDim.x + threadIdx.x) >> 6;
  int nw = (gridDim.x * blockDim.x) >> 6;
  float a1 = 0.f, a2 = 0.f;
  for (int i = wid; i < NU; i += nw) {
    a1 += bf2f(x1[(size_t)i * DD + lane]);
    a2 += bf2f(x2[(size_t)i * DD + lane]);
  }
  atomicAdd(&c1[lane], a1);
  atomicAdd(&c2[lane], a2);
}

__global__ void k_wvec(const float* __restrict__ fkW, const float* __restrict__ c1r,
                       const float* __restrict__ c2r, float* __restrict__ w1,
                       float* __restrict__ w2) {
  int j = threadIdx.x;
  float a1 = 0.f, a2 = 0.f;
  for (int k = 0; k < 64; ++k) {
    float w = fkW[j * 64 + k];
    a1 += w * c1r[k];
    a2 += w * c2r[k];
  }
  w1[j] = a1 * (1.0f / NU);
  w2[j] = a2 * (1.0f / NU);
}

// ================= post: logits4 || comb_gemm (both read u1s/u2s) =================
__global__ LB void k_post(const ushort* __restrict__ u1s, const ushort* __restrict__ u2s,
                          const ushort* __restrict__ n1o, const ushort* __restrict__ n2o,
                          const float* __restrict__ w1, const float* __restrict__ w2,
                          const float* __restrict__ fkb, float* __restrict__ out_logits,
                          const float* __restrict__ Ws, ushort* __restrict__ UC) {
  __shared__ float Wt[64 * 65];
  __shared__ float AB[4][128];
  int lane = threadIdx.x & 63;
  if ((int)blockIdx.x < 1024) {
    // logits: true slots 0-2 + false slot 3
    int wid = (blockIdx.x * 256 + threadIdx.x) >> 6;
    int nw = (1024 * 256) >> 6;
    float b = fkb[0];
    for (int i = wid; i < 2 * NU; i += nw) {
      bool lo = i < NU;
      int r = lo ? i : i - NU;
      const ushort* xs = lo ? u2s : u1s;
      const ushort* xn = lo ? n2o : n1o;
      const float* wv = lo ? w1 : w2;
      float wvl = wv[lane];
      float ps = bf2f(xs[(size_t)r * DD + lane]) * wvl;
      float pn = bf2f(xn[(size_t)r * DD + lane]) * wvl;
#pragma unroll
      for (int off = 32; off > 0; off >>= 1) {
        ps += __shfl_xor(ps, off);
        pn += __shfl_xor(pn, off);
      }
      if (lane == 0) {
        float vs = ps + b;
        out_logits[(size_t)i * 6 + 0] = vs;
        out_logits[(size_t)i * 6 + 1] = vs;
        out_logits[(size_t)i * 6 + 2] = vs;
        out_logits[(size_t)i * 6 + 3] = pn + b;
      }
    }
  } else {
    // comb: UC[i] = (0.5*(u1s+u2s)) @ Ws[:,64:].T -> bf16
    for (int idx = threadIdx.x; idx < 64 * 64; idx += blockDim.x)
      Wt[(idx & 63) * 65 + (idx >> 6)] = Ws[(idx >> 6) * 128 + 64 + (idx & 63)];
    __syncthreads();
    volatile float* ab = AB[threadIdx.x >> 6];
    int wid = (((int)blockIdx.x - 1024) * 256 + (int)threadIdx.x) >> 6;
    int nw = (1024 * 256) >> 6;
    for (int i = wid; i < NU; i += nw) {
      float c = 0.5f * (bf2f(u1s[(size_t)i * DD + lane]) + bf2f(u2s[(size_t)i * DD + lane]));
      UC[(size_t)i * DD + lane] = f2bf(gemm64x1_b(c, Wt, ab, lane));
    }
  }
}

__global__ LB void k_users(const ushort* __restrict__ u_next, const ushort* __restrict__ uc,
                           const float* __restrict__ Ws, float* __restrict__ users_raw,
                           float* __restrict__ sumsq) {
  __shared__ float Wt[64 * 65];
  __shared__ float AB[4][128];
  for (int idx = threadIdx.x; idx < 64 * 64; idx += blockDim.x)
    Wt[(idx & 63) * 65 + (idx >> 6)] = Ws[(idx >> 6) * 128 + (idx & 63)];
  __syncthreads();
  int lane = threadIdx.x & 63;
  volatile float* ab = AB[threadIdx.x >> 6];
  int wid = (blockIdx.x * blockDim.x + threadIdx.x) >> 6;
  int nw = (gridDim.x * blockDim.x) >> 6;
  float ss = 0.f;
  for (int i = wid; i < NU; i += nw) {
    float va = bf2f(u_next[(size_t)i * DD + lane]);
    float acc = bf2f(uc[(size_t)i * DD + lane]) + gemm64x1_b(va, Wt, ab, lane);
    users_raw[(size_t)i * DD + lane] = acc;
    ss += acc * acc;
  }
#pragma unroll
  for (int off = 32; off > 0; off >>= 1) ss += __shfl_xor(ss, off);
  if (lane == 0) atomicAdd(sumsq, ss);
}

__global__ void k_users_acc(const float* __restrict__ users_raw,
                            const float* __restrict__ sumsq, float* __restrict__ out_final) {
  float scale = 0.25f / sqrtf(*sumsq);
  int idx = blockIdx.x * blockDim.x + threadIdx.x;
  for (; idx < NU * DD; idx += gridDim.x * blockDim.x)
    out_final[idx] += users_raw[idx] * scale;
}

extern "C" void kernel_launch(void* const* d_in, const int* in_sizes, int n_in,
                              void* d_out, int out_size, void* d_ws, size_t ws_size,
                              hipStream_t stream) {
  const float* u1      = (const float*)d_in[0];
  const float* u2      = (const float*)d_in[1];
  const float* item    = (const float*)d_in[2];
  const float* Wi      = (const float*)d_in[3];
  const float* Wc      = (const float*)d_in[4];
  const float* Ws      = (const float*)d_in[5];
  const float* fk_W    = (const float*)d_in[6];
  const float* fk_b    = (const float*)d_in[7];
  const float* A_vals  = (const float*)d_in[8];
  const float* A2_vals = (const float*)d_in[9];
  const float* S_vals  = (const float*)d_in[10];
  const int*   A_rows  = (const int*)d_in[11];
  const int*   A_cols  = (const int*)d_in[12];
  const int*   A2_rows = (const int*)d_in[13];
  const int*   A2_cols = (const int*)d_in[14];
  const int*   S_rows  = (const int*)d_in[15];
  const int*   S_cols  = (const int*)d_in[16];
  const int*   sh1     = (const int*)d_in[17];
  const int*   sh2     = (const int*)d_in[18];

  // ---- workspace layout (float-word offsets); cv arrays padded +8 int2 ----
  float* ws = (float*)d_ws;
  ushort* embA_bf = (ushort*)ws;                   // [0, 8M)
  ushort* embB_bf = (ushort*)(ws + 8000000);       // [8M, 16M)
  uint2*  QUADP   = (uint2*)(ws + 16000000);       // [16M, 28.8M) live negmap..quadS
  int*    rankS2  = (int*)(ws + 16000000);         // 800,000 (QUADP overlay)
  int*    rankA   = (int*)(ws + 16800000);         // 2,000,000
  int*    cntS    = (int*)(ws + 18800000);         // 100,000 } contiguous
  int*    cntA    = (int*)(ws + 18900000);         // 250,000 } one memset
  int*    bsumS   = (int*)(ws + 19150000);         // 256
  int*    bsumA   = (int*)(ws + 19150256);         // 256
  int*    bsumA2  = (int*)(ws + 19150512);         // 256
  uint*   NEGPb   = (uint*)(ws + 16000000);        //  overlay: l=1 dual output
  float*  uraw    = ws + 22400000;                 //  overlay: fp32 users scratch
  uint*   NEGPa   = (uint*)(ws + 28800000);        // [28.8M, 35.2M)
  ushort* u1s     = (ushort*)(ws + 35200000);      // [35.2M, 38.4M) dead after k_post
  ushort* u2s     = (ushort*)(ws + 38400000);      // [38.4M, 41.6M) dead after k_post
  int2*   cvA2    = (int2*)(ws + 35200000);        //  overlay: written in k_l0
  uint*   SOCPt   = (uint*)(ws + 41600000);        // [41.6M, 48M) dead after negmap
  ushort* n1o     = (ushort*)(ws + 41600000);      //  overlay: quadS output
  ushort* UCb     = (ushort*)(ws + 41600000);      //  overlay: k_post comb output
  ushort* n2o     = (ushort*)(ws + 44800000);      //  overlay: quadS output
  int2*   cvA     = (int2*)(ws + 48000000);        // 2,000,008 int2
  int2*   cvS     = (int2*)(ws + 52000016);        // 800,008 int2
  int*    ptrA    = (int*)(ws + 53600032);         // 250,001
  int*    ptrS    = ptrA + (NTOT + 1);             // 100,001
  int*    cntA2   = ptrS + (NU + 1);               // 250,000 (permanent)
  int*    spare   = cntA2 + NTOT;                  // 256
  float*  c1r     = (float*)(spare + 256);         // 64
  float*  c2r     = c1r + 64;
  float*  w1      = c2r + 64;
  float*  w2      = w1 + 64;
  float*  sumsq   = w2 + 64;                       // 1
  int*    rankA2  = (int*)(ws + 54200580);         // 2,000,000
  int*    ptrA2   = (int*)(ws + 56200580);         // 250,001 -> 56,450,581 (225.8MB)

  float* out        = (float*)d_out;
  float* out_logits = out + (size_t)NTOT * DD;

  // ---------- mega1: 3-way hist || transform(+user init) || items init ----------
  hipMemsetAsync(cntS, 0, 350000 * sizeof(int), stream);          // cntS+cntA
  hipMemsetAsync(cntA2, 0, (size_t)NTOT * sizeof(int), stream);   // cntA2
  hipMemsetAsync(c1r, 0, 128 * sizeof(float), stream);
  k_mega1<<<HB + TB + IB, 256, 0, stream>>>(S_rows, cntS, rankS2,
                                            A_rows, cntA, rankA,
                                            A2_rows, cntA2, rankA2,
                                            u1, u2, Wc, SOCPt, item, embA_bf, out);

  // ---------- scans + S/A scatter ----------
  k_scan1_3<<<NBS + 2 * NBA, 256, 0, stream>>>(cntS, bsumS, cntA, bsumA, cntA2, bsumA2);
  k_scan2_3<<<3, 256, 0, stream>>>(bsumS, bsumA, bsumA2);
  k_scan3_3<<<NBS + 2 * NBA, 256, 0, stream>>>(cntS, bsumS, ptrS,
                                               cntA, bsumA, ptrA,
                                               cntA2, bsumA2, ptrA2);
  k_scatter2_2<<<GBS + GBA, 256, 0, stream>>>(S_rows, S_cols, S_vals, ptrS, rankS2, cvS,
                                              A_rows, A_cols, A_vals, ptrA, rankA, cvA);

  // ---------- negmap + quad gather ----------
  k_negmap<<<1024, 256, 0, stream>>>(SOCPt, sh1, sh2, QUADP);
  k_quadS<<<2048, 256, 0, stream>>>(ptrS, cvS, QUADP, Wc, u1s, u2s, n1o, n2o, NEGPa);
  k_colsum2<<<256, 256, 0, stream>>>(u1s, u2s, c1r, c2r);
  k_wvec<<<1, 64, 0, stream>>>(fk_W, c1r, c2r, w1, w2);
  k_post<<<2048, 256, 0, stream>>>(u1s, u2s, n1o, n2o, w1, w2, fk_b, out_logits, Ws, UCb);

  // ---------- layer 0: fusedA2 || A2 scatter (u1s/u2s dead after k_post) ----------
  k_l0<<<GBA + 4096, 256, 0, stream>>>(A2_rows, A2_cols, A2_vals, ptrA2, rankA2, cvA2,
                                       ptrA, cvA, embA_bf, Wi, embB_bf, out);
  hipMemsetAsync(sumsq, 0, sizeof(float), stream);
  k_users<<<1024, 256, 0, stream>>>(embB_bf, UCb, Ws, uraw, sumsq);
  k_users_acc<<<2048, 256, 0, stream>>>(uraw, sumsq, out);

  // ---------- layer 1 ----------
  k_spmm_fusedA2<<<4096, 256, 0, stream>>>(ptrA2, cvA2, embB_bf, Wi, embA_bf, out);
  k_dualS<<<2048, 256, 0, stream>>>(ptrS, cvS, NEGPa, Wc, w2, w1, fk_b,
                                    out_logits, 4, NEGPb);
  hipMemsetAsync(sumsq, 0, sizeof(float), stream);
  k_users<<<1024, 256, 0, stream>>>(embA_bf, UCb, Ws, uraw, sumsq);
  k_users_acc<<<2048, 256, 0, stream>>>(uraw, sumsq, out);

  // ---------- layer 2 ----------
  k_spmm_fusedA2<<<4096, 256, 0, stream>>>(ptrA2, cvA2, embA_bf, Wi, embB_bf, out);
  k_dualS<<<2048, 256, 0, stream>>>(ptrS, cvS, NEGPb, Wc, w2, w1, fk_b,
                                    out_logits, 5, (uint*)nullptr);
  hipMemsetAsync(sumsq, 0, sizeof(float), stream);
  k_users<<<1024, 256, 0, stream>>>(embB_bf, UCb, Ws, uraw, sumsq);
  k_users_acc<<<2048, 256, 0, stream>>>(uraw, sumsq, out);
}